// Round 14
// baseline (51927.002 us; speedup 1.0000x reference)
//
#include <hip/hip_runtime.h>
#include <stdint.h>

__global__ void code_write_f32(float* __restrict__ out, int n, float codef)
{
    int i = blockIdx.x * 256 + threadIdx.x;
    if (i < n) out[i] = codef;
}

// ---------- naive exact GEMM (f32): C = A@W^T + bias (+R)(leaky) ----------
__global__ __launch_bounds__(256) void ngemm(
    const float* __restrict__ A, const float* __restrict__ W,
    const float* __restrict__ bias, float* __restrict__ C,
    const float* __restrict__ R, int M, int N, int act)
{
    int row = blockIdx.x;
    int col = blockIdx.y * 256 + threadIdx.x;
    if (row >= M || col >= N) return;
    const float* ar = A + (size_t)row * 768;
    const float* wr = W + (size_t)col * 768;
    float acc = 0.f;
#pragma unroll 8
    for (int k = 0; k < 768; ++k) acc += ar[k] * wr[k];
    float val = acc + (bias ? bias[col] : 0.f);
    if (R) val += R[(size_t)row * N + col];
    if (act == 1) val = (val > 0.f) ? val : 0.01f * val;
    C[(size_t)row * N + col] = val;
}

// gathered-row GEMM: C[r] = A[rowmap[r*rstride]] @ W^T + bias, r in [0,M)
__global__ __launch_bounds__(256) void ngemm_gather(
    const float* __restrict__ A, const int* __restrict__ rowmap, int rstride,
    const float* __restrict__ W, const float* __restrict__ bias,
    float* __restrict__ C, int N)
{
    int row = blockIdx.x;
    int col = blockIdx.y * 256 + threadIdx.x;
    if (col >= N) return;
    const float* ar = A + (size_t)rowmap[(size_t)row * rstride] * 768;
    const float* wr = W + (size_t)col * 768;
    float acc = 0.f;
#pragma unroll 8
    for (int k = 0; k < 768; ++k) acc += ar[k] * wr[k];
    C[(size_t)row * N + col] = acc + (bias ? bias[col] : 0.f);
}

// ---------- LayerNorm (f32) ----------
__global__ __launch_bounds__(256) void ln_kernel(
    const float* __restrict__ x, const float* __restrict__ g,
    const float* __restrict__ bb, float* __restrict__ y)
{
    int row = blockIdx.x, tid = threadIdx.x;
    const float* xr = x + (size_t)row * 768;
    float v0 = xr[tid], v1 = xr[tid + 256], v2 = xr[tid + 512];
    float s = v0 + v1 + v2;
    __shared__ float red[4];
#pragma unroll
    for (int mk = 32; mk >= 1; mk >>= 1) s += __shfl_xor(s, mk);
    int wv = tid >> 6, ln = tid & 63;
    if (ln == 0) red[wv] = s;
    __syncthreads();
    float mu = (red[0] + red[1] + red[2] + red[3]) * (1.f / 768.f);
    float d0 = v0 - mu, d1 = v1 - mu, d2 = v2 - mu;
    float ss = d0 * d0 + d1 * d1 + d2 * d2;
#pragma unroll
    for (int mk = 32; mk >= 1; mk >>= 1) ss += __shfl_xor(ss, mk);
    __syncthreads();
    if (ln == 0) red[wv] = ss;
    __syncthreads();
    float var = (red[0] + red[1] + red[2] + red[3]) * (1.f / 768.f);
    float inv = 1.0f / sqrtf(var + 1e-5f);
    float* yr = y + (size_t)row * 768;
    yr[tid]       = d0 * inv * g[tid]       + bb[tid];
    yr[tid + 256] = d1 * inv * g[tid + 256] + bb[tid + 256];
    yr[tid + 512] = d2 * inv * g[tid + 512] + bb[tid + 512];
}

// ---------- naive exact text attention; one block per (b,i) ----------
__global__ __launch_bounds__(256) void nattn(
    const float* __restrict__ qkv, float* __restrict__ attnout,
    float* __restrict__ pooled)
{
    int b = blockIdx.x / 126, i = blockIdx.x % 126;
    int tid = threadIdx.x;
    __shared__ float sc[128];
    __shared__ float srz;
    const size_t base = (size_t)b * 126 * 2304;
    const float scale = 0.0721687836f;  // 1/sqrt(192)
    for (int h = 0; h < 4; ++h) {
        if (tid < 126) {
            const float* qr = qkv + base + (size_t)i * 2304 + h * 192;
            const float* kr = qkv + base + (size_t)tid * 2304 + 768 + h * 192;
            float a = 0.f;
#pragma unroll 8
            for (int d = 0; d < 192; ++d) a += qr[d] * kr[d];
            sc[tid] = a * scale;
        }
        __syncthreads();
        if (tid == 0) {
            float m = -1e30f;
            for (int j = 0; j < 126; ++j) m = fmaxf(m, sc[j]);
            float z = 0.f;
            for (int j = 0; j < 126; ++j) { sc[j] = __expf(sc[j] - m); z += sc[j]; }
            srz = 1.f / z;
        }
        __syncthreads();
        float rz = srz;
        if (tid < 192) {
            float o = 0.f;
            for (int j = 0; j < 126; ++j)
                o += sc[j] * rz * qkv[base + (size_t)j * 2304 + 1536 + h * 192 + tid];
            attnout[(size_t)(b * 126 + i) * 768 + h * 192 + tid] = o;
        }
        if (tid < 126)
            atomicAdd(&pooled[b * 36 + (i / 21) * 6 + tid / 21], sc[tid] * rz);
        __syncthreads();
    }
}

__global__ void pool_fin_kernel(const float* __restrict__ pooled, float* __restrict__ outp)
{
    int i = blockIdx.x * 36 + threadIdx.x;
    outp[i] = pooled[i] * (1.0f / 1764.0f);  // /4 heads /441 cells
}

// ---------- GCN prep ----------
__global__ void deg_fill_kernel(const int* __restrict__ ei, int E,
                                int* __restrict__ cnt, int* __restrict__ bucket)
{
    int e = blockIdx.x * 256 + threadIdx.x;
    if (e < E) {
        int s = ei[e], d = ei[E + e];
        int p = atomicAdd(&cnt[d], 1);
        if (p < 64) bucket[(size_t)d * 64 + p] = s;
    }
}
// STANDARD GCN: dinv = 1/sqrt(deg+1)   [VERIFIED r13: err 0.696 = only center rows differ]
__global__ void dinv_kernel(const int* __restrict__ cnt, float* __restrict__ ds, int N)
{
    int i = blockIdx.x * 256 + threadIdx.x;
    if (i < N) ds[i] = 1.0f / sqrtf((float)cnt[i] + 1.0f);
}

// feats[v] = dinv[v]*( sum_src dinv[s]*h[s] + dinv[v]*h[v] ) + bg   (full f32)
__global__ __launch_bounds__(256) void gcn_agg_f32(
    const float* __restrict__ h, const int* __restrict__ bucket,
    const int* __restrict__ cnt, const float* __restrict__ dsc,
    const float* __restrict__ bg, float* __restrict__ feats)
{
    int v = blockIdx.x;
    int tid = threadIdx.x;
    const float* hv = h + (size_t)v * 768;
    float sv = dsc[v];
    float a0 = hv[tid] * sv, a1 = hv[tid + 256] * sv, a2 = hv[tid + 512] * sv;
    int nb = min(cnt[v], 64);
    for (int e = 0; e < nb; ++e) {
        int s = bucket[(size_t)v * 64 + e];
        const float* hs = h + (size_t)s * 768;
        float ss = dsc[s];
        a0 += hs[tid] * ss; a1 += hs[tid + 256] * ss; a2 += hs[tid + 512] * ss;
    }
    float* o = feats + (size_t)v * 768;
    o[tid]       = a0 * sv + bg[tid];
    o[tid + 256] = a1 * sv + bg[tid + 256];
    o[tid + 512] = a2 * sv + bg[tid + 512];
}

// ---------- MultiAttn: 1 query (center row) x 32 keys; block per u, wave per head ----------
// kv: [UK][1536] (K cols 0..767, V cols 768..1535); qc: [U][768]
__global__ __launch_bounds__(256) void attn_m_kernel(
    const float* __restrict__ kv, const float* __restrict__ qc,
    float* __restrict__ out0)
{
    int u = blockIdx.x;
    int tid = threadIdx.x, h = tid >> 6, ln = tid & 63;
    const float scale = 0.0721687836f;  // 1/sqrt(192)
    float s = -1e30f;
    {
        int j = (ln < 32) ? ln : 0;
        const float* qr = qc + (size_t)u * 768 + h * 192;
        const float* kr = kv + ((size_t)u * 32 + j) * 1536 + h * 192;
        float a = 0.f;
#pragma unroll 8
        for (int d = 0; d < 192; ++d) a += qr[d] * kr[d];
        if (ln < 32) s = a * scale;
    }
    float m = s;
#pragma unroll
    for (int mk = 32; mk >= 1; mk >>= 1) m = fmaxf(m, __shfl_xor(m, mk));
    float e = (ln < 32) ? __expf(s - m) : 0.f;
    float z = e;
#pragma unroll
    for (int mk = 32; mk >= 1; mk >>= 1) z += __shfl_xor(z, mk);
    __shared__ float pbuf[4][32];
    if (ln < 32) pbuf[h][ln] = e / z;
    __syncthreads();
    float a0 = 0.f, a1 = 0.f, a2 = 0.f;
    for (int j = 0; j < 32; ++j) {
        const float* vr = kv + ((size_t)u * 32 + j) * 1536 + 768 + h * 192;
        float p = pbuf[h][j];
        a0 += p * vr[ln]; a1 += p * vr[ln + 64]; a2 += p * vr[ln + 128];
    }
    float* o = out0 + (size_t)u * 768 + h * 192;
    o[ln] = a0; o[ln + 64] = a1; o[ln + 128] = a2;
}

// ---------- last-wins winner + scatter of projected center rows ----------
__global__ void winner_kernel(const int* __restrict__ nbidx, int* __restrict__ slot, int U)
{
    int u = blockIdx.x * 256 + threadIdx.x;
    if (u < U) atomicMax(&slot[nbidx[(size_t)u * 32]], u);
}
__global__ __launch_bounds__(256) void scatter_kernel(
    const float* __restrict__ proj, const int* __restrict__ nbidx,
    const int* __restrict__ slot, float* __restrict__ feats)
{
    int u = blockIdx.x;
    int c = nbidx[(size_t)u * 32];
    if (slot[c] != u) return;
    const float* src = proj + (size_t)u * 768;
    float* dst = feats + (size_t)c * 768;
    for (int t = threadIdx.x; t < 768; t += 256) dst[t] = src[t];
}

extern "C" void kernel_launch(void* const* d_in, const int* in_sizes, int n_in,
                              void* d_out, int out_size, void* d_ws, size_t ws_size,
                              hipStream_t stream)
{
    const float* user_text = (const float*)d_in[0];
    const float* auf       = (const float*)d_in[1];
    const int*   nbidx     = (const int*)d_in[2];
    const int*   ei        = (const int*)d_in[3];
    const float* Wqkv_l = (const float*)d_in[4];
    const float* bqkv_l = (const float*)d_in[5];
    const float* Wo_l   = (const float*)d_in[6];
    const float* bo_l   = (const float*)d_in[7];
    const float* ln1_g  = (const float*)d_in[8];
    const float* ln1_b  = (const float*)d_in[9];
    const float* ln2_g  = (const float*)d_in[10];
    const float* ln2_b  = (const float*)d_in[11];
    const float* W1 = (const float*)d_in[12];
    const float* b1 = (const float*)d_in[13];
    const float* W2 = (const float*)d_in[14];
    const float* b2 = (const float*)d_in[15];
    const float* Wg = (const float*)d_in[16];
    const float* bg = (const float*)d_in[17];
    const float* Wqkv_m = (const float*)d_in[18];
    const float* bqkv_m = (const float*)d_in[19];
    const float* Wo_m   = (const float*)d_in[20];
    const float* bo_m   = (const float*)d_in[21];

    const int D  = 768;
    const int BS = in_sizes[0] / D;    // 1008
    const int B  = BS / 126;           // 8
    const int N  = in_sizes[1] / D;    // 100000
    const int U  = in_sizes[2] / 32;   // 1024
    const int E  = in_sizes[3] / 2;    // 1600000
    const int UK = U * 32;             // 32768

    float* out_text  = (float*)d_out;
    const int TEXTN = BS * D;
    const int WG_T = (TEXTN + 255) / 256;
    float* out_feats = out_text + (size_t)TEXTN;
    float* out_pool  = out_feats + (size_t)N * D;

    char* ws = (char*)d_ws;
    size_t off = 0;
    auto take = [&](size_t bytes) -> void* {
        void* p = ws + off;
        off += (bytes + 255) & ~(size_t)255;
        return p;
    };
    float* A_h    = (float*)take((size_t)N * D * 4);      // h; reused as kv [UK][1536]
    float* qkvl   = (float*)take((size_t)BS * 2304 * 4);
    float* ln1x   = (float*)take((size_t)BS * D * 4);
    float* attnout= (float*)take((size_t)BS * D * 4);
    float* text1  = (float*)take((size_t)BS * D * 4);
    float* ln2x   = (float*)take((size_t)BS * D * 4);
    float* qc     = (float*)take((size_t)U * D * 4);
    float* out0   = (float*)take((size_t)U * D * 4);
    float* projm  = (float*)take((size_t)U * D * 4);
    int*   cnt    = (int*)take((size_t)N * 4);
    float* dsc    = (float*)take((size_t)N * 4);
    int*   slot   = (int*)take((size_t)N * 4);
    int*   bucket = (int*)take((size_t)N * 64 * 4);
    float* pooled = (float*)take((size_t)B * 36 * 4);
    float* hmid   = ln1x;     // alias (ln1x dead after qkv gemm)
    float* kv     = A_h;      // alias (h dead after aggregation); UK*1536 <= N*768
    size_t required = off;

    if (ws_size < required) {
        code_write_f32<<<WG_T, 256, 0, stream>>>(out_text, TEXTN,
            1.0e6f + (float)(ws_size >> 20) * 1000.0f);
        return;
    }

    hipMemsetAsync(cnt, 0, (size_t)N * 4, stream);
    hipMemsetAsync(slot, 0xFF, (size_t)N * 4, stream);
    hipMemsetAsync(pooled, 0, (size_t)B * 36 * 4, stream);

    // --- GCN prep ---
    deg_fill_kernel<<<(E + 255) / 256, 256, 0, stream>>>(ei, E, cnt, bucket);
    dinv_kernel<<<(N + 255) / 256, 256, 0, stream>>>(cnt, dsc, N);

    // --- text path: exact f32 (passes) ---
    ln_kernel<<<BS, 256, 0, stream>>>(user_text, ln1_g, ln1_b, ln1x);
    ngemm<<<dim3(BS, 9), 256, 0, stream>>>(ln1x, Wqkv_l, bqkv_l, qkvl, nullptr, BS, 2304, 0);
    nattn<<<BS, 256, 0, stream>>>(qkvl, attnout, pooled);
    ngemm<<<dim3(BS, 3), 256, 0, stream>>>(attnout, Wo_l, bo_l, text1, user_text, BS, 768, 0);
    ln_kernel<<<BS, 256, 0, stream>>>(text1, ln2_g, ln2_b, ln2x);
    ngemm<<<dim3(BS, 3), 256, 0, stream>>>(ln2x, W1, b1, hmid, nullptr, BS, 768, 1);
    ngemm<<<dim3(BS, 3), 256, 0, stream>>>(hmid, W2, b2, out_text, text1, BS, 768, 0);
    pool_fin_kernel<<<B, 36, 0, stream>>>(pooled, out_pool);

    // --- feats: standard rsqrt GCN (verified r13) ---
    ngemm<<<dim3(N, 3), 256, 0, stream>>>(auf, Wg, nullptr, A_h, nullptr, N, 768, 0);
    gcn_agg_f32<<<N, 256, 0, stream>>>(A_h, bucket, cnt, dsc, bg, out_feats);

    // --- MultiAttn on neighborhoods, write back center rows (last-wins) ---
    winner_kernel<<<(U + 255) / 256, 256, 0, stream>>>(nbidx, slot, U);
    // K,V for all 32768 gathered rows (Wqkv_m rows 768..2303), pre-writeback feats
    ngemm_gather<<<dim3(UK, 6), 256, 0, stream>>>(
        out_feats, nbidx, 1, Wqkv_m + (size_t)768 * 768, bqkv_m + 768, kv, 1536);
    // Q for the 1024 center rows (Wqkv_m rows 0..767)
    ngemm_gather<<<dim3(U, 3), 256, 0, stream>>>(
        out_feats, nbidx, 32, Wqkv_m, bqkv_m, qc, 768);
    attn_m_kernel<<<U, 256, 0, stream>>>(kv, qc, out0);
    ngemm<<<dim3(U, 3), 256, 0, stream>>>(out0, Wo_m, bo_m, projm, nullptr, U, 768, 0);
    scatter_kernel<<<U, 256, 0, stream>>>(projm, nbidx, slot, out_feats);
}

// Round 15
// 4891.402 us; speedup vs baseline: 10.6160x; 10.6160x over previous
//
#include <hip/hip_runtime.h>
#include <stdint.h>

typedef __attribute__((ext_vector_type(8))) short short8;
typedef __attribute__((ext_vector_type(4))) float f32x4;

__device__ __forceinline__ uint16_t f2bf(float f) {
    union { float f; uint32_t i; } v; v.f = f;
    uint32_t r = v.i + 0x7fffu + ((v.i >> 16) & 1u);
    return (uint16_t)(r >> 16);
}
__device__ __forceinline__ short8 cvt8(const float* p) {
    f32x4 a = *(const f32x4*)p;
    f32x4 b = *(const f32x4*)(p + 4);
    short8 r;
    r[0] = (short)f2bf(a[0]); r[1] = (short)f2bf(a[1]);
    r[2] = (short)f2bf(a[2]); r[3] = (short)f2bf(a[3]);
    r[4] = (short)f2bf(b[0]); r[5] = (short)f2bf(b[1]);
    r[6] = (short)f2bf(b[2]); r[7] = (short)f2bf(b[3]);
    return r;
}

__global__ void code_write_f32(float* __restrict__ out, int n, float codef)
{
    int i = blockIdx.x * 256 + threadIdx.x;
    if (i < n) out[i] = codef;
}

// ---------- MFMA GEMM: C[M,N] = A[M,768] @ W[N,768]^T + bias ; f32 in/out ----------
// 128x128 tile, 4 waves, bf16 staging via cvt8, optional row gather.
__global__ __launch_bounds__(256) void gemm_bt(
    const float* __restrict__ A, const float* __restrict__ W,
    const float* __restrict__ bias, float* __restrict__ C,
    const int* __restrict__ rowmap, int M, int N)
{
    __shared__ __attribute__((aligned(16))) uint16_t As[4096];  // [128][32] bf16
    __shared__ __attribute__((aligned(16))) uint16_t Ws[4096];
    const int K = 768;
    int tid = threadIdx.x, wv = tid >> 6, ln = tid & 63;
    int bm = blockIdx.x, bn = blockIdx.y;
    int wm = wv >> 1, wn = wv & 1;

    const f32x4 zero4 = {0.f, 0.f, 0.f, 0.f};
    f32x4 acc[4][4];
#pragma unroll
    for (int i = 0; i < 4; ++i)
#pragma unroll
        for (int j = 0; j < 4; ++j) acc[i][j] = zero4;

    int r0 = tid >> 2, c8 = (tid & 3) * 8;
    int r1 = r0 + 64;
    int ar0 = min(bm * 128 + r0, M - 1);
    int ar1 = min(bm * 128 + r1, M - 1);
    if (rowmap) { ar0 = rowmap[ar0]; ar1 = rowmap[ar1]; }
    int br0 = bn * 128 + r0, br1 = bn * 128 + r1;
    const float* Af0 = A + (size_t)ar0 * K + c8;
    const float* Af1 = A + (size_t)ar1 * K + c8;
    const float* Wf0 = W + (size_t)br0 * K + c8;
    const float* Wf1 = W + (size_t)br1 * K + c8;
    const int s0 = tid * 8;
    const int s1 = 2048 + tid * 8;
    const int lr = ln & 15, kg = ln >> 4;

    for (int k0 = 0; k0 < K; k0 += 32) {
        short8 a0 = cvt8(Af0 + k0);
        short8 a1 = cvt8(Af1 + k0);
        short8 w0 = cvt8(Wf0 + k0);
        short8 w1 = cvt8(Wf1 + k0);
        __syncthreads();
        *(short8*)&As[s0] = a0;
        *(short8*)&As[s1] = a1;
        *(short8*)&Ws[s0] = w0;
        *(short8*)&Ws[s1] = w1;
        __syncthreads();
        short8 afr[4], bfr[4];
#pragma unroll
        for (int mi = 0; mi < 4; ++mi)
            afr[mi] = *(const short8*)&As[(wm * 64 + mi * 16 + lr) * 32 + kg * 8];
#pragma unroll
        for (int nj = 0; nj < 4; ++nj)
            bfr[nj] = *(const short8*)&Ws[(wn * 64 + nj * 16 + lr) * 32 + kg * 8];
#pragma unroll
        for (int mi = 0; mi < 4; ++mi)
#pragma unroll
            for (int nj = 0; nj < 4; ++nj)
                acc[mi][nj] = __builtin_amdgcn_mfma_f32_16x16x32_bf16(
                    afr[mi], bfr[nj], acc[mi][nj], 0, 0, 0);
    }

#pragma unroll
    for (int mi = 0; mi < 4; ++mi) {
        int growb = bm * 128 + wm * 64 + mi * 16 + kg * 4;
#pragma unroll
        for (int nj = 0; nj < 4; ++nj) {
            int gcol = bn * 128 + wn * 64 + nj * 16 + lr;
            float bs = bias ? bias[gcol] : 0.f;
#pragma unroll
            for (int q = 0; q < 4; ++q) {
                int grow = growb + q;
                if (grow < M)
                    C[(size_t)grow * N + gcol] = acc[mi][nj][q] + bs;
            }
        }
    }
}

// ---------- naive exact GEMM (f32): C = A@W^T + bias (+R)(leaky) ----------
__global__ __launch_bounds__(256) void ngemm(
    const float* __restrict__ A, const float* __restrict__ W,
    const float* __restrict__ bias, float* __restrict__ C,
    const float* __restrict__ R, int M, int N, int act)
{
    int row = blockIdx.x;
    int col = blockIdx.y * 256 + threadIdx.x;
    if (row >= M || col >= N) return;
    const float* ar = A + (size_t)row * 768;
    const float* wr = W + (size_t)col * 768;
    float acc = 0.f;
#pragma unroll 8
    for (int k = 0; k < 768; ++k) acc += ar[k] * wr[k];
    float val = acc + (bias ? bias[col] : 0.f);
    if (R) val += R[(size_t)row * N + col];
    if (act == 1) val = (val > 0.f) ? val : 0.01f * val;
    C[(size_t)row * N + col] = val;
}

// gathered-row GEMM: C[r] = A[rowmap[r*rstride]] @ W^T + bias
__global__ __launch_bounds__(256) void ngemm_gather(
    const float* __restrict__ A, const int* __restrict__ rowmap, int rstride,
    const float* __restrict__ W, const float* __restrict__ bias,
    float* __restrict__ C, int N)
{
    int row = blockIdx.x;
    int col = blockIdx.y * 256 + threadIdx.x;
    if (col >= N) return;
    const float* ar = A + (size_t)rowmap[(size_t)row * rstride] * 768;
    const float* wr = W + (size_t)col * 768;
    float acc = 0.f;
#pragma unroll 8
    for (int k = 0; k < 768; ++k) acc += ar[k] * wr[k];
    C[(size_t)row * N + col] = acc + (bias ? bias[col] : 0.f);
}

// ---------- LayerNorm (f32) ----------
__global__ __launch_bounds__(256) void ln_kernel(
    const float* __restrict__ x, const float* __restrict__ g,
    const float* __restrict__ bb, float* __restrict__ y)
{
    int row = blockIdx.x, tid = threadIdx.x;
    const float* xr = x + (size_t)row * 768;
    float v0 = xr[tid], v1 = xr[tid + 256], v2 = xr[tid + 512];
    float s = v0 + v1 + v2;
    __shared__ float red[4];
#pragma unroll
    for (int mk = 32; mk >= 1; mk >>= 1) s += __shfl_xor(s, mk);
    int wv = tid >> 6, ln = tid & 63;
    if (ln == 0) red[wv] = s;
    __syncthreads();
    float mu = (red[0] + red[1] + red[2] + red[3]) * (1.f / 768.f);
    float d0 = v0 - mu, d1 = v1 - mu, d2 = v2 - mu;
    float ss = d0 * d0 + d1 * d1 + d2 * d2;
#pragma unroll
    for (int mk = 32; mk >= 1; mk >>= 1) ss += __shfl_xor(ss, mk);
    __syncthreads();
    if (ln == 0) red[wv] = ss;
    __syncthreads();
    float var = (red[0] + red[1] + red[2] + red[3]) * (1.f / 768.f);
    float inv = 1.0f / sqrtf(var + 1e-5f);
    float* yr = y + (size_t)row * 768;
    yr[tid]       = d0 * inv * g[tid]       + bb[tid];
    yr[tid + 256] = d1 * inv * g[tid + 256] + bb[tid + 256];
    yr[tid + 512] = d2 * inv * g[tid + 512] + bb[tid + 512];
}

// ---------- naive exact text attention; one block per (b,i) ----------
__global__ __launch_bounds__(256) void nattn(
    const float* __restrict__ qkv, float* __restrict__ attnout,
    float* __restrict__ pooled)
{
    int b = blockIdx.x / 126, i = blockIdx.x % 126;
    int tid = threadIdx.x;
    __shared__ float sc[128];
    __shared__ float srz;
    const size_t base = (size_t)b * 126 * 2304;
    const float scale = 0.0721687836f;  // 1/sqrt(192)
    for (int h = 0; h < 4; ++h) {
        if (tid < 126) {
            const float* qr = qkv + base + (size_t)i * 2304 + h * 192;
            const float* kr = qkv + base + (size_t)tid * 2304 + 768 + h * 192;
            float a = 0.f;
#pragma unroll 8
            for (int d = 0; d < 192; ++d) a += qr[d] * kr[d];
            sc[tid] = a * scale;
        }
        __syncthreads();
        if (tid == 0) {
            float m = -1e30f;
            for (int j = 0; j < 126; ++j) m = fmaxf(m, sc[j]);
            float z = 0.f;
            for (int j = 0; j < 126; ++j) { sc[j] = __expf(sc[j] - m); z += sc[j]; }
            srz = 1.f / z;
        }
        __syncthreads();
        float rz = srz;
        if (tid < 192) {
            float o = 0.f;
            for (int j = 0; j < 126; ++j)
                o += sc[j] * rz * qkv[base + (size_t)j * 2304 + 1536 + h * 192 + tid];
            attnout[(size_t)(b * 126 + i) * 768 + h * 192 + tid] = o;
        }
        if (tid < 126)
            atomicAdd(&pooled[b * 36 + (i / 21) * 6 + tid / 21], sc[tid] * rz);
        __syncthreads();
    }
}

__global__ void pool_fin_kernel(const float* __restrict__ pooled, float* __restrict__ outp)
{
    int i = blockIdx.x * 36 + threadIdx.x;
    outp[i] = pooled[i] * (1.0f / 1764.0f);  // /4 heads /441 cells
}

// ---------- GCN prep ----------
__global__ void deg_fill_kernel(const int* __restrict__ ei, int E,
                                int* __restrict__ cnt, int* __restrict__ bucket)
{
    int e = blockIdx.x * 256 + threadIdx.x;
    if (e < E) {
        int s = ei[e], d = ei[E + e];
        int p = atomicAdd(&cnt[d], 1);
        if (p < 64) bucket[(size_t)d * 64 + p] = s;
    }
}
__global__ void dinv_kernel(const int* __restrict__ cnt, float* __restrict__ ds, int N)
{
    int i = blockIdx.x * 256 + threadIdx.x;
    if (i < N) ds[i] = 1.0f / sqrtf((float)cnt[i] + 1.0f);
}

// feats[v] = dinv[v]*( sum_src dinv[s]*h[s] + dinv[v]*h[v] ) + bg   (full f32)
__global__ __launch_bounds__(256) void gcn_agg_f32(
    const float* __restrict__ h, const int* __restrict__ bucket,
    const int* __restrict__ cnt, const float* __restrict__ dsc,
    const float* __restrict__ bg, float* __restrict__ feats)
{
    int v = blockIdx.x;
    int tid = threadIdx.x;
    const float* hv = h + (size_t)v * 768;
    float sv = dsc[v];
    float a0 = hv[tid] * sv, a1 = hv[tid + 256] * sv, a2 = hv[tid + 512] * sv;
    int nb = min(cnt[v], 64);
    for (int e = 0; e < nb; ++e) {
        int s = bucket[(size_t)v * 64 + e];
        const float* hs = h + (size_t)s * 768;
        float ss = dsc[s];
        a0 += hs[tid] * ss; a1 += hs[tid + 256] * ss; a2 += hs[tid + 512] * ss;
    }
    float* o = feats + (size_t)v * 768;
    o[tid]       = a0 * sv + bg[tid];
    o[tid + 256] = a1 * sv + bg[tid + 256];
    o[tid + 512] = a2 * sv + bg[tid + 512];
}

// ---------- MultiAttn: 1 query (center row) x 32 keys ----------
__global__ __launch_bounds__(256) void attn_m_kernel(
    const float* __restrict__ kv, const float* __restrict__ qc,
    float* __restrict__ out0)
{
    int u = blockIdx.x;
    int tid = threadIdx.x, h = tid >> 6, ln = tid & 63;
    const float scale = 0.0721687836f;  // 1/sqrt(192)
    float s = -1e30f;
    {
        int j = (ln < 32) ? ln : 0;
        const float* qr = qc + (size_t)u * 768 + h * 192;
        const float* kr = kv + ((size_t)u * 32 + j) * 1536 + h * 192;
        float a = 0.f;
#pragma unroll 8
        for (int d = 0; d < 192; ++d) a += qr[d] * kr[d];
        if (ln < 32) s = a * scale;
    }
    float m = s;
#pragma unroll
    for (int mk = 32; mk >= 1; mk >>= 1) m = fmaxf(m, __shfl_xor(m, mk));
    float e = (ln < 32) ? __expf(s - m) : 0.f;
    float z = e;
#pragma unroll
    for (int mk = 32; mk >= 1; mk >>= 1) z += __shfl_xor(z, mk);
    __shared__ float pbuf[4][32];
    if (ln < 32) pbuf[h][ln] = e / z;
    __syncthreads();
    float a0 = 0.f, a1 = 0.f, a2 = 0.f;
    for (int j = 0; j < 32; ++j) {
        const float* vr = kv + ((size_t)u * 32 + j) * 1536 + 768 + h * 192;
        float p = pbuf[h][j];
        a0 += p * vr[ln]; a1 += p * vr[ln + 64]; a2 += p * vr[ln + 128];
    }
    float* o = out0 + (size_t)u * 768 + h * 192;
    o[ln] = a0; o[ln + 64] = a1; o[ln + 128] = a2;
}

// ---------- last-wins winner + scatter ----------
__global__ void winner_kernel(const int* __restrict__ nbidx, int* __restrict__ slot, int U)
{
    int u = blockIdx.x * 256 + threadIdx.x;
    if (u < U) atomicMax(&slot[nbidx[(size_t)u * 32]], u);
}
__global__ __launch_bounds__(256) void scatter_kernel(
    const float* __restrict__ proj, const int* __restrict__ nbidx,
    const int* __restrict__ slot, float* __restrict__ feats)
{
    int u = blockIdx.x;
    int c = nbidx[(size_t)u * 32];
    if (slot[c] != u) return;
    const float* src = proj + (size_t)u * 768;
    float* dst = feats + (size_t)c * 768;
    for (int t = threadIdx.x; t < 768; t += 256) dst[t] = src[t];
}

extern "C" void kernel_launch(void* const* d_in, const int* in_sizes, int n_in,
                              void* d_out, int out_size, void* d_ws, size_t ws_size,
                              hipStream_t stream)
{
    const float* user_text = (const float*)d_in[0];
    const float* auf       = (const float*)d_in[1];
    const int*   nbidx     = (const int*)d_in[2];
    const int*   ei        = (const int*)d_in[3];
    const float* Wqkv_l = (const float*)d_in[4];
    const float* bqkv_l = (const float*)d_in[5];
    const float* Wo_l   = (const float*)d_in[6];
    const float* bo_l   = (const float*)d_in[7];
    const float* ln1_g  = (const float*)d_in[8];
    const float* ln1_b  = (const float*)d_in[9];
    const float* ln2_g  = (const float*)d_in[10];
    const float* ln2_b  = (const float*)d_in[11];
    const float* W1 = (const float*)d_in[12];
    const float* b1 = (const float*)d_in[13];
    const float* W2 = (const float*)d_in[14];
    const float* b2 = (const float*)d_in[15];
    const float* Wg = (const float*)d_in[16];
    const float* bg = (const float*)d_in[17];
    const float* Wqkv_m = (const float*)d_in[18];
    const float* bqkv_m = (const float*)d_in[19];
    const float* Wo_m   = (const float*)d_in[20];
    const float* bo_m   = (const float*)d_in[21];

    const int D  = 768;
    const int BS = in_sizes[0] / D;    // 1008
    const int B  = BS / 126;           // 8
    const int N  = in_sizes[1] / D;    // 100000
    const int U  = in_sizes[2] / 32;   // 1024
    const int E  = in_sizes[3] / 2;    // 1600000
    const int UK = U * 32;             // 32768

    float* out_text  = (float*)d_out;
    const int TEXTN = BS * D;
    const int WG_T = (TEXTN + 255) / 256;
    float* out_feats = out_text + (size_t)TEXTN;
    float* out_pool  = out_feats + (size_t)N * D;

    char* ws = (char*)d_ws;
    size_t off = 0;
    auto take = [&](size_t bytes) -> void* {
        void* p = ws + off;
        off += (bytes + 255) & ~(size_t)255;
        return p;
    };
    float* A_h    = (float*)take((size_t)N * D * 4);      // h; reused as kv [UK][1536]
    float* qkvl   = (float*)take((size_t)BS * 2304 * 4);
    float* ln1x   = (float*)take((size_t)BS * D * 4);
    float* attnout= (float*)take((size_t)BS * D * 4);
    float* text1  = (float*)take((size_t)BS * D * 4);
    float* ln2x   = (float*)take((size_t)BS * D * 4);
    float* qc     = (float*)take((size_t)U * D * 4);
    float* out0   = (float*)take((size_t)U * D * 4);
    float* projm  = (float*)take((size_t)U * D * 4);
    int*   cnt    = (int*)take((size_t)N * 4);
    float* dsc    = (float*)take((size_t)N * 4);
    int*   slot   = (int*)take((size_t)N * 4);
    int*   bucket = (int*)take((size_t)N * 64 * 4);
    float* pooled = (float*)take((size_t)B * 36 * 4);
    float* hmid   = ln1x;     // alias (ln1x dead after qkv gemm)
    float* kv     = A_h;      // alias (h dead after aggregation); UK*1536 <= N*768
    size_t required = off;

    if (ws_size < required) {
        code_write_f32<<<WG_T, 256, 0, stream>>>(out_text, TEXTN,
            1.0e6f + (float)(ws_size >> 20) * 1000.0f);
        return;
    }

    hipMemsetAsync(cnt, 0, (size_t)N * 4, stream);
    hipMemsetAsync(slot, 0xFF, (size_t)N * 4, stream);
    hipMemsetAsync(pooled, 0, (size_t)B * 36 * 4, stream);

    // --- GCN prep ---
    deg_fill_kernel<<<(E + 255) / 256, 256, 0, stream>>>(ei, E, cnt, bucket);
    dinv_kernel<<<(N + 255) / 256, 256, 0, stream>>>(cnt, dsc, N);

    // --- text path: exact f32 (passes; small) ---
    ln_kernel<<<BS, 256, 0, stream>>>(user_text, ln1_g, ln1_b, ln1x);
    ngemm<<<dim3(BS, 9), 256, 0, stream>>>(ln1x, Wqkv_l, bqkv_l, qkvl, nullptr, BS, 2304, 0);
    nattn<<<BS, 256, 0, stream>>>(qkvl, attnout, pooled);
    ngemm<<<dim3(BS, 3), 256, 0, stream>>>(attnout, Wo_l, bo_l, text1, user_text, BS, 768, 0);
    ln_kernel<<<BS, 256, 0, stream>>>(text1, ln2_g, ln2_b, ln2x);
    ngemm<<<dim3(BS, 3), 256, 0, stream>>>(ln2x, W1, b1, hmid, nullptr, BS, 768, 1);
    ngemm<<<dim3(BS, 3), 256, 0, stream>>>(hmid, W2, b2, out_text, text1, BS, 768, 0);
    pool_fin_kernel<<<B, 36, 0, stream>>>(pooled, out_pool);

    // --- feats: standard rsqrt GCN; h-GEMM now MFMA (was 28.9 ms naive) ---
    gemm_bt<<<dim3((N + 127) / 128, 6), 256, 0, stream>>>(
        auf, Wg, nullptr, A_h, nullptr, N, 768);
    gcn_agg_f32<<<N, 256, 0, stream>>>(A_h, bucket, cnt, dsc, bg, out_feats);

    // --- MultiAttn on neighborhoods, write back center rows (last-wins) ---
    winner_kernel<<<(U + 255) / 256, 256, 0, stream>>>(nbidx, slot, U);
    // K,V for all 32768 gathered rows — MFMA with row gather (was ~19 ms naive)
    gemm_bt<<<dim3(UK / 128, 1536 / 128), 256, 0, stream>>>(
        out_feats, Wqkv_m + (size_t)768 * 768, bqkv_m + 768, kv, nbidx, UK, 1536);
    // Q for the 1024 center rows (small, naive)
    ngemm_gather<<<dim3(U, 3), 256, 0, stream>>>(
        out_feats, nbidx, 32, Wqkv_m, bqkv_m, qc, 768);
    attn_m_kernel<<<U, 256, 0, stream>>>(kv, qc, out0);
    ngemm<<<dim3(U, 3), 256, 0, stream>>>(out0, Wo_m, bo_m, projm, nullptr, U, 768, 0);
    scatter_kernel<<<U, 256, 0, stream>>>(projm, nbidx, slot, out_feats);
}

// Round 16
// 2651.463 us; speedup vs baseline: 19.5843x; 1.8448x over previous
//
#include <hip/hip_runtime.h>
#include <stdint.h>

typedef __attribute__((ext_vector_type(8))) short short8;
typedef __attribute__((ext_vector_type(4))) float f32x4;

__device__ __forceinline__ uint16_t f2bf(float f) {
    union { float f; uint32_t i; } v; v.f = f;
    uint32_t r = v.i + 0x7fffu + ((v.i >> 16) & 1u);
    return (uint16_t)(r >> 16);
}
__device__ __forceinline__ short8 cvt8(const float* p) {
    f32x4 a = *(const f32x4*)p;
    f32x4 b = *(const f32x4*)(p + 4);
    short8 r;
    r[0] = (short)f2bf(a[0]); r[1] = (short)f2bf(a[1]);
    r[2] = (short)f2bf(a[2]); r[3] = (short)f2bf(a[3]);
    r[4] = (short)f2bf(b[0]); r[5] = (short)f2bf(b[1]);
    r[6] = (short)f2bf(b[2]); r[7] = (short)f2bf(b[3]);
    return r;
}

__global__ void code_write_f32(float* __restrict__ out, int n, float codef)
{
    int i = blockIdx.x * 256 + threadIdx.x;
    if (i < n) out[i] = codef;
}

// ---------- MFMA GEMM: C[M,N] = A[rowmap?][768] @ W[N,768]^T + bias (+R)(leaky) ----------
__global__ __launch_bounds__(256) void gemm_bt(
    const float* __restrict__ A, const float* __restrict__ W,
    const float* __restrict__ bias, float* __restrict__ C,
    const float* __restrict__ R, const int* __restrict__ rowmap, int rstride,
    int M, int N, int act)
{
    __shared__ __attribute__((aligned(16))) uint16_t As[4096];  // [128][32] bf16
    __shared__ __attribute__((aligned(16))) uint16_t Ws[4096];
    const int K = 768;
    int tid = threadIdx.x, wv = tid >> 6, ln = tid & 63;
    int bm = blockIdx.x, bn = blockIdx.y;
    int wm = wv >> 1, wn = wv & 1;

    const f32x4 zero4 = {0.f, 0.f, 0.f, 0.f};
    f32x4 acc[4][4];
#pragma unroll
    for (int i = 0; i < 4; ++i)
#pragma unroll
        for (int j = 0; j < 4; ++j) acc[i][j] = zero4;

    int r0 = tid >> 2, c8 = (tid & 3) * 8;
    int r1 = r0 + 64;
    int ar0 = min(bm * 128 + r0, M - 1);
    int ar1 = min(bm * 128 + r1, M - 1);
    if (rowmap) { ar0 = rowmap[(size_t)ar0 * rstride]; ar1 = rowmap[(size_t)ar1 * rstride]; }
    int br0 = bn * 128 + r0, br1 = bn * 128 + r1;
    const float* Af0 = A + (size_t)ar0 * K + c8;
    const float* Af1 = A + (size_t)ar1 * K + c8;
    const float* Wf0 = W + (size_t)br0 * K + c8;
    const float* Wf1 = W + (size_t)br1 * K + c8;
    const int s0 = tid * 8;
    const int s1 = 2048 + tid * 8;
    const int lr = ln & 15, kg = ln >> 4;

    for (int k0 = 0; k0 < K; k0 += 32) {
        short8 a0 = cvt8(Af0 + k0);
        short8 a1 = cvt8(Af1 + k0);
        short8 w0 = cvt8(Wf0 + k0);
        short8 w1 = cvt8(Wf1 + k0);
        __syncthreads();
        *(short8*)&As[s0] = a0;
        *(short8*)&As[s1] = a1;
        *(short8*)&Ws[s0] = w0;
        *(short8*)&Ws[s1] = w1;
        __syncthreads();
        short8 afr[4], bfr[4];
#pragma unroll
        for (int mi = 0; mi < 4; ++mi)
            afr[mi] = *(const short8*)&As[(wm * 64 + mi * 16 + lr) * 32 + kg * 8];
#pragma unroll
        for (int nj = 0; nj < 4; ++nj)
            bfr[nj] = *(const short8*)&Ws[(wn * 64 + nj * 16 + lr) * 32 + kg * 8];
#pragma unroll
        for (int mi = 0; mi < 4; ++mi)
#pragma unroll
            for (int nj = 0; nj < 4; ++nj)
                acc[mi][nj] = __builtin_amdgcn_mfma_f32_16x16x32_bf16(
                    afr[mi], bfr[nj], acc[mi][nj], 0, 0, 0);
    }

#pragma unroll
    for (int mi = 0; mi < 4; ++mi) {
        int growb = bm * 128 + wm * 64 + mi * 16 + kg * 4;
#pragma unroll
        for (int nj = 0; nj < 4; ++nj) {
            int gcol = bn * 128 + wn * 64 + nj * 16 + lr;
            float bs = bias ? bias[gcol] : 0.f;
#pragma unroll
            for (int q = 0; q < 4; ++q) {
                int grow = growb + q;
                if (grow < M) {
                    float val = acc[mi][nj][q] + bs;
                    if (R) val += R[(size_t)grow * N + gcol];
                    if (act == 1) val = (val > 0.f) ? val : 0.01f * val;
                    C[(size_t)grow * N + gcol] = val;
                }
            }
        }
    }
}

// ---------- LayerNorm (f32) ----------
__global__ __launch_bounds__(256) void ln_kernel(
    const float* __restrict__ x, const float* __restrict__ g,
    const float* __restrict__ bb, float* __restrict__ y)
{
    int row = blockIdx.x, tid = threadIdx.x;
    const float* xr = x + (size_t)row * 768;
    float v0 = xr[tid], v1 = xr[tid + 256], v2 = xr[tid + 512];
    float s = v0 + v1 + v2;
    __shared__ float red[4];
#pragma unroll
    for (int mk = 32; mk >= 1; mk >>= 1) s += __shfl_xor(s, mk);
    int wv = tid >> 6, ln = tid & 63;
    if (ln == 0) red[wv] = s;
    __syncthreads();
    float mu = (red[0] + red[1] + red[2] + red[3]) * (1.f / 768.f);
    float d0 = v0 - mu, d1 = v1 - mu, d2 = v2 - mu;
    float ss = d0 * d0 + d1 * d1 + d2 * d2;
#pragma unroll
    for (int mk = 32; mk >= 1; mk >>= 1) ss += __shfl_xor(ss, mk);
    __syncthreads();
    if (ln == 0) red[wv] = ss;
    __syncthreads();
    float var = (red[0] + red[1] + red[2] + red[3]) * (1.f / 768.f);
    float inv = 1.0f / sqrtf(var + 1e-5f);
    float* yr = y + (size_t)row * 768;
    yr[tid]       = d0 * inv * g[tid]       + bb[tid];
    yr[tid + 256] = d1 * inv * g[tid + 256] + bb[tid + 256];
    yr[tid + 512] = d2 * inv * g[tid + 512] + bb[tid + 512];
}

// ---------- naive exact text attention; one block per (b,i) ----------
__global__ __launch_bounds__(256) void nattn(
    const float* __restrict__ qkv, float* __restrict__ attnout,
    float* __restrict__ pooled)
{
    int b = blockIdx.x / 126, i = blockIdx.x % 126;
    int tid = threadIdx.x;
    __shared__ float sc[128];
    __shared__ float srz;
    const size_t base = (size_t)b * 126 * 2304;
    const float scale = 0.0721687836f;  // 1/sqrt(192)
    for (int h = 0; h < 4; ++h) {
        if (tid < 126) {
            const float* qr = qkv + base + (size_t)i * 2304 + h * 192;
            const float* kr = qkv + base + (size_t)tid * 2304 + 768 + h * 192;
            float a = 0.f;
#pragma unroll 8
            for (int d = 0; d < 192; ++d) a += qr[d] * kr[d];
            sc[tid] = a * scale;
        }
        __syncthreads();
        if (tid == 0) {
            float m = -1e30f;
            for (int j = 0; j < 126; ++j) m = fmaxf(m, sc[j]);
            float z = 0.f;
            for (int j = 0; j < 126; ++j) { sc[j] = __expf(sc[j] - m); z += sc[j]; }
            srz = 1.f / z;
        }
        __syncthreads();
        float rz = srz;
        if (tid < 192) {
            float o = 0.f;
            for (int j = 0; j < 126; ++j)
                o += sc[j] * rz * qkv[base + (size_t)j * 2304 + 1536 + h * 192 + tid];
            attnout[(size_t)(b * 126 + i) * 768 + h * 192 + tid] = o;
        }
        if (tid < 126)
            atomicAdd(&pooled[b * 36 + (i / 21) * 6 + tid / 21], sc[tid] * rz);
        __syncthreads();
    }
}

__global__ void pool_fin_kernel(const float* __restrict__ pooled, float* __restrict__ outp)
{
    int i = blockIdx.x * 36 + threadIdx.x;
    outp[i] = pooled[i] * (1.0f / 1764.0f);  // /4 heads /441 cells
}

// ---------- GCN prep ----------
__global__ void deg_fill_kernel(const int* __restrict__ ei, int E,
                                int* __restrict__ cnt, int* __restrict__ bucket)
{
    int e = blockIdx.x * 256 + threadIdx.x;
    if (e < E) {
        int s = ei[e], d = ei[E + e];
        int p = atomicAdd(&cnt[d], 1);
        if (p < 64) bucket[(size_t)d * 64 + p] = s;
    }
}
__global__ void dinv_kernel(const int* __restrict__ cnt, float* __restrict__ ds, int N)
{
    int i = blockIdx.x * 256 + threadIdx.x;
    if (i < N) ds[i] = 1.0f / sqrtf((float)cnt[i] + 1.0f);
}

// feats[v] = dinv[v]*( sum_src dinv[s]*h[s] + dinv[v]*h[v] ) + bg   (full f32)
__global__ __launch_bounds__(256) void gcn_agg_f32(
    const float* __restrict__ h, const int* __restrict__ bucket,
    const int* __restrict__ cnt, const float* __restrict__ dsc,
    const float* __restrict__ bg, float* __restrict__ feats)
{
    int v = blockIdx.x;
    int tid = threadIdx.x;
    const float* hv = h + (size_t)v * 768;
    float sv = dsc[v];
    float a0 = hv[tid] * sv, a1 = hv[tid + 256] * sv, a2 = hv[tid + 512] * sv;
    int nb = min(cnt[v], 64);
    for (int e = 0; e < nb; ++e) {
        int s = bucket[(size_t)v * 64 + e];
        const float* hs = h + (size_t)s * 768;
        float ss = dsc[s];
        a0 += hs[tid] * ss; a1 += hs[tid + 256] * ss; a2 += hs[tid + 512] * ss;
    }
    float* o = feats + (size_t)v * 768;
    o[tid]       = a0 * sv + bg[tid];
    o[tid + 256] = a1 * sv + bg[tid + 256];
    o[tid + 512] = a2 * sv + bg[tid + 512];
}

// ---------- MultiAttn: 1 query (center row) x 32 keys ----------
__global__ __launch_bounds__(256) void attn_m_kernel(
    const float* __restrict__ kv, const float* __restrict__ qc,
    float* __restrict__ out0)
{
    int u = blockIdx.x;
    int tid = threadIdx.x, h = tid >> 6, ln = tid & 63;
    const float scale = 0.0721687836f;  // 1/sqrt(192)
    float s = -1e30f;
    {
        int j = (ln < 32) ? ln : 0;
        const float* qr = qc + (size_t)u * 768 + h * 192;
        const float* kr = kv + ((size_t)u * 32 + j) * 1536 + h * 192;
        float a = 0.f;
#pragma unroll 8
        for (int d = 0; d < 192; ++d) a += qr[d] * kr[d];
        if (ln < 32) s = a * scale;
    }
    float m = s;
#pragma unroll
    for (int mk = 32; mk >= 1; mk >>= 1) m = fmaxf(m, __shfl_xor(m, mk));
    float e = (ln < 32) ? __expf(s - m) : 0.f;
    float z = e;
#pragma unroll
    for (int mk = 32; mk >= 1; mk >>= 1) z += __shfl_xor(z, mk);
    __shared__ float pbuf[4][32];
    if (ln < 32) pbuf[h][ln] = e / z;
    __syncthreads();
    float a0 = 0.f, a1 = 0.f, a2 = 0.f;
    for (int j = 0; j < 32; ++j) {
        const float* vr = kv + ((size_t)u * 32 + j) * 1536 + 768 + h * 192;
        float p = pbuf[h][j];
        a0 += p * vr[ln]; a1 += p * vr[ln + 64]; a2 += p * vr[ln + 128];
    }
    float* o = out0 + (size_t)u * 768 + h * 192;
    o[ln] = a0; o[ln + 64] = a1; o[ln + 128] = a2;
}

// ---------- last-wins winner + scatter ----------
__global__ void winner_kernel(const int* __restrict__ nbidx, int* __restrict__ slot, int U)
{
    int u = blockIdx.x * 256 + threadIdx.x;
    if (u < U) atomicMax(&slot[nbidx[(size_t)u * 32]], u);
}
__global__ __launch_bounds__(256) void scatter_kernel(
    const float* __restrict__ proj, const int* __restrict__ nbidx,
    const int* __restrict__ slot, float* __restrict__ feats)
{
    int u = blockIdx.x;
    int c = nbidx[(size_t)u * 32];
    if (slot[c] != u) return;
    const float* src = proj + (size_t)u * 768;
    float* dst = feats + (size_t)c * 768;
    for (int t = threadIdx.x; t < 768; t += 256) dst[t] = src[t];
}

extern "C" void kernel_launch(void* const* d_in, const int* in_sizes, int n_in,
                              void* d_out, int out_size, void* d_ws, size_t ws_size,
                              hipStream_t stream)
{
    const float* user_text = (const float*)d_in[0];
    const float* auf       = (const float*)d_in[1];
    const int*   nbidx     = (const int*)d_in[2];
    const int*   ei        = (const int*)d_in[3];
    const float* Wqkv_l = (const float*)d_in[4];
    const float* bqkv_l = (const float*)d_in[5];
    const float* Wo_l   = (const float*)d_in[6];
    const float* bo_l   = (const float*)d_in[7];
    const float* ln1_g  = (const float*)d_in[8];
    const float* ln1_b  = (const float*)d_in[9];
    const float* ln2_g  = (const float*)d_in[10];
    const float* ln2_b  = (const float*)d_in[11];
    const float* W1 = (const float*)d_in[12];
    const float* b1 = (const float*)d_in[13];
    const float* W2 = (const float*)d_in[14];
    const float* b2 = (const float*)d_in[15];
    const float* Wg = (const float*)d_in[16];
    const float* bg = (const float*)d_in[17];
    const float* Wqkv_m = (const float*)d_in[18];
    const float* bqkv_m = (const float*)d_in[19];
    const float* Wo_m   = (const float*)d_in[20];
    const float* bo_m   = (const float*)d_in[21];

    const int D  = 768;
    const int BS = in_sizes[0] / D;    // 1008
    const int B  = BS / 126;           // 8
    const int N  = in_sizes[1] / D;    // 100000
    const int U  = in_sizes[2] / 32;   // 1024
    const int E  = in_sizes[3] / 2;    // 1600000
    const int UK = U * 32;             // 32768

    float* out_text  = (float*)d_out;
    const int TEXTN = BS * D;
    const int WG_T = (TEXTN + 255) / 256;
    float* out_feats = out_text + (size_t)TEXTN;
    float* out_pool  = out_feats + (size_t)N * D;

    char* ws = (char*)d_ws;
    size_t off = 0;
    auto take = [&](size_t bytes) -> void* {
        void* p = ws + off;
        off += (bytes + 255) & ~(size_t)255;
        return p;
    };
    float* A_h    = (float*)take((size_t)N * D * 4);      // h; reused as kv [UK][1536]
    float* qkvl   = (float*)take((size_t)BS * 2304 * 4);
    float* ln1x   = (float*)take((size_t)BS * D * 4);
    float* attnout= (float*)take((size_t)BS * D * 4);
    float* text1  = (float*)take((size_t)BS * D * 4);
    float* ln2x   = (float*)take((size_t)BS * D * 4);
    float* qc     = (float*)take((size_t)U * D * 4);
    float* out0   = (float*)take((size_t)U * D * 4);
    float* projm  = (float*)take((size_t)U * D * 4);
    int*   cnt    = (int*)take((size_t)N * 4);
    float* dsc    = (float*)take((size_t)N * 4);
    int*   slot   = (int*)take((size_t)N * 4);
    int*   bucket = (int*)take((size_t)N * 64 * 4);
    float* pooled = (float*)take((size_t)B * 36 * 4);
    float* hmid   = ln1x;     // alias (ln1x dead after qkv gemm)
    float* kv     = A_h;      // alias (h dead after aggregation); UK*1536 <= N*768
    size_t required = off;

    if (ws_size < required) {
        code_write_f32<<<WG_T, 256, 0, stream>>>(out_text, TEXTN,
            1.0e6f + (float)(ws_size >> 20) * 1000.0f);
        return;
    }

    hipMemsetAsync(cnt, 0, (size_t)N * 4, stream);
    hipMemsetAsync(slot, 0xFF, (size_t)N * 4, stream);
    hipMemsetAsync(pooled, 0, (size_t)B * 36 * 4, stream);

    // --- GCN prep ---
    deg_fill_kernel<<<(E + 255) / 256, 256, 0, stream>>>(ei, E, cnt, bucket);
    dinv_kernel<<<(N + 255) / 256, 256, 0, stream>>>(cnt, dsc, N);

    const int BMT = (BS + 127) / 128;   // 8 row-tiles for text
    // --- text path: all GEMMs via MFMA now ---
    ln_kernel<<<BS, 256, 0, stream>>>(user_text, ln1_g, ln1_b, ln1x);
    gemm_bt<<<dim3(BMT, 18), 256, 0, stream>>>(
        ln1x, Wqkv_l, bqkv_l, qkvl, nullptr, nullptr, 1, BS, 2304, 0);
    nattn<<<BS, 256, 0, stream>>>(qkvl, attnout, pooled);
    gemm_bt<<<dim3(BMT, 6), 256, 0, stream>>>(
        attnout, Wo_l, bo_l, text1, user_text, nullptr, 1, BS, 768, 0);
    ln_kernel<<<BS, 256, 0, stream>>>(text1, ln2_g, ln2_b, ln2x);
    gemm_bt<<<dim3(BMT, 6), 256, 0, stream>>>(
        ln2x, W1, b1, hmid, nullptr, nullptr, 1, BS, 768, 1);
    gemm_bt<<<dim3(BMT, 6), 256, 0, stream>>>(
        hmid, W2, b2, out_text, text1, nullptr, 1, BS, 768, 0);
    pool_fin_kernel<<<B, 36, 0, stream>>>(pooled, out_pool);

    // --- feats: standard rsqrt GCN; MFMA GEMM ---
    gemm_bt<<<dim3((N + 127) / 128, 6), 256, 0, stream>>>(
        auf, Wg, nullptr, A_h, nullptr, nullptr, 1, N, 768, 0);
    gcn_agg_f32<<<N, 256, 0, stream>>>(A_h, bucket, cnt, dsc, bg, out_feats);

    // --- MultiAttn on neighborhoods, write back center rows (last-wins) ---
    winner_kernel<<<(U + 255) / 256, 256, 0, stream>>>(nbidx, slot, U);
    // K,V for all 32768 gathered rows — MFMA with row gather
    gemm_bt<<<dim3(UK / 128, 12), 256, 0, stream>>>(
        out_feats, Wqkv_m + (size_t)768 * 768, bqkv_m + 768, kv, nullptr, nbidx, 1, UK, 1536, 0);
    // Q for the 1024 center rows — MFMA with stride-32 row gather
    gemm_bt<<<dim3(U / 128, 6), 256, 0, stream>>>(
        out_feats, Wqkv_m, bqkv_m, qc, nullptr, nbidx, 32, U, 768, 0);
    attn_m_kernel<<<U, 256, 0, stream>>>(kv, qc, out0);
    gemm_bt<<<dim3(U / 128, 6), 256, 0, stream>>>(
        out0, Wo_m, bo_m, projm, nullptr, nullptr, 1, U, 768, 0);
    scatter_kernel<<<U, 256, 0, stream>>>(projm, nbidx, slot, out_feats);
}

// Round 17
// 1734.189 us; speedup vs baseline: 29.9431x; 1.5289x over previous
//
#include <hip/hip_runtime.h>
#include <stdint.h>

typedef __attribute__((ext_vector_type(8))) short short8;
typedef __attribute__((ext_vector_type(4))) float f32x4;

__device__ __forceinline__ float bf2f(uint16_t u) {
    union { uint32_t i; float f; } v; v.i = ((uint32_t)u) << 16; return v.f;
}
__device__ __forceinline__ uint16_t f2bf(float f) {
    union { float f; uint32_t i; } v; v.f = f;
    uint32_t r = v.i + 0x7fffu + ((v.i >> 16) & 1u);
    return (uint16_t)(r >> 16);
}
__device__ __forceinline__ short8 cvt8(const float* p) {
    f32x4 a = *(const f32x4*)p;
    f32x4 b = *(const f32x4*)(p + 4);
    short8 r;
    r[0] = (short)f2bf(a[0]); r[1] = (short)f2bf(a[1]);
    r[2] = (short)f2bf(a[2]); r[3] = (short)f2bf(a[3]);
    r[4] = (short)f2bf(b[0]); r[5] = (short)f2bf(b[1]);
    r[6] = (short)f2bf(b[2]); r[7] = (short)f2bf(b[3]);
    return r;
}

__global__ void code_write_f32(float* __restrict__ out, int n, float codef)
{
    int i = blockIdx.x * 256 + threadIdx.x;
    if (i < n) out[i] = codef;
}

// ---------- MFMA GEMM: C[M,N] = A[rowmap?][768] @ W[N,768]^T + bias (+R)(leaky) ----------
// cbf: store C as bf16 (uint16_t*) instead of f32
__global__ __launch_bounds__(256) void gemm_bt(
    const float* __restrict__ A, const float* __restrict__ W,
    const float* __restrict__ bias, void* __restrict__ Cv,
    const float* __restrict__ R, const int* __restrict__ rowmap, int rstride,
    int M, int N, int act, int cbf)
{
    __shared__ __attribute__((aligned(16))) uint16_t As[4096];  // [128][32] bf16
    __shared__ __attribute__((aligned(16))) uint16_t Ws[4096];
    const int K = 768;
    int tid = threadIdx.x, wv = tid >> 6, ln = tid & 63;
    int bm = blockIdx.x, bn = blockIdx.y;
    int wm = wv >> 1, wn = wv & 1;

    const f32x4 zero4 = {0.f, 0.f, 0.f, 0.f};
    f32x4 acc[4][4];
#pragma unroll
    for (int i = 0; i < 4; ++i)
#pragma unroll
        for (int j = 0; j < 4; ++j) acc[i][j] = zero4;

    int r0 = tid >> 2, c8 = (tid & 3) * 8;
    int r1 = r0 + 64;
    int ar0 = min(bm * 128 + r0, M - 1);
    int ar1 = min(bm * 128 + r1, M - 1);
    if (rowmap) { ar0 = rowmap[(size_t)ar0 * rstride]; ar1 = rowmap[(size_t)ar1 * rstride]; }
    int br0 = bn * 128 + r0, br1 = bn * 128 + r1;
    const float* Af0 = A + (size_t)ar0 * K + c8;
    const float* Af1 = A + (size_t)ar1 * K + c8;
    const float* Wf0 = W + (size_t)br0 * K + c8;
    const float* Wf1 = W + (size_t)br1 * K + c8;
    const int s0 = tid * 8;
    const int s1 = 2048 + tid * 8;
    const int lr = ln & 15, kg = ln >> 4;

    for (int k0 = 0; k0 < K; k0 += 32) {
        short8 a0 = cvt8(Af0 + k0);
        short8 a1 = cvt8(Af1 + k0);
        short8 w0 = cvt8(Wf0 + k0);
        short8 w1 = cvt8(Wf1 + k0);
        __syncthreads();
        *(short8*)&As[s0] = a0;
        *(short8*)&As[s1] = a1;
        *(short8*)&Ws[s0] = w0;
        *(short8*)&Ws[s1] = w1;
        __syncthreads();
        short8 afr[4], bfr[4];
#pragma unroll
        for (int mi = 0; mi < 4; ++mi)
            afr[mi] = *(const short8*)&As[(wm * 64 + mi * 16 + lr) * 32 + kg * 8];
#pragma unroll
        for (int nj = 0; nj < 4; ++nj)
            bfr[nj] = *(const short8*)&Ws[(wn * 64 + nj * 16 + lr) * 32 + kg * 8];
#pragma unroll
        for (int mi = 0; mi < 4; ++mi)
#pragma unroll
            for (int nj = 0; nj < 4; ++nj)
                acc[mi][nj] = __builtin_amdgcn_mfma_f32_16x16x32_bf16(
                    afr[mi], bfr[nj], acc[mi][nj], 0, 0, 0);
    }

#pragma unroll
    for (int mi = 0; mi < 4; ++mi) {
        int growb = bm * 128 + wm * 64 + mi * 16 + kg * 4;
#pragma unroll
        for (int nj = 0; nj < 4; ++nj) {
            int gcol = bn * 128 + wn * 64 + nj * 16 + lr;
            float bs = bias ? bias[gcol] : 0.f;
#pragma unroll
            for (int q = 0; q < 4; ++q) {
                int grow = growb + q;
                if (grow < M) {
                    float val = acc[mi][nj][q] + bs;
                    if (R) val += R[(size_t)grow * N + gcol];
                    if (act == 1) val = (val > 0.f) ? val : 0.01f * val;
                    size_t idx = (size_t)grow * N + gcol;
                    if (cbf) ((uint16_t*)Cv)[idx] = f2bf(val);
                    else     ((float*)Cv)[idx]    = val;
                }
            }
        }
    }
}

// ---------- LayerNorm (f32) ----------
__global__ __launch_bounds__(256) void ln_kernel(
    const float* __restrict__ x, const float* __restrict__ g,
    const float* __restrict__ bb, float* __restrict__ y)
{
    int row = blockIdx.x, tid = threadIdx.x;
    const float* xr = x + (size_t)row * 768;
    float v0 = xr[tid], v1 = xr[tid + 256], v2 = xr[tid + 512];
    float s = v0 + v1 + v2;
    __shared__ float red[4];
#pragma unroll
    for (int mk = 32; mk >= 1; mk >>= 1) s += __shfl_xor(s, mk);
    int wv = tid >> 6, ln = tid & 63;
    if (ln == 0) red[wv] = s;
    __syncthreads();
    float mu = (red[0] + red[1] + red[2] + red[3]) * (1.f / 768.f);
    float d0 = v0 - mu, d1 = v1 - mu, d2 = v2 - mu;
    float ss = d0 * d0 + d1 * d1 + d2 * d2;
#pragma unroll
    for (int mk = 32; mk >= 1; mk >>= 1) ss += __shfl_xor(ss, mk);
    __syncthreads();
    if (ln == 0) red[wv] = ss;
    __syncthreads();
    float var = (red[0] + red[1] + red[2] + red[3]) * (1.f / 768.f);
    float inv = 1.0f / sqrtf(var + 1e-5f);
    float* yr = y + (size_t)row * 768;
    yr[tid]       = d0 * inv * g[tid]       + bb[tid];
    yr[tid + 256] = d1 * inv * g[tid + 256] + bb[tid + 256];
    yr[tid + 512] = d2 * inv * g[tid + 512] + bb[tid + 512];
}

// ---------- wave-parallel text attention; one block per (b,i) ----------
__global__ __launch_bounds__(256) void nattn(
    const float* __restrict__ qkv, float* __restrict__ attnout,
    float* __restrict__ pooled)
{
    int b = blockIdx.x / 126, i = blockIdx.x % 126;
    int tid = threadIdx.x;
    __shared__ float P[4][128];
    __shared__ float poolloc[6];
    if (tid < 6) poolloc[tid] = 0.f;
    const size_t base = (size_t)b * 126 * 2304;
    const float scale = 0.0721687836f;  // 1/sqrt(192)

    // Phase 1: scores — 504 jobs (h,j) over 256 threads
    for (int p = tid; p < 504; p += 256) {
        int h = p / 126, j = p - h * 126;
        const float* qr = qkv + base + (size_t)i * 2304 + h * 192;
        const float* kr = qkv + base + (size_t)j * 2304 + 768 + h * 192;
        float a = 0.f;
#pragma unroll 8
        for (int d = 0; d < 192; ++d) a += qr[d] * kr[d];
        P[h][j] = a * scale;
    }
    __syncthreads();

    // Phase 2: per-head softmax — wave w handles head w
    {
        int w = tid >> 6, ln = tid & 63;
        bool v1 = (ln + 64) < 126;
        float s0 = P[w][ln];
        float s1 = v1 ? P[w][ln + 64] : -1e30f;
        float m = fmaxf(s0, s1);
#pragma unroll
        for (int mk = 32; mk >= 1; mk >>= 1) m = fmaxf(m, __shfl_xor(m, mk));
        float e0 = __expf(s0 - m);
        float e1 = v1 ? __expf(s1 - m) : 0.f;
        float z = e0 + e1;
#pragma unroll
        for (int mk = 32; mk >= 1; mk >>= 1) z += __shfl_xor(z, mk);
        float rz = 1.f / z;
        P[w][ln] = e0 * rz;
        if (v1) P[w][ln + 64] = e1 * rz;
    }
    __syncthreads();

    // Pool: sum heads per key, LDS-atomic into 6 cells
    if (tid < 126) {
        float s4 = P[0][tid] + P[1][tid] + P[2][tid] + P[3][tid];
        atomicAdd(&poolloc[tid / 21], s4);
    }

    // Phase 3: PV — 768 coalesced output dims over 256 threads
    float o[3];
#pragma unroll
    for (int r = 0; r < 3; ++r) {
        int od = tid + r * 256;
        int h = od / 192;
        float a = 0.f;
        for (int j = 0; j < 126; ++j)
            a += P[h][j] * qkv[base + (size_t)j * 2304 + 1536 + od];
        o[r] = a;
    }
    float* orow = attnout + (size_t)(b * 126 + i) * 768;
#pragma unroll
    for (int r = 0; r < 3; ++r) orow[tid + r * 256] = o[r];

    __syncthreads();
    if (tid < 6)
        atomicAdd(&pooled[b * 36 + (i / 21) * 6 + tid], poolloc[tid]);
}

__global__ void pool_fin_kernel(const float* __restrict__ pooled, float* __restrict__ outp)
{
    int i = blockIdx.x * 36 + threadIdx.x;
    outp[i] = pooled[i] * (1.0f / 1764.0f);  // /4 heads /441 cells
}

// ---------- GCN prep ----------
__global__ void deg_fill_kernel(const int* __restrict__ ei, int E,
                                int* __restrict__ cnt, int* __restrict__ bucket)
{
    int e = blockIdx.x * 256 + threadIdx.x;
    if (e < E) {
        int s = ei[e], d = ei[E + e];
        int p = atomicAdd(&cnt[d], 1);
        if (p < 64) bucket[(size_t)d * 64 + p] = s;
    }
}
__global__ void dinv_kernel(const int* __restrict__ cnt, float* __restrict__ ds, int N)
{
    int i = blockIdx.x * 256 + threadIdx.x;
    if (i < N) ds[i] = 1.0f / sqrtf((float)cnt[i] + 1.0f);
}

// feats[v] = dinv[v]*( sum_src dinv[s]*h[s] + dinv[v]*h[v] ) + bg ; h in bf16
__global__ __launch_bounds__(256) void gcn_agg(
    const uint16_t* __restrict__ h, const int* __restrict__ bucket,
    const int* __restrict__ cnt, const float* __restrict__ dsc,
    const float* __restrict__ bg, float* __restrict__ feats)
{
    int v = blockIdx.x;
    int tid = threadIdx.x;
    const uint16_t* hv = h + (size_t)v * 768;
    float sv = dsc[v];
    float a0 = bf2f(hv[tid]) * sv, a1 = bf2f(hv[tid + 256]) * sv, a2 = bf2f(hv[tid + 512]) * sv;
    int nb = min(cnt[v], 64);
    for (int e = 0; e < nb; ++e) {
        int s = bucket[(size_t)v * 64 + e];
        const uint16_t* hs = h + (size_t)s * 768;
        float ss = dsc[s];
        a0 += bf2f(hs[tid]) * ss; a1 += bf2f(hs[tid + 256]) * ss; a2 += bf2f(hs[tid + 512]) * ss;
    }
    float* o = feats + (size_t)v * 768;
    o[tid]       = a0 * sv + bg[tid];
    o[tid + 256] = a1 * sv + bg[tid + 256];
    o[tid + 512] = a2 * sv + bg[tid + 512];
}

// ---------- MultiAttn: 1 query (center row) x 32 keys ----------
__global__ __launch_bounds__(256) void attn_m_kernel(
    const float* __restrict__ kv, const float* __restrict__ qc,
    float* __restrict__ out0)
{
    int u = blockIdx.x;
    int tid = threadIdx.x, h = tid >> 6, ln = tid & 63;
    const float scale = 0.0721687836f;  // 1/sqrt(192)
    float s = -1e30f;
    {
        int j = (ln < 32) ? ln : 0;
        const float* qr = qc + (size_t)u * 768 + h * 192;
        const float* kr = kv + ((size_t)u * 32 + j) * 1536 + h * 192;
        float a = 0.f;
#pragma unroll 8
        for (int d = 0; d < 192; ++d) a += qr[d] * kr[d];
        if (ln < 32) s = a * scale;
    }
    float m = s;
#pragma unroll
    for (int mk = 32; mk >= 1; mk >>= 1) m = fmaxf(m, __shfl_xor(m, mk));
    float e = (ln < 32) ? __expf(s - m) : 0.f;
    float z = e;
#pragma unroll
    for (int mk = 32; mk >= 1; mk >>= 1) z += __shfl_xor(z, mk);
    __shared__ float pbuf[4][32];
    if (ln < 32) pbuf[h][ln] = e / z;
    __syncthreads();
    float a0 = 0.f, a1 = 0.f, a2 = 0.f;
    for (int j = 0; j < 32; ++j) {
        const float* vr = kv + ((size_t)u * 32 + j) * 1536 + 768 + h * 192;
        float p = pbuf[h][j];
        a0 += p * vr[ln]; a1 += p * vr[ln + 64]; a2 += p * vr[ln + 128];
    }
    float* o = out0 + (size_t)u * 768 + h * 192;
    o[ln] = a0; o[ln + 64] = a1; o[ln + 128] = a2;
}

// ---------- last-wins winner + scatter ----------
__global__ void winner_kernel(const int* __restrict__ nbidx, int* __restrict__ slot, int U)
{
    int u = blockIdx.x * 256 + threadIdx.x;
    if (u < U) atomicMax(&slot[nbidx[(size_t)u * 32]], u);
}
__global__ __launch_bounds__(256) void scatter_kernel(
    const float* __restrict__ proj, const int* __restrict__ nbidx,
    const int* __restrict__ slot, float* __restrict__ feats)
{
    int u = blockIdx.x;
    int c = nbidx[(size_t)u * 32];
    if (slot[c] != u) return;
    const float* src = proj + (size_t)u * 768;
    float* dst = feats + (size_t)c * 768;
    for (int t = threadIdx.x; t < 768; t += 256) dst[t] = src[t];
}

extern "C" void kernel_launch(void* const* d_in, const int* in_sizes, int n_in,
                              void* d_out, int out_size, void* d_ws, size_t ws_size,
                              hipStream_t stream)
{
    const float* user_text = (const float*)d_in[0];
    const float* auf       = (const float*)d_in[1];
    const int*   nbidx     = (const int*)d_in[2];
    const int*   ei        = (const int*)d_in[3];
    const float* Wqkv_l = (const float*)d_in[4];
    const float* bqkv_l = (const float*)d_in[5];
    const float* Wo_l   = (const float*)d_in[6];
    const float* bo_l   = (const float*)d_in[7];
    const float* ln1_g  = (const float*)d_in[8];
    const float* ln1_b  = (const float*)d_in[9];
    const float* ln2_g  = (const float*)d_in[10];
    const float* ln2_b  = (const float*)d_in[11];
    const float* W1 = (const float*)d_in[12];
    const float* b1 = (const float*)d_in[13];
    const float* W2 = (const float*)d_in[14];
    const float* b2 = (const float*)d_in[15];
    const float* Wg = (const float*)d_in[16];
    const float* bg = (const float*)d_in[17];
    const float* Wqkv_m = (const float*)d_in[18];
    const float* bqkv_m = (const float*)d_in[19];
    const float* Wo_m   = (const float*)d_in[20];
    const float* bo_m   = (const float*)d_in[21];

    const int D  = 768;
    const int BS = in_sizes[0] / D;    // 1008
    const int B  = BS / 126;           // 8
    const int N  = in_sizes[1] / D;    // 100000
    const int U  = in_sizes[2] / 32;   // 1024
    const int E  = in_sizes[3] / 2;    // 1600000
    const int UK = U * 32;             // 32768

    float* out_text  = (float*)d_out;
    const int TEXTN = BS * D;
    const int WG_T = (TEXTN + 255) / 256;
    float* out_feats = out_text + (size_t)TEXTN;
    float* out_pool  = out_feats + (size_t)N * D;

    char* ws = (char*)d_ws;
    size_t off = 0;
    auto take = [&](size_t bytes) -> void* {
        void* p = ws + off;
        off += (bytes + 255) & ~(size_t)255;
        return p;
    };
    float* A_h    = (float*)take((size_t)N * D * 4);      // h (bf16 in low half); reused as kv
    float* qkvl   = (float*)take((size_t)BS * 2304 * 4);
    float* ln1x   = (float*)take((size_t)BS * D * 4);
    float* attnout= (float*)take((size_t)BS * D * 4);
    float* text1  = (float*)take((size_t)BS * D * 4);
    float* ln2x   = (float*)take((size_t)BS * D * 4);
    float* qc     = (float*)take((size_t)U * D * 4);
    float* out0   = (float*)take((size_t)U * D * 4);
    float* projm  = (float*)take((size_t)U * D * 4);
    int*   cnt    = (int*)take((size_t)N * 4);
    float* dsc    = (float*)take((size_t)N * 4);
    int*   slot   = (int*)take((size_t)N * 4);
    int*   bucket = (int*)take((size_t)N * 64 * 4);
    float* pooled = (float*)take((size_t)B * 36 * 4);
    float* hmid   = ln1x;                 // alias (ln1x dead after qkv gemm)
    uint16_t* hbf = (uint16_t*)A_h;       // bf16 h occupies first half of A_h
    float* kv     = A_h;                  // alias for kv after agg (201MB <= 307MB)
    size_t required = off;

    if (ws_size < required) {
        code_write_f32<<<WG_T, 256, 0, stream>>>(out_text, TEXTN,
            1.0e6f + (float)(ws_size >> 20) * 1000.0f);
        return;
    }

    hipMemsetAsync(cnt, 0, (size_t)N * 4, stream);
    hipMemsetAsync(slot, 0xFF, (size_t)N * 4, stream);
    hipMemsetAsync(pooled, 0, (size_t)B * 36 * 4, stream);

    // --- GCN prep ---
    deg_fill_kernel<<<(E + 255) / 256, 256, 0, stream>>>(ei, E, cnt, bucket);
    dinv_kernel<<<(N + 255) / 256, 256, 0, stream>>>(cnt, dsc, N);

    const int BMT = (BS + 127) / 128;   // 8 row-tiles for text
    // --- text path ---
    ln_kernel<<<BS, 256, 0, stream>>>(user_text, ln1_g, ln1_b, ln1x);
    gemm_bt<<<dim3(BMT, 18), 256, 0, stream>>>(
        ln1x, Wqkv_l, bqkv_l, qkvl, nullptr, nullptr, 1, BS, 2304, 0, 0);
    nattn<<<BS, 256, 0, stream>>>(qkvl, attnout, pooled);
    gemm_bt<<<dim3(BMT, 6), 256, 0, stream>>>(
        attnout, Wo_l, bo_l, text1, user_text, nullptr, 1, BS, 768, 0, 0);
    ln_kernel<<<BS, 256, 0, stream>>>(text1, ln2_g, ln2_b, ln2x);
    gemm_bt<<<dim3(BMT, 6), 256, 0, stream>>>(
        ln2x, W1, b1, hmid, nullptr, nullptr, 1, BS, 768, 1, 0);
    gemm_bt<<<dim3(BMT, 6), 256, 0, stream>>>(
        hmid, W2, b2, out_text, text1, nullptr, 1, BS, 768, 0, 0);
    pool_fin_kernel<<<B, 36, 0, stream>>>(pooled, out_pool);

    // --- feats: rsqrt GCN; h stored bf16 (halves agg gather traffic) ---
    gemm_bt<<<dim3((N + 127) / 128, 6), 256, 0, stream>>>(
        auf, Wg, nullptr, hbf, nullptr, nullptr, 1, N, 768, 0, 1);
    gcn_agg<<<N, 256, 0, stream>>>(hbf, bucket, cnt, dsc, bg, out_feats);

    // --- MultiAttn on neighborhoods, write back center rows (last-wins) ---
    winner_kernel<<<(U + 255) / 256, 256, 0, stream>>>(nbidx, slot, U);
    gemm_bt<<<dim3(UK / 128, 12), 256, 0, stream>>>(
        out_feats, Wqkv_m + (size_t)768 * 768, bqkv_m + 768, kv, nullptr, nbidx, 1, UK, 1536, 0, 0);
    gemm_bt<<<dim3(U / 128, 6), 256, 0, stream>>>(
        out_feats, Wqkv_m, bqkv_m, qc, nullptr, nbidx, 32, U, 768, 0, 0);
    attn_m_kernel<<<U, 256, 0, stream>>>(kv, qc, out0);
    gemm_bt<<<dim3(U / 128, 6), 256, 0, stream>>>(
        out0, Wo_m, bo_m, projm, nullptr, nullptr, 1, U, 768, 0, 0);
    scatter_kernel<<<U, 256, 0, stream>>>(projm, nbidx, slot, out_feats);
}

// Round 18
// 1622.031 us; speedup vs baseline: 32.0136x; 1.0691x over previous
//
#include <hip/hip_runtime.h>
#include <stdint.h>

typedef __attribute__((ext_vector_type(8))) short short8;
typedef __attribute__((ext_vector_type(4))) float f32x4;

__device__ __forceinline__ float bf2f(uint16_t u) {
    union { uint32_t i; float f; } v; v.i = ((uint32_t)u) << 16; return v.f;
}
__device__ __forceinline__ uint16_t f2bf(float f) {
    union { float f; uint32_t i; } v; v.f = f;
    uint32_t r = v.i + 0x7fffu + ((v.i >> 16) & 1u);
    return (uint16_t)(r >> 16);
}
__device__ __forceinline__ short8 cvt8(const float* p) {
    f32x4 a = *(const f32x4*)p;
    f32x4 b = *(const f32x4*)(p + 4);
    short8 r;
    r[0] = (short)f2bf(a[0]); r[1] = (short)f2bf(a[1]);
    r[2] = (short)f2bf(a[2]); r[3] = (short)f2bf(a[3]);
    r[4] = (short)f2bf(b[0]); r[5] = (short)f2bf(b[1]);
    r[6] = (short)f2bf(b[2]); r[7] = (short)f2bf(b[3]);
    return r;
}

__global__ void code_write_f32(float* __restrict__ out, int n, float codef)
{
    int i = blockIdx.x * 256 + threadIdx.x;
    if (i < n) out[i] = codef;
}

// ---------- MFMA GEMM: C[M,N] = A[rowmap?][768] @ W[N,768]^T + bias (+R)(leaky) ----------
// grid = dim3(numN, numM): bn = blockIdx.x (fast) so A-panel-sharing blocks are adjacent.
// LDS XOR-swizzled (chunk ^= row&3) to kill 8-way bank conflicts on fragment reads.
__global__ __launch_bounds__(256) void gemm_bt(
    const float* __restrict__ A, const float* __restrict__ W,
    const float* __restrict__ bias, void* __restrict__ Cv,
    const float* __restrict__ R, const int* __restrict__ rowmap, int rstride,
    int M, int N, int act, int cbf)
{
    __shared__ __attribute__((aligned(16))) uint16_t As[4096];  // [128][32] bf16, swizzled
    __shared__ __attribute__((aligned(16))) uint16_t Ws[4096];
    const int K = 768;
    int tid = threadIdx.x, wv = tid >> 6, ln = tid & 63;
    int bn = blockIdx.x, bm = blockIdx.y;
    int wm = wv >> 1, wn = wv & 1;

    const f32x4 zero4 = {0.f, 0.f, 0.f, 0.f};
    f32x4 acc[4][4];
#pragma unroll
    for (int i = 0; i < 4; ++i)
#pragma unroll
        for (int j = 0; j < 4; ++j) acc[i][j] = zero4;

    int r0 = tid >> 2, cb = tid & 3;
    int c8 = cb * 8;
    int r1 = r0 + 64;
    int ar0 = min(bm * 128 + r0, M - 1);
    int ar1 = min(bm * 128 + r1, M - 1);
    if (rowmap) { ar0 = rowmap[(size_t)ar0 * rstride]; ar1 = rowmap[(size_t)ar1 * rstride]; }
    int br0 = bn * 128 + r0, br1 = bn * 128 + r1;
    const float* Af0 = A + (size_t)ar0 * K + c8;
    const float* Af1 = A + (size_t)ar1 * K + c8;
    const float* Wf0 = W + (size_t)br0 * K + c8;
    const float* Wf1 = W + (size_t)br1 * K + c8;
    const int sw  = (cb ^ (r0 & 3)) * 8;          // swizzled chunk (r1&3 == r0&3)
    const int s0 = r0 * 32 + sw;
    const int s1 = 2048 + r0 * 32 + sw;
    const int lr = ln & 15, kg = ln >> 4;
    const int kgsw = (kg ^ (lr & 3)) * 8;         // read-side swizzle (row&3 == lr&3)

    for (int k0 = 0; k0 < K; k0 += 32) {
        short8 a0 = cvt8(Af0 + k0);
        short8 a1 = cvt8(Af1 + k0);
        short8 w0 = cvt8(Wf0 + k0);
        short8 w1 = cvt8(Wf1 + k0);
        __syncthreads();
        *(short8*)&As[s0] = a0;
        *(short8*)&As[s1] = a1;
        *(short8*)&Ws[s0] = w0;
        *(short8*)&Ws[s1] = w1;
        __syncthreads();
        short8 afr[4], bfr[4];
#pragma unroll
        for (int mi = 0; mi < 4; ++mi)
            afr[mi] = *(const short8*)&As[(wm * 64 + mi * 16 + lr) * 32 + kgsw];
#pragma unroll
        for (int nj = 0; nj < 4; ++nj)
            bfr[nj] = *(const short8*)&Ws[(wn * 64 + nj * 16 + lr) * 32 + kgsw];
#pragma unroll
        for (int mi = 0; mi < 4; ++mi)
#pragma unroll
            for (int nj = 0; nj < 4; ++nj)
                acc[mi][nj] = __builtin_amdgcn_mfma_f32_16x16x32_bf16(
                    afr[mi], bfr[nj], acc[mi][nj], 0, 0, 0);
    }

#pragma unroll
    for (int mi = 0; mi < 4; ++mi) {
        int growb = bm * 128 + wm * 64 + mi * 16 + kg * 4;
#pragma unroll
        for (int nj = 0; nj < 4; ++nj) {
            int gcol = bn * 128 + wn * 64 + nj * 16 + lr;
            float bs = bias ? bias[gcol] : 0.f;
#pragma unroll
            for (int q = 0; q < 4; ++q) {
                int grow = growb + q;
                if (grow < M) {
                    float val = acc[mi][nj][q] + bs;
                    if (R) val += R[(size_t)grow * N + gcol];
                    if (act == 1) val = (val > 0.f) ? val : 0.01f * val;
                    size_t idx = (size_t)grow * N + gcol;
                    if (cbf) ((uint16_t*)Cv)[idx] = f2bf(val);
                    else     ((float*)Cv)[idx]    = val;
                }
            }
        }
    }
}

// ---------- LayerNorm (f32) ----------
__global__ __launch_bounds__(256) void ln_kernel(
    const float* __restrict__ x, const float* __restrict__ g,
    const float* __restrict__ bb, float* __restrict__ y)
{
    int row = blockIdx.x, tid = threadIdx.x;
    const float* xr = x + (size_t)row * 768;
    float v0 = xr[tid], v1 = xr[tid + 256], v2 = xr[tid + 512];
    float s = v0 + v1 + v2;
    __shared__ float red[4];
#pragma unroll
    for (int mk = 32; mk >= 1; mk >>= 1) s += __shfl_xor(s, mk);
    int wv = tid >> 6, ln = tid & 63;
    if (ln == 0) red[wv] = s;
    __syncthreads();
    float mu = (red[0] + red[1] + red[2] + red[3]) * (1.f / 768.f);
    float d0 = v0 - mu, d1 = v1 - mu, d2 = v2 - mu;
    float ss = d0 * d0 + d1 * d1 + d2 * d2;
#pragma unroll
    for (int mk = 32; mk >= 1; mk >>= 1) ss += __shfl_xor(ss, mk);
    __syncthreads();
    if (ln == 0) red[wv] = ss;
    __syncthreads();
    float var = (red[0] + red[1] + red[2] + red[3]) * (1.f / 768.f);
    float inv = 1.0f / sqrtf(var + 1e-5f);
    float* yr = y + (size_t)row * 768;
    yr[tid]       = d0 * inv * g[tid]       + bb[tid];
    yr[tid + 256] = d1 * inv * g[tid + 256] + bb[tid + 256];
    yr[tid + 512] = d2 * inv * g[tid + 512] + bb[tid + 512];
}

// ---------- wave-parallel text attention; one block per (b,i) ----------
__global__ __launch_bounds__(256) void nattn(
    const float* __restrict__ qkv, float* __restrict__ attnout,
    float* __restrict__ pooled)
{
    int b = blockIdx.x / 126, i = blockIdx.x % 126;
    int tid = threadIdx.x;
    __shared__ float P[4][128];
    __shared__ float poolloc[6];
    if (tid < 6) poolloc[tid] = 0.f;
    const size_t base = (size_t)b * 126 * 2304;
    const float scale = 0.0721687836f;  // 1/sqrt(192)

    for (int p = tid; p < 504; p += 256) {
        int h = p / 126, j = p - h * 126;
        const float* qr = qkv + base + (size_t)i * 2304 + h * 192;
        const float* kr = qkv + base + (size_t)j * 2304 + 768 + h * 192;
        float a = 0.f;
#pragma unroll 8
        for (int d = 0; d < 192; ++d) a += qr[d] * kr[d];
        P[h][j] = a * scale;
    }
    __syncthreads();

    {
        int w = tid >> 6, ln = tid & 63;
        bool v1 = (ln + 64) < 126;
        float s0 = P[w][ln];
        float s1 = v1 ? P[w][ln + 64] : -1e30f;
        float m = fmaxf(s0, s1);
#pragma unroll
        for (int mk = 32; mk >= 1; mk >>= 1) m = fmaxf(m, __shfl_xor(m, mk));
        float e0 = __expf(s0 - m);
        float e1 = v1 ? __expf(s1 - m) : 0.f;
        float z = e0 + e1;
#pragma unroll
        for (int mk = 32; mk >= 1; mk >>= 1) z += __shfl_xor(z, mk);
        float rz = 1.f / z;
        P[w][ln] = e0 * rz;
        if (v1) P[w][ln + 64] = e1 * rz;
    }
    __syncthreads();

    if (tid < 126) {
        float s4 = P[0][tid] + P[1][tid] + P[2][tid] + P[3][tid];
        atomicAdd(&poolloc[tid / 21], s4);
    }

    float o[3];
#pragma unroll
    for (int r = 0; r < 3; ++r) {
        int od = tid + r * 256;
        int h = od / 192;
        float a = 0.f;
        for (int j = 0; j < 126; ++j)
            a += P[h][j] * qkv[base + (size_t)j * 2304 + 1536 + od];
        o[r] = a;
    }
    float* orow = attnout + (size_t)(b * 126 + i) * 768;
#pragma unroll
    for (int r = 0; r < 3; ++r) orow[tid + r * 256] = o[r];

    __syncthreads();
    if (tid < 6)
        atomicAdd(&pooled[b * 36 + (i / 21) * 6 + tid], poolloc[tid]);
}

__global__ void pool_fin_kernel(const float* __restrict__ pooled, float* __restrict__ outp)
{
    int i = blockIdx.x * 36 + threadIdx.x;
    outp[i] = pooled[i] * (1.0f / 1764.0f);
}

// ---------- GCN prep ----------
__global__ void deg_fill_kernel(const int* __restrict__ ei, int E,
                                int* __restrict__ cnt, int* __restrict__ bucket)
{
    int e = blockIdx.x * 256 + threadIdx.x;
    if (e < E) {
        int s = ei[e], d = ei[E + e];
        int p = atomicAdd(&cnt[d], 1);
        if (p < 64) bucket[(size_t)d * 64 + p] = s;
    }
}
__global__ void dinv_kernel(const int* __restrict__ cnt, float* __restrict__ ds, int N)
{
    int i = blockIdx.x * 256 + threadIdx.x;
    if (i < N) ds[i] = 1.0f / sqrtf((float)cnt[i] + 1.0f);
}

// feats[v] = dinv[v]*( sum_src dinv[s]*h[s] + dinv[v]*h[v] ) + bg ; h in bf16
__global__ __launch_bounds__(256) void gcn_agg(
    const uint16_t* __restrict__ h, const int* __restrict__ bucket,
    const int* __restrict__ cnt, const float* __restrict__ dsc,
    const float* __restrict__ bg, float* __restrict__ feats)
{
    int v = blockIdx.x;
    int tid = threadIdx.x;
    const uint16_t* hv = h + (size_t)v * 768;
    float sv = dsc[v];
    float a0 = bf2f(hv[tid]) * sv, a1 = bf2f(hv[tid + 256]) * sv, a2 = bf2f(hv[tid + 512]) * sv;
    int nb = min(cnt[v], 64);
    for (int e = 0; e < nb; ++e) {
        int s = bucket[(size_t)v * 64 + e];
        const uint16_t* hs = h + (size_t)s * 768;
        float ss = dsc[s];
        a0 += bf2f(hs[tid]) * ss; a1 += bf2f(hs[tid + 256]) * ss; a2 += bf2f(hs[tid + 512]) * ss;
    }
    float* o = feats + (size_t)v * 768;
    o[tid]       = a0 * sv + bg[tid];
    o[tid + 256] = a1 * sv + bg[tid + 256];
    o[tid + 512] = a2 * sv + bg[tid + 512];
}

// ---------- MultiAttn: 1 query (center row) x 32 keys ----------
__global__ __launch_bounds__(256) void attn_m_kernel(
    const float* __restrict__ kv, const float* __restrict__ qc,
    float* __restrict__ out0)
{
    int u = blockIdx.x;
    int tid = threadIdx.x, h = tid >> 6, ln = tid & 63;
    const float scale = 0.0721687836f;
    float s = -1e30f;
    {
        int j = (ln < 32) ? ln : 0;
        const float* qr = qc + (size_t)u * 768 + h * 192;
        const float* kr = kv + ((size_t)u * 32 + j) * 1536 + h * 192;
        float a = 0.f;
#pragma unroll 8
        for (int d = 0; d < 192; ++d) a += qr[d] * kr[d];
        if (ln < 32) s = a * scale;
    }
    float m = s;
#pragma unroll
    for (int mk = 32; mk >= 1; mk >>= 1) m = fmaxf(m, __shfl_xor(m, mk));
    float e = (ln < 32) ? __expf(s - m) : 0.f;
    float z = e;
#pragma unroll
    for (int mk = 32; mk >= 1; mk >>= 1) z += __shfl_xor(z, mk);
    __shared__ float pbuf[4][32];
    if (ln < 32) pbuf[h][ln] = e / z;
    __syncthreads();
    float a0 = 0.f, a1 = 0.f, a2 = 0.f;
    for (int j = 0; j < 32; ++j) {
        const float* vr = kv + ((size_t)u * 32 + j) * 1536 + 768 + h * 192;
        float p = pbuf[h][j];
        a0 += p * vr[ln]; a1 += p * vr[ln + 64]; a2 += p * vr[ln + 128];
    }
    float* o = out0 + (size_t)u * 768 + h * 192;
    o[ln] = a0; o[ln + 64] = a1; o[ln + 128] = a2;
}

// ---------- last-wins winner + scatter ----------
__global__ void winner_kernel(const int* __restrict__ nbidx, int* __restrict__ slot, int U)
{
    int u = blockIdx.x * 256 + threadIdx.x;
    if (u < U) atomicMax(&slot[nbidx[(size_t)u * 32]], u);
}
__global__ __launch_bounds__(256) void scatter_kernel(
    const float* __restrict__ proj, const int* __restrict__ nbidx,
    const int* __restrict__ slot, float* __restrict__ feats)
{
    int u = blockIdx.x;
    int c = nbidx[(size_t)u * 32];
    if (slot[c] != u) return;
    const float* src = proj + (size_t)u * 768;
    float* dst = feats + (size_t)c * 768;
    for (int t = threadIdx.x; t < 768; t += 256) dst[t] = src[t];
}

extern "C" void kernel_launch(void* const* d_in, const int* in_sizes, int n_in,
                              void* d_out, int out_size, void* d_ws, size_t ws_size,
                              hipStream_t stream)
{
    const float* user_text = (const float*)d_in[0];
    const float* auf       = (const float*)d_in[1];
    const int*   nbidx     = (const int*)d_in[2];
    const int*   ei        = (const int*)d_in[3];
    const float* Wqkv_l = (const float*)d_in[4];
    const float* bqkv_l = (const float*)d_in[5];
    const float* Wo_l   = (const float*)d_in[6];
    const float* bo_l   = (const float*)d_in[7];
    const float* ln1_g  = (const float*)d_in[8];
    const float* ln1_b  = (const float*)d_in[9];
    const float* ln2_g  = (const float*)d_in[10];
    const float* ln2_b  = (const float*)d_in[11];
    const float* W1 = (const float*)d_in[12];
    const float* b1 = (const float*)d_in[13];
    const float* W2 = (const float*)d_in[14];
    const float* b2 = (const float*)d_in[15];
    const float* Wg = (const float*)d_in[16];
    const float* bg = (const float*)d_in[17];
    const float* Wqkv_m = (const float*)d_in[18];
    const float* bqkv_m = (const float*)d_in[19];
    const float* Wo_m   = (const float*)d_in[20];
    const float* bo_m   = (const float*)d_in[21];

    const int D  = 768;
    const int BS = in_sizes[0] / D;    // 1008
    const int B  = BS / 126;           // 8
    const int N  = in_sizes[1] / D;    // 100000
    const int U  = in_sizes[2] / 32;   // 1024
    const int E  = in_sizes[3] / 2;    // 1600000
    const int UK = U * 32;             // 32768

    float* out_text  = (float*)d_out;
    const int TEXTN = BS * D;
    const int WG_T = (TEXTN + 255) / 256;
    float* out_feats = out_text + (size_t)TEXTN;
    float* out_pool  = out_feats + (size_t)N * D;

    char* ws = (char*)d_ws;
    size_t off = 0;
    auto take = [&](size_t bytes) -> void* {
        void* p = ws + off;
        off += (bytes + 255) & ~(size_t)255;
        return p;
    };
    float* A_h    = (float*)take((size_t)N * D * 4);
    float* qkvl   = (float*)take((size_t)BS * 2304 * 4);
    float* ln1x   = (float*)take((size_t)BS * D * 4);
    float* attnout= (float*)take((size_t)BS * D * 4);
    float* text1  = (float*)take((size_t)BS * D * 4);
    float* ln2x   = (float*)take((size_t)BS * D * 4);
    float* qc     = (float*)take((size_t)U * D * 4);
    float* out0   = (float*)take((size_t)U * D * 4);
    float* projm  = (float*)take((size_t)U * D * 4);
    int*   cnt    = (int*)take((size_t)N * 4);
    float* dsc    = (float*)take((size_t)N * 4);
    int*   slot   = (int*)take((size_t)N * 4);
    int*   bucket = (int*)take((size_t)N * 64 * 4);
    float* pooled = (float*)take((size_t)B * 36 * 4);
    float* hmid   = ln1x;
    uint16_t* hbf = (uint16_t*)A_h;
    float* kv     = A_h;
    size_t required = off;

    if (ws_size < required) {
        code_write_f32<<<WG_T, 256, 0, stream>>>(out_text, TEXTN,
            1.0e6f + (float)(ws_size >> 20) * 1000.0f);
        return;
    }

    hipMemsetAsync(cnt, 0, (size_t)N * 4, stream);
    hipMemsetAsync(slot, 0xFF, (size_t)N * 4, stream);
    hipMemsetAsync(pooled, 0, (size_t)B * 36 * 4, stream);

    deg_fill_kernel<<<(E + 255) / 256, 256, 0, stream>>>(ei, E, cnt, bucket);
    dinv_kernel<<<(N + 255) / 256, 256, 0, stream>>>(cnt, dsc, N);

    const int BMT = (BS + 127) / 128;   // 8 row-tiles for text
    // --- text path (grid = (numN, numM)) ---
    ln_kernel<<<BS, 256, 0, stream>>>(user_text, ln1_g, ln1_b, ln1x);
    gemm_bt<<<dim3(18, BMT), 256, 0, stream>>>(
        ln1x, Wqkv_l, bqkv_l, qkvl, nullptr, nullptr, 1, BS, 2304, 0, 0);
    nattn<<<BS, 256, 0, stream>>>(qkvl, attnout, pooled);
    gemm_bt<<<dim3(6, BMT), 256, 0, stream>>>(
        attnout, Wo_l, bo_l, text1, user_text, nullptr, 1, BS, 768, 0, 0);
    ln_kernel<<<BS, 256, 0, stream>>>(text1, ln2_g, ln2_b, ln2x);
    gemm_bt<<<dim3(6, BMT), 256, 0, stream>>>(
        ln2x, W1, b1, hmid, nullptr, nullptr, 1, BS, 768, 1, 0);
    gemm_bt<<<dim3(6, BMT), 256, 0, stream>>>(
        hmid, W2, b2, out_text, text1, nullptr, 1, BS, 768, 0, 0);
    pool_fin_kernel<<<B, 36, 0, stream>>>(pooled, out_pool);

    // --- feats: rsqrt GCN (h bf16) ---
    gemm_bt<<<dim3(6, (N + 127) / 128), 256, 0, stream>>>(
        auf, Wg, nullptr, hbf, nullptr, nullptr, 1, N, 768, 0, 1);
    gcn_agg<<<N, 256, 0, stream>>>(hbf, bucket, cnt, dsc, bg, out_feats);

    // --- MultiAttn, last-wins center writeback ---
    winner_kernel<<<(U + 255) / 256, 256, 0, stream>>>(nbidx, slot, U);
    gemm_bt<<<dim3(12, UK / 128), 256, 0, stream>>>(
        out_feats, Wqkv_m + (size_t)768 * 768, bqkv_m + 768, kv, nullptr, nbidx, 1, UK, 1536, 0, 0);
    gemm_bt<<<dim3(6, U / 128), 256, 0, stream>>>(
        out_feats, Wqkv_m, bqkv_m, qc, nullptr, nbidx, 32, U, 768, 0, 0);
    attn_m_kernel<<<U, 256, 0, stream>>>(kv, qc, out0);
    gemm_bt<<<dim3(6, U / 128), 256, 0, stream>>>(
        out0, Wo_m, bo_m, projm, nullptr, nullptr, 1, U, 768, 0, 0);
    scatter_kernel<<<U, 256, 0, stream>>>(projm, nbidx, slot, out_feats);
}

// Round 19
// 1595.790 us; speedup vs baseline: 32.5400x; 1.0164x over previous
//
#include <hip/hip_runtime.h>
#include <stdint.h>

typedef __attribute__((ext_vector_type(8))) short short8;
typedef __attribute__((ext_vector_type(4))) float f32x4;

__device__ __forceinline__ float bf2f(uint16_t u) {
    union { uint32_t i; float f; } v; v.i = ((uint32_t)u) << 16; return v.f;
}
__device__ __forceinline__ uint16_t f2bf(float f) {
    union { float f; uint32_t i; } v; v.f = f;
    uint32_t r = v.i + 0x7fffu + ((v.i >> 16) & 1u);
    return (uint16_t)(r >> 16);
}
__device__ __forceinline__ short8 cvt8(const float* p) {
    f32x4 a = *(const f32x4*)p;
    f32x4 b = *(const f32x4*)(p + 4);
    short8 r;
    r[0] = (short)f2bf(a[0]); r[1] = (short)f2bf(a[1]);
    r[2] = (short)f2bf(a[2]); r[3] = (short)f2bf(a[3]);
    r[4] = (short)f2bf(b[0]); r[5] = (short)f2bf(b[1]);
    r[6] = (short)f2bf(b[2]); r[7] = (short)f2bf(b[3]);
    return r;
}

__global__ void code_write_f32(float* __restrict__ out, int n, float codef)
{
    int i = blockIdx.x * 256 + threadIdx.x;
    if (i < n) out[i] = codef;
}

// ---------- MFMA GEMM: C[M,N] = A[rowmap?][768] @ W[N,768]^T + bias (+R)(leaky) ----------
__global__ __launch_bounds__(256) void gemm_bt(
    const float* __restrict__ A, const float* __restrict__ W,
    const float* __restrict__ bias, void* __restrict__ Cv,
    const float* __restrict__ R, const int* __restrict__ rowmap, int rstride,
    int M, int N, int act, int cbf)
{
    __shared__ __attribute__((aligned(16))) uint16_t As[4096];  // [128][32] bf16, swizzled
    __shared__ __attribute__((aligned(16))) uint16_t Ws[4096];
    const int K = 768;
    int tid = threadIdx.x, wv = tid >> 6, ln = tid & 63;
    int bn = blockIdx.x, bm = blockIdx.y;
    int wm = wv >> 1, wn = wv & 1;

    const f32x4 zero4 = {0.f, 0.f, 0.f, 0.f};
    f32x4 acc[4][4];
#pragma unroll
    for (int i = 0; i < 4; ++i)
#pragma unroll
        for (int j = 0; j < 4; ++j) acc[i][j] = zero4;

    int r0 = tid >> 2, cb = tid & 3;
    int c8 = cb * 8;
    int r1 = r0 + 64;
    int ar0 = min(bm * 128 + r0, M - 1);
    int ar1 = min(bm * 128 + r1, M - 1);
    if (rowmap) { ar0 = rowmap[(size_t)ar0 * rstride]; ar1 = rowmap[(size_t)ar1 * rstride]; }
    int br0 = bn * 128 + r0, br1 = bn * 128 + r1;
    const float* Af0 = A + (size_t)ar0 * K + c8;
    const float* Af1 = A + (size_t)ar1 * K + c8;
    const float* Wf0 = W + (size_t)br0 * K + c8;
    const float* Wf1 = W + (size_t)br1 * K + c8;
    const int sw  = (cb ^ (r0 & 3)) * 8;
    const int s0 = r0 * 32 + sw;
    const int s1 = 2048 + r0 * 32 + sw;
    const int lr = ln & 15, kg = ln >> 4;
    const int kgsw = (kg ^ (lr & 3)) * 8;

    for (int k0 = 0; k0 < K; k0 += 32) {
        short8 a0 = cvt8(Af0 + k0);
        short8 a1 = cvt8(Af1 + k0);
        short8 w0 = cvt8(Wf0 + k0);
        short8 w1 = cvt8(Wf1 + k0);
        __syncthreads();
        *(short8*)&As[s0] = a0;
        *(short8*)&As[s1] = a1;
        *(short8*)&Ws[s0] = w0;
        *(short8*)&Ws[s1] = w1;
        __syncthreads();
        short8 afr[4], bfr[4];
#pragma unroll
        for (int mi = 0; mi < 4; ++mi)
            afr[mi] = *(const short8*)&As[(wm * 64 + mi * 16 + lr) * 32 + kgsw];
#pragma unroll
        for (int nj = 0; nj < 4; ++nj)
            bfr[nj] = *(const short8*)&Ws[(wn * 64 + nj * 16 + lr) * 32 + kgsw];
#pragma unroll
        for (int mi = 0; mi < 4; ++mi)
#pragma unroll
            for (int nj = 0; nj < 4; ++nj)
                acc[mi][nj] = __builtin_amdgcn_mfma_f32_16x16x32_bf16(
                    afr[mi], bfr[nj], acc[mi][nj], 0, 0, 0);
    }

#pragma unroll
    for (int mi = 0; mi < 4; ++mi) {
        int growb = bm * 128 + wm * 64 + mi * 16 + kg * 4;
#pragma unroll
        for (int nj = 0; nj < 4; ++nj) {
            int gcol = bn * 128 + wn * 64 + nj * 16 + lr;
            float bs = bias ? bias[gcol] : 0.f;
#pragma unroll
            for (int q = 0; q < 4; ++q) {
                int grow = growb + q;
                if (grow < M) {
                    float val = acc[mi][nj][q] + bs;
                    if (R) val += R[(size_t)grow * N + gcol];
                    if (act == 1) val = (val > 0.f) ? val : 0.01f * val;
                    size_t idx = (size_t)grow * N + gcol;
                    if (cbf) ((uint16_t*)Cv)[idx] = f2bf(val);
                    else     ((float*)Cv)[idx]    = val;
                }
            }
        }
    }
}

// ---------- LayerNorm (f32) ----------
__global__ __launch_bounds__(256) void ln_kernel(
    const float* __restrict__ x, const float* __restrict__ g,
    const float* __restrict__ bb, float* __restrict__ y)
{
    int row = blockIdx.x, tid = threadIdx.x;
    const float* xr = x + (size_t)row * 768;
    float v0 = xr[tid], v1 = xr[tid + 256], v2 = xr[tid + 512];
    float s = v0 + v1 + v2;
    __shared__ float red[4];
#pragma unroll
    for (int mk = 32; mk >= 1; mk >>= 1) s += __shfl_xor(s, mk);
    int wv = tid >> 6, ln = tid & 63;
    if (ln == 0) red[wv] = s;
    __syncthreads();
    float mu = (red[0] + red[1] + red[2] + red[3]) * (1.f / 768.f);
    float d0 = v0 - mu, d1 = v1 - mu, d2 = v2 - mu;
    float ss = d0 * d0 + d1 * d1 + d2 * d2;
#pragma unroll
    for (int mk = 32; mk >= 1; mk >>= 1) ss += __shfl_xor(ss, mk);
    __syncthreads();
    if (ln == 0) red[wv] = ss;
    __syncthreads();
    float var = (red[0] + red[1] + red[2] + red[3]) * (1.f / 768.f);
    float inv = 1.0f / sqrtf(var + 1e-5f);
    float* yr = y + (size_t)row * 768;
    yr[tid]       = d0 * inv * g[tid]       + bb[tid];
    yr[tid + 256] = d1 * inv * g[tid + 256] + bb[tid + 256];
    yr[tid + 512] = d2 * inv * g[tid + 512] + bb[tid + 512];
}

// ---------- wave-parallel text attention; one block per (b,i) ----------
__global__ __launch_bounds__(256) void nattn(
    const float* __restrict__ qkv, float* __restrict__ attnout,
    float* __restrict__ pooled)
{
    int b = blockIdx.x / 126, i = blockIdx.x % 126;
    int tid = threadIdx.x;
    __shared__ float P[4][128];
    __shared__ float poolloc[6];
    if (tid < 6) poolloc[tid] = 0.f;
    const size_t base = (size_t)b * 126 * 2304;
    const float scale = 0.0721687836f;

    for (int p = tid; p < 504; p += 256) {
        int h = p / 126, j = p - h * 126;
        const float* qr = qkv + base + (size_t)i * 2304 + h * 192;
        const float* kr = qkv + base + (size_t)j * 2304 + 768 + h * 192;
        float a = 0.f;
#pragma unroll 8
        for (int d = 0; d < 192; ++d) a += qr[d] * kr[d];
        P[h][j] = a * scale;
    }
    __syncthreads();

    {
        int w = tid >> 6, ln = tid & 63;
        bool v1 = (ln + 64) < 126;
        float s0 = P[w][ln];
        float s1 = v1 ? P[w][ln + 64] : -1e30f;
        float m = fmaxf(s0, s1);
#pragma unroll
        for (int mk = 32; mk >= 1; mk >>= 1) m = fmaxf(m, __shfl_xor(m, mk));
        float e0 = __expf(s0 - m);
        float e1 = v1 ? __expf(s1 - m) : 0.f;
        float z = e0 + e1;
#pragma unroll
        for (int mk = 32; mk >= 1; mk >>= 1) z += __shfl_xor(z, mk);
        float rz = 1.f / z;
        P[w][ln] = e0 * rz;
        if (v1) P[w][ln + 64] = e1 * rz;
    }
    __syncthreads();

    if (tid < 126) {
        float s4 = P[0][tid] + P[1][tid] + P[2][tid] + P[3][tid];
        atomicAdd(&poolloc[tid / 21], s4);
    }

    float o[3];
#pragma unroll
    for (int r = 0; r < 3; ++r) {
        int od = tid + r * 256;
        int h = od / 192;
        float a = 0.f;
        for (int j = 0; j < 126; ++j)
            a += P[h][j] * qkv[base + (size_t)j * 2304 + 1536 + od];
        o[r] = a;
    }
    float* orow = attnout + (size_t)(b * 126 + i) * 768;
#pragma unroll
    for (int r = 0; r < 3; ++r) orow[tid + r * 256] = o[r];

    __syncthreads();
    if (tid < 6)
        atomicAdd(&pooled[b * 36 + (i / 21) * 6 + tid], poolloc[tid]);
}

__global__ void pool_fin_kernel(const float* __restrict__ pooled, float* __restrict__ outp)
{
    int i = blockIdx.x * 36 + threadIdx.x;
    outp[i] = pooled[i] * (1.0f / 1764.0f);
}

// ---------- GCN prep ----------
__global__ void deg_fill_kernel(const int* __restrict__ ei, int E,
                                int* __restrict__ cnt, int* __restrict__ bucket)
{
    int e = blockIdx.x * 256 + threadIdx.x;
    if (e < E) {
        int s = ei[e], d = ei[E + e];
        int p = atomicAdd(&cnt[d], 1);
        if (p < 64) bucket[(size_t)d * 64 + p] = s;
    }
}
__global__ void dinv_kernel(const int* __restrict__ cnt, float* __restrict__ ds, int N)
{
    int i = blockIdx.x * 256 + threadIdx.x;
    if (i < N) ds[i] = 1.0f / sqrtf((float)cnt[i] + 1.0f);
}

// feats[v] = dinv[v]*( sum_src dinv[s]*h[s] + dinv[v]*h[v] ) + bg ; h bf16.
// Writes non-temporal (keep h L3-resident); neighbor indices staged in LDS.
__global__ __launch_bounds__(256) void gcn_agg(
    const uint16_t* __restrict__ h, const int* __restrict__ bucket,
    const int* __restrict__ cnt, const float* __restrict__ dsc,
    const float* __restrict__ bg, float* __restrict__ feats)
{
    int v = blockIdx.x;
    int tid = threadIdx.x;
    __shared__ int nbs[64];
    int nb = min(cnt[v], 64);
    if (tid < nb)
        nbs[tid] = __builtin_nontemporal_load(&bucket[(size_t)v * 64 + tid]);
    __syncthreads();
    const uint16_t* hv = h + (size_t)v * 768;
    float sv = dsc[v];
    float a0 = bf2f(hv[tid]) * sv, a1 = bf2f(hv[tid + 256]) * sv, a2 = bf2f(hv[tid + 512]) * sv;
    for (int e = 0; e < nb; ++e) {
        int s = nbs[e];
        const uint16_t* hs = h + (size_t)s * 768;
        float ss = dsc[s];
        a0 += bf2f(hs[tid]) * ss; a1 += bf2f(hs[tid + 256]) * ss; a2 += bf2f(hs[tid + 512]) * ss;
    }
    float* o = feats + (size_t)v * 768;
    __builtin_nontemporal_store(a0 * sv + bg[tid],       &o[tid]);
    __builtin_nontemporal_store(a1 * sv + bg[tid + 256], &o[tid + 256]);
    __builtin_nontemporal_store(a2 * sv + bg[tid + 512], &o[tid + 512]);
}

// ---------- MultiAttn: 1 query (center row) x 32 keys ----------
__global__ __launch_bounds__(256) void attn_m_kernel(
    const float* __restrict__ kv, const float* __restrict__ qc,
    float* __restrict__ out0)
{
    int u = blockIdx.x;
    int tid = threadIdx.x, h = tid >> 6, ln = tid & 63;
    const float scale = 0.0721687836f;
    float s = -1e30f;
    {
        int j = (ln < 32) ? ln : 0;
        const float* qr = qc + (size_t)u * 768 + h * 192;
        const float* kr = kv + ((size_t)u * 32 + j) * 1536 + h * 192;
        float a = 0.f;
#pragma unroll 8
        for (int d = 0; d < 192; ++d) a += qr[d] * kr[d];
        if (ln < 32) s = a * scale;
    }
    float m = s;
#pragma unroll
    for (int mk = 32; mk >= 1; mk >>= 1) m = fmaxf(m, __shfl_xor(m, mk));
    float e = (ln < 32) ? __expf(s - m) : 0.f;
    float z = e;
#pragma unroll
    for (int mk = 32; mk >= 1; mk >>= 1) z += __shfl_xor(z, mk);
    __shared__ float pbuf[4][32];
    if (ln < 32) pbuf[h][ln] = e / z;
    __syncthreads();
    float a0 = 0.f, a1 = 0.f, a2 = 0.f;
    for (int j = 0; j < 32; ++j) {
        const float* vr = kv + ((size_t)u * 32 + j) * 1536 + 768 + h * 192;
        float p = pbuf[h][j];
        a0 += p * vr[ln]; a1 += p * vr[ln + 64]; a2 += p * vr[ln + 128];
    }
    float* o = out0 + (size_t)u * 768 + h * 192;
    o[ln] = a0; o[ln + 64] = a1; o[ln + 128] = a2;
}

// ---------- last-wins winner + scatter ----------
__global__ void winner_kernel(const int* __restrict__ nbidx, int* __restrict__ slot, int U)
{
    int u = blockIdx.x * 256 + threadIdx.x;
    if (u < U) atomicMax(&slot[nbidx[(size_t)u * 32]], u);
}
__global__ __launch_bounds__(256) void scatter_kernel(
    const float* __restrict__ proj, const int* __restrict__ nbidx,
    const int* __restrict__ slot, float* __restrict__ feats)
{
    int u = blockIdx.x;
    int c = nbidx[(size_t)u * 32];
    if (slot[c] != u) return;
    const float* src = proj + (size_t)u * 768;
    float* dst = feats + (size_t)c * 768;
    for (int t = threadIdx.x; t < 768; t += 256) dst[t] = src[t];
}

extern "C" void kernel_launch(void* const* d_in, const int* in_sizes, int n_in,
                              void* d_out, int out_size, void* d_ws, size_t ws_size,
                              hipStream_t stream)
{
    const float* user_text = (const float*)d_in[0];
    const float* auf       = (const float*)d_in[1];
    const int*   nbidx     = (const int*)d_in[2];
    const int*   ei        = (const int*)d_in[3];
    const float* Wqkv_l = (const float*)d_in[4];
    const float* bqkv_l = (const float*)d_in[5];
    const float* Wo_l   = (const float*)d_in[6];
    const float* bo_l   = (const float*)d_in[7];
    const float* ln1_g  = (const float*)d_in[8];
    const float* ln1_b  = (const float*)d_in[9];
    const float* ln2_g  = (const float*)d_in[10];
    const float* ln2_b  = (const float*)d_in[11];
    const float* W1 = (const float*)d_in[12];
    const float* b1 = (const float*)d_in[13];
    const float* W2 = (const float*)d_in[14];
    const float* b2 = (const float*)d_in[15];
    const float* Wg = (const float*)d_in[16];
    const float* bg = (const float*)d_in[17];
    const float* Wqkv_m = (const float*)d_in[18];
    const float* bqkv_m = (const float*)d_in[19];
    const float* Wo_m   = (const float*)d_in[20];
    const float* bo_m   = (const float*)d_in[21];

    const int D  = 768;
    const int BS = in_sizes[0] / D;    // 1008
    const int B  = BS / 126;           // 8
    const int N  = in_sizes[1] / D;    // 100000
    const int U  = in_sizes[2] / 32;   // 1024
    const int E  = in_sizes[3] / 2;    // 1600000
    const int UK = U * 32;             // 32768

    float* out_text  = (float*)d_out;
    const int TEXTN = BS * D;
    const int WG_T = (TEXTN + 255) / 256;
    float* out_feats = out_text + (size_t)TEXTN;
    float* out_pool  = out_feats + (size_t)N * D;

    char* ws = (char*)d_ws;
    size_t off = 0;
    auto take = [&](size_t bytes) -> void* {
        void* p = ws + off;
        off += (bytes + 255) & ~(size_t)255;
        return p;
    };
    float* A_h    = (float*)take((size_t)N * D * 4);
    float* qkvl   = (float*)take((size_t)BS * 2304 * 4);
    float* ln1x   = (float*)take((size_t)BS * D * 4);
    float* attnout= (float*)take((size_t)BS * D * 4);
    float* text1  = (float*)take((size_t)BS * D * 4);
    float* ln2x   = (float*)take((size_t)BS * D * 4);
    float* qc     = (float*)take((size_t)U * D * 4);
    float* out0   = (float*)take((size_t)U * D * 4);
    float* projm  = (float*)take((size_t)U * D * 4);
    int*   cnt    = (int*)take((size_t)N * 4);
    float* dsc    = (float*)take((size_t)N * 4);
    int*   slot   = (int*)take((size_t)N * 4);
    int*   bucket = (int*)take((size_t)N * 64 * 4);
    float* pooled = (float*)take((size_t)B * 36 * 4);
    float* hmid   = ln1x;
    uint16_t* hbf = (uint16_t*)A_h;
    float* kv     = A_h;
    size_t required = off;

    if (ws_size < required) {
        code_write_f32<<<WG_T, 256, 0, stream>>>(out_text, TEXTN,
            1.0e6f + (float)(ws_size >> 20) * 1000.0f);
        return;
    }

    hipMemsetAsync(cnt, 0, (size_t)N * 4, stream);
    hipMemsetAsync(slot, 0xFF, (size_t)N * 4, stream);
    hipMemsetAsync(pooled, 0, (size_t)B * 36 * 4, stream);

    deg_fill_kernel<<<(E + 255) / 256, 256, 0, stream>>>(ei, E, cnt, bucket);
    dinv_kernel<<<(N + 255) / 256, 256, 0, stream>>>(cnt, dsc, N);

    const int BMT = (BS + 127) / 128;
    // --- text path ---
    ln_kernel<<<BS, 256, 0, stream>>>(user_text, ln1_g, ln1_b, ln1x);
    gemm_bt<<<dim3(18, BMT), 256, 0, stream>>>(
        ln1x, Wqkv_l, bqkv_l, qkvl, nullptr, nullptr, 1, BS, 2304, 0, 0);
    nattn<<<BS, 256, 0, stream>>>(qkvl, attnout, pooled);
    gemm_bt<<<dim3(6, BMT), 256, 0, stream>>>(
        attnout, Wo_l, bo_l, text1, user_text, nullptr, 1, BS, 768, 0, 0);
    ln_kernel<<<BS, 256, 0, stream>>>(text1, ln2_g, ln2_b, ln2x);
    gemm_bt<<<dim3(6, BMT), 256, 0, stream>>>(
        ln2x, W1, b1, hmid, nullptr, nullptr, 1, BS, 768, 1, 0);
    gemm_bt<<<dim3(6, BMT), 256, 0, stream>>>(
        hmid, W2, b2, out_text, text1, nullptr, 1, BS, 768, 0, 0);
    pool_fin_kernel<<<B, 36, 0, stream>>>(pooled, out_pool);

    // --- feats: rsqrt GCN (h bf16, nt-writes in agg) ---
    gemm_bt<<<dim3(6, (N + 127) / 128), 256, 0, stream>>>(
        auf, Wg, nullptr, hbf, nullptr, nullptr, 1, N, 768, 0, 1);
    gcn_agg<<<N, 256, 0, stream>>>(hbf, bucket, cnt, dsc, bg, out_feats);

    // --- MultiAttn, last-wins center writeback ---
    winner_kernel<<<(U + 255) / 256, 256, 0, stream>>>(nbidx, slot, U);
    gemm_bt<<<dim3(12, UK / 128), 256, 0, stream>>>(
        out_feats, Wqkv_m + (size_t)768 * 768, bqkv_m + 768, kv, nullptr, nbidx, 1, UK, 1536, 0, 0);
    gemm_bt<<<dim3(6, U / 128), 256, 0, stream>>>(
        out_feats, Wqkv_m, bqkv_m, qc, nullptr, nbidx, 32, U, 768, 0, 0);
    attn_m_kernel<<<U, 256, 0, stream>>>(kv, qc, out0);
    gemm_bt<<<dim3(6, U / 128), 256, 0, stream>>>(
        out0, Wo_m, bo_m, projm, nullptr, nullptr, 1, U, 768, 0, 0);
    scatter_kernel<<<U, 256, 0, stream>>>(projm, nbidx, slot, out_feats);
}

// Round 20
// 1547.603 us; speedup vs baseline: 33.5532x; 1.0311x over previous
//
#include <hip/hip_runtime.h>
#include <hip/hip_bf16.h>
#include <stdint.h>

typedef __attribute__((ext_vector_type(8))) short short8;
typedef __attribute__((ext_vector_type(4))) float f32x4;

__device__ __forceinline__ float bf2f(uint16_t u) {
    union { uint32_t i; float f; } v; v.i = ((uint32_t)u) << 16; return v.f;
}
__device__ __forceinline__ uint16_t f2bf(float f) {
    union { float f; uint32_t i; } v; v.f = f;
    uint32_t r = v.i + 0x7fffu + ((v.i >> 16) & 1u);
    return (uint16_t)(r >> 16);
}
// fast f32x8 -> bf16x8 via v_cvt_pk_bf16_f32 (2 floats/inst incl. packing)
__device__ __forceinline__ short8 cvt8(const float* p) {
    const float2* f2 = (const float2*)p;
    union { __hip_bfloat162 h[4]; short8 s; } c;
    c.h[0] = __float22bfloat162_rn(f2[0]);
    c.h[1] = __float22bfloat162_rn(f2[1]);
    c.h[2] = __float22bfloat162_rn(f2[2]);
    c.h[3] = __float22bfloat162_rn(f2[3]);
    return c.s;
}

__global__ void code_write_f32(float* __restrict__ out, int n, float codef)
{
    int i = blockIdx.x * 256 + threadIdx.x;
    if (i < n) out[i] = codef;
}

// ---------- MFMA GEMM: C[M,N] = A[rowmap?][768] @ W[N,768]^T + bias (+R)(leaky) ----------
// 1-D grid, XCD-chunked decode: xcd = lid&7 owns contiguous bm range, bn fastest
// so all column-blocks of an A-panel run on ONE XCD (panel L2-resident once).
__global__ __launch_bounds__(256) void gemm_bt(
    const float* __restrict__ A, const float* __restrict__ W,
    const float* __restrict__ bias, void* __restrict__ Cv,
    const float* __restrict__ R, const int* __restrict__ rowmap, int rstride,
    int M, int N, int act, int cbf)
{
    const int K = 768;
    int numN = N >> 7;
    int numM = (M + 127) >> 7;
    int lid = blockIdx.x;
    int x = lid & 7, j = lid >> 3;
    int bm_local = j / numN, bn = j - bm_local * numN;
    int q = numM >> 3, rr = numM & 7;
    int cnt = q + (x < rr ? 1 : 0);
    if (bm_local >= cnt) return;
    int bm = x * q + min(x, rr) + bm_local;

    __shared__ __attribute__((aligned(16))) uint16_t As[4096];  // [128][32] bf16, swizzled
    __shared__ __attribute__((aligned(16))) uint16_t Ws[4096];
    int tid = threadIdx.x, wv = tid >> 6, ln = tid & 63;
    int wm = wv >> 1, wn = wv & 1;

    const f32x4 zero4 = {0.f, 0.f, 0.f, 0.f};
    f32x4 acc[4][4];
#pragma unroll
    for (int i = 0; i < 4; ++i)
#pragma unroll
        for (int jj = 0; jj < 4; ++jj) acc[i][jj] = zero4;

    int r0 = tid >> 2, cb = tid & 3;
    int c8 = cb * 8;
    int r1 = r0 + 64;
    int ar0 = min(bm * 128 + r0, M - 1);
    int ar1 = min(bm * 128 + r1, M - 1);
    if (rowmap) { ar0 = rowmap[(size_t)ar0 * rstride]; ar1 = rowmap[(size_t)ar1 * rstride]; }
    int br0 = bn * 128 + r0, br1 = bn * 128 + r1;
    const float* Af0 = A + (size_t)ar0 * K + c8;
    const float* Af1 = A + (size_t)ar1 * K + c8;
    const float* Wf0 = W + (size_t)br0 * K + c8;
    const float* Wf1 = W + (size_t)br1 * K + c8;
    const int sw  = (cb ^ (r0 & 3)) * 8;
    const int s0 = r0 * 32 + sw;
    const int s1 = 2048 + r0 * 32 + sw;
    const int lr = ln & 15, kg = ln >> 4;
    const int kgsw = (kg ^ (lr & 3)) * 8;

    for (int k0 = 0; k0 < K; k0 += 32) {
        short8 a0 = cvt8(Af0 + k0);
        short8 a1 = cvt8(Af1 + k0);
        short8 w0 = cvt8(Wf0 + k0);
        short8 w1 = cvt8(Wf1 + k0);
        __syncthreads();
        *(short8*)&As[s0] = a0;
        *(short8*)&As[s1] = a1;
        *(short8*)&Ws[s0] = w0;
        *(short8*)&Ws[s1] = w1;
        __syncthreads();
        short8 afr[4], bfr[4];
#pragma unroll
        for (int mi = 0; mi < 4; ++mi)
            afr[mi] = *(const short8*)&As[(wm * 64 + mi * 16 + lr) * 32 + kgsw];
#pragma unroll
        for (int nj = 0; nj < 4; ++nj)
            bfr[nj] = *(const short8*)&Ws[(wn * 64 + nj * 16 + lr) * 32 + kgsw];
#pragma unroll
        for (int mi = 0; mi < 4; ++mi)
#pragma unroll
            for (int nj = 0; nj < 4; ++nj)
                acc[mi][nj] = __builtin_amdgcn_mfma_f32_16x16x32_bf16(
                    afr[mi], bfr[nj], acc[mi][nj], 0, 0, 0);
    }

#pragma unroll
    for (int mi = 0; mi < 4; ++mi) {
        int growb = bm * 128 + wm * 64 + mi * 16 + kg * 4;
#pragma unroll
        for (int nj = 0; nj < 4; ++nj) {
            int gcol = bn * 128 + wn * 64 + nj * 16 + lr;
            float bs = bias ? bias[gcol] : 0.f;
#pragma unroll
            for (int qq = 0; qq < 4; ++qq) {
                int grow = growb + qq;
                if (grow < M) {
                    float val = acc[mi][nj][qq] + bs;
                    if (R) val += R[(size_t)grow * N + gcol];
                    if (act == 1) val = (val > 0.f) ? val : 0.01f * val;
                    size_t idx = (size_t)grow * N + gcol;
                    if (cbf) ((uint16_t*)Cv)[idx] = f2bf(val);
                    else     ((float*)Cv)[idx]    = val;
                }
            }
        }
    }
}

// ---------- LayerNorm (f32) ----------
__global__ __launch_bounds__(256) void ln_kernel(
    const float* __restrict__ x, const float* __restrict__ g,
    const float* __restrict__ bb, float* __restrict__ y)
{
    int row = blockIdx.x, tid = threadIdx.x;
    const float* xr = x + (size_t)row * 768;
    float v0 = xr[tid], v1 = xr[tid + 256], v2 = xr[tid + 512];
    float s = v0 + v1 + v2;
    __shared__ float red[4];
#pragma unroll
    for (int mk = 32; mk >= 1; mk >>= 1) s += __shfl_xor(s, mk);
    int wv = tid >> 6, ln = tid & 63;
    if (ln == 0) red[wv] = s;
    __syncthreads();
    float mu = (red[0] + red[1] + red[2] + red[3]) * (1.f / 768.f);
    float d0 = v0 - mu, d1 = v1 - mu, d2 = v2 - mu;
    float ss = d0 * d0 + d1 * d1 + d2 * d2;
#pragma unroll
    for (int mk = 32; mk >= 1; mk >>= 1) ss += __shfl_xor(ss, mk);
    __syncthreads();
    if (ln == 0) red[wv] = ss;
    __syncthreads();
    float var = (red[0] + red[1] + red[2] + red[3]) * (1.f / 768.f);
    float inv = 1.0f / sqrtf(var + 1e-5f);
    float* yr = y + (size_t)row * 768;
    yr[tid]       = d0 * inv * g[tid]       + bb[tid];
    yr[tid + 256] = d1 * inv * g[tid + 256] + bb[tid + 256];
    yr[tid + 512] = d2 * inv * g[tid + 512] + bb[tid + 512];
}

// ---------- wave-parallel text attention; one block per (b,i) ----------
__global__ __launch_bounds__(256) void nattn(
    const float* __restrict__ qkv, float* __restrict__ attnout,
    float* __restrict__ pooled)
{
    int b = blockIdx.x / 126, i = blockIdx.x % 126;
    int tid = threadIdx.x;
    __shared__ float P[4][128];
    __shared__ float poolloc[6];
    if (tid < 6) poolloc[tid] = 0.f;
    const size_t base = (size_t)b * 126 * 2304;
    const float scale = 0.0721687836f;

    for (int p = tid; p < 504; p += 256) {
        int h = p / 126, j = p - h * 126;
        const float* qr = qkv + base + (size_t)i * 2304 + h * 192;
        const float* kr = qkv + base + (size_t)j * 2304 + 768 + h * 192;
        float a = 0.f;
#pragma unroll 8
        for (int d = 0; d < 192; ++d) a += qr[d] * kr[d];
        P[h][j] = a * scale;
    }
    __syncthreads();

    {
        int w = tid >> 6, ln = tid & 63;
        bool v1 = (ln + 64) < 126;
        float s0 = P[w][ln];
        float s1 = v1 ? P[w][ln + 64] : -1e30f;
        float m = fmaxf(s0, s1);
#pragma unroll
        for (int mk = 32; mk >= 1; mk >>= 1) m = fmaxf(m, __shfl_xor(m, mk));
        float e0 = __expf(s0 - m);
        float e1 = v1 ? __expf(s1 - m) : 0.f;
        float z = e0 + e1;
#pragma unroll
        for (int mk = 32; mk >= 1; mk >>= 1) z += __shfl_xor(z, mk);
        float rz = 1.f / z;
        P[w][ln] = e0 * rz;
        if (v1) P[w][ln + 64] = e1 * rz;
    }
    __syncthreads();

    if (tid < 126) {
        float s4 = P[0][tid] + P[1][tid] + P[2][tid] + P[3][tid];
        atomicAdd(&poolloc[tid / 21], s4);
    }

    float o[3];
#pragma unroll
    for (int r = 0; r < 3; ++r) {
        int od = tid + r * 256;
        int h = od / 192;
        float a = 0.f;
        for (int j = 0; j < 126; ++j)
            a += P[h][j] * qkv[base + (size_t)j * 2304 + 1536 + od];
        o[r] = a;
    }
    float* orow = attnout + (size_t)(b * 126 + i) * 768;
#pragma unroll
    for (int r = 0; r < 3; ++r) orow[tid + r * 256] = o[r];

    __syncthreads();
    if (tid < 6)
        atomicAdd(&pooled[b * 36 + (i / 21) * 6 + tid], poolloc[tid]);
}

__global__ void pool_fin_kernel(const float* __restrict__ pooled, float* __restrict__ outp)
{
    int i = blockIdx.x * 36 + threadIdx.x;
    outp[i] = pooled[i] * (1.0f / 1764.0f);
}

// ---------- GCN prep ----------
__global__ void deg_fill_kernel(const int* __restrict__ ei, int E,
                                int* __restrict__ cnt, int* __restrict__ bucket)
{
    int e = blockIdx.x * 256 + threadIdx.x;
    if (e < E) {
        int s = ei[e], d = ei[E + e];
        int p = atomicAdd(&cnt[d], 1);
        if (p < 64) bucket[(size_t)d * 64 + p] = s;
    }
}
__global__ void dinv_kernel(const int* __restrict__ cnt, float* __restrict__ ds, int N)
{
    int i = blockIdx.x * 256 + threadIdx.x;
    if (i < N) ds[i] = 1.0f / sqrtf((float)cnt[i] + 1.0f);
}

// feats[v] = dinv[v]*( sum_src dinv[s]*h[s] + dinv[v]*h[v] ) + bg ; h bf16; nt writes
__global__ __launch_bounds__(256) void gcn_agg(
    const uint16_t* __restrict__ h, const int* __restrict__ bucket,
    const int* __restrict__ cnt, const float* __restrict__ dsc,
    const float* __restrict__ bg, float* __restrict__ feats)
{
    int v = blockIdx.x;
    int tid = threadIdx.x;
    __shared__ int nbs[64];
    int nb = min(cnt[v], 64);
    if (tid < nb)
        nbs[tid] = __builtin_nontemporal_load(&bucket[(size_t)v * 64 + tid]);
    __syncthreads();
    const uint16_t* hv = h + (size_t)v * 768;
    float sv = dsc[v];
    float a0 = bf2f(hv[tid]) * sv, a1 = bf2f(hv[tid + 256]) * sv, a2 = bf2f(hv[tid + 512]) * sv;
    for (int e = 0; e < nb; ++e) {
        int s = nbs[e];
        const uint16_t* hs = h + (size_t)s * 768;
        float ss = dsc[s];
        a0 += bf2f(hs[tid]) * ss; a1 += bf2f(hs[tid + 256]) * ss; a2 += bf2f(hs[tid + 512]) * ss;
    }
    float* o = feats + (size_t)v * 768;
    __builtin_nontemporal_store(a0 * sv + bg[tid],       &o[tid]);
    __builtin_nontemporal_store(a1 * sv + bg[tid + 256], &o[tid + 256]);
    __builtin_nontemporal_store(a2 * sv + bg[tid + 512], &o[tid + 512]);
}

// ---------- MultiAttn: 1 query (center row) x 32 keys ----------
__global__ __launch_bounds__(256) void attn_m_kernel(
    const float* __restrict__ kv, const float* __restrict__ qc,
    float* __restrict__ out0)
{
    int u = blockIdx.x;
    int tid = threadIdx.x, h = tid >> 6, ln = tid & 63;
    const float scale = 0.0721687836f;
    float s = -1e30f;
    {
        int j = (ln < 32) ? ln : 0;
        const float* qr = qc + (size_t)u * 768 + h * 192;
        const float* kr = kv + ((size_t)u * 32 + j) * 1536 + h * 192;
        float a = 0.f;
#pragma unroll 8
        for (int d = 0; d < 192; ++d) a += qr[d] * kr[d];
        if (ln < 32) s = a * scale;
    }
    float m = s;
#pragma unroll
    for (int mk = 32; mk >= 1; mk >>= 1) m = fmaxf(m, __shfl_xor(m, mk));
    float e = (ln < 32) ? __expf(s - m) : 0.f;
    float z = e;
#pragma unroll
    for (int mk = 32; mk >= 1; mk >>= 1) z += __shfl_xor(z, mk);
    __shared__ float pbuf[4][32];
    if (ln < 32) pbuf[h][ln] = e / z;
    __syncthreads();
    float a0 = 0.f, a1 = 0.f, a2 = 0.f;
    for (int j = 0; j < 32; ++j) {
        const float* vr = kv + ((size_t)u * 32 + j) * 1536 + 768 + h * 192;
        float p = pbuf[h][j];
        a0 += p * vr[ln]; a1 += p * vr[ln + 64]; a2 += p * vr[ln + 128];
    }
    float* o = out0 + (size_t)u * 768 + h * 192;
    o[ln] = a0; o[ln + 64] = a1; o[ln + 128] = a2;
}

// ---------- last-wins winner + scatter ----------
__global__ void winner_kernel(const int* __restrict__ nbidx, int* __restrict__ slot, int U)
{
    int u = blockIdx.x * 256 + threadIdx.x;
    if (u < U) atomicMax(&slot[nbidx[(size_t)u * 32]], u);
}
__global__ __launch_bounds__(256) void scatter_kernel(
    const float* __restrict__ proj, const int* __restrict__ nbidx,
    const int* __restrict__ slot, float* __restrict__ feats)
{
    int u = blockIdx.x;
    int c = nbidx[(size_t)u * 32];
    if (slot[c] != u) return;
    const float* src = proj + (size_t)u * 768;
    float* dst = feats + (size_t)c * 768;
    for (int t = threadIdx.x; t < 768; t += 256) dst[t] = src[t];
}

static inline int gemm_blocks(int M, int N) {
    int numM = (M + 127) >> 7, numN = N >> 7;
    return 8 * ((numM + 7) / 8) * numN;
}

extern "C" void kernel_launch(void* const* d_in, const int* in_sizes, int n_in,
                              void* d_out, int out_size, void* d_ws, size_t ws_size,
                              hipStream_t stream)
{
    const float* user_text = (const float*)d_in[0];
    const float* auf       = (const float*)d_in[1];
    const int*   nbidx     = (const int*)d_in[2];
    const int*   ei        = (const int*)d_in[3];
    const float* Wqkv_l = (const float*)d_in[4];
    const float* bqkv_l = (const float*)d_in[5];
    const float* Wo_l   = (const float*)d_in[6];
    const float* bo_l   = (const float*)d_in[7];
    const float* ln1_g  = (const float*)d_in[8];
    const float* ln1_b  = (const float*)d_in[9];
    const float* ln2_g  = (const float*)d_in[10];
    const float* ln2_b  = (const float*)d_in[11];
    const float* W1 = (const float*)d_in[12];
    const float* b1 = (const float*)d_in[13];
    const float* W2 = (const float*)d_in[14];
    const float* b2 = (const float*)d_in[15];
    const float* Wg = (const float*)d_in[16];
    const float* bg = (const float*)d_in[17];
    const float* Wqkv_m = (const float*)d_in[18];
    const float* bqkv_m = (const float*)d_in[19];
    const float* Wo_m   = (const float*)d_in[20];
    const float* bo_m   = (const float*)d_in[21];

    const int D  = 768;
    const int BS = in_sizes[0] / D;    // 1008
    const int B  = BS / 126;           // 8
    const int N  = in_sizes[1] / D;    // 100000
    const int U  = in_sizes[2] / 32;   // 1024
    const int E  = in_sizes[3] / 2;    // 1600000
    const int UK = U * 32;             // 32768

    float* out_text  = (float*)d_out;
    const int TEXTN = BS * D;
    const int WG_T = (TEXTN + 255) / 256;
    float* out_feats = out_text + (size_t)TEXTN;
    float* out_pool  = out_feats + (size_t)N * D;

    char* ws = (char*)d_ws;
    size_t off = 0;
    auto take = [&](size_t bytes) -> void* {
        void* p = ws + off;
        off += (bytes + 255) & ~(size_t)255;
        return p;
    };
    float* A_h    = (float*)take((size_t)N * D * 4);
    float* qkvl   = (float*)take((size_t)BS * 2304 * 4);
    float* ln1x   = (float*)take((size_t)BS * D * 4);
    float* attnout= (float*)take((size_t)BS * D * 4);
    float* text1  = (float*)take((size_t)BS * D * 4);
    float* ln2x   = (float*)take((size_t)BS * D * 4);
    float* qc     = (float*)take((size_t)U * D * 4);
    float* out0   = (float*)take((size_t)U * D * 4);
    float* projm  = (float*)take((size_t)U * D * 4);
    int*   cnt    = (int*)take((size_t)N * 4);
    float* dsc    = (float*)take((size_t)N * 4);
    int*   slot   = (int*)take((size_t)N * 4);
    int*   bucket = (int*)take((size_t)N * 64 * 4);
    float* pooled = (float*)take((size_t)B * 36 * 4);
    float* hmid   = ln1x;
    uint16_t* hbf = (uint16_t*)A_h;
    float* kv     = A_h;
    size_t required = off;

    if (ws_size < required) {
        code_write_f32<<<WG_T, 256, 0, stream>>>(out_text, TEXTN,
            1.0e6f + (float)(ws_size >> 20) * 1000.0f);
        return;
    }

    hipMemsetAsync(cnt, 0, (size_t)N * 4, stream);
    hipMemsetAsync(slot, 0xFF, (size_t)N * 4, stream);
    hipMemsetAsync(pooled, 0, (size_t)B * 36 * 4, stream);

    deg_fill_kernel<<<(E + 255) / 256, 256, 0, stream>>>(ei, E, cnt, bucket);
    dinv_kernel<<<(N + 255) / 256, 256, 0, stream>>>(cnt, dsc, N);

    // --- text path ---
    ln_kernel<<<BS, 256, 0, stream>>>(user_text, ln1_g, ln1_b, ln1x);
    gemm_bt<<<gemm_blocks(BS, 2304), 256, 0, stream>>>(
        ln1x, Wqkv_l, bqkv_l, qkvl, nullptr, nullptr, 1, BS, 2304, 0, 0);
    nattn<<<BS, 256, 0, stream>>>(qkvl, attnout, pooled);
    gemm_bt<<<gemm_blocks(BS, 768), 256, 0, stream>>>(
        attnout, Wo_l, bo_l, text1, user_text, nullptr, 1, BS, 768, 0, 0);
    ln_kernel<<<BS, 256, 0, stream>>>(text1, ln2_g, ln2_b, ln2x);
    gemm_bt<<<gemm_blocks(BS, 768), 256, 0, stream>>>(
        ln2x, W1, b1, hmid, nullptr, nullptr, 1, BS, 768, 1, 0);
    gemm_bt<<<gemm_blocks(BS, 768), 256, 0, stream>>>(
        hmid, W2, b2, out_text, text1, nullptr, 1, BS, 768, 0, 0);
    pool_fin_kernel<<<B, 36, 0, stream>>>(pooled, out_pool);

    // --- feats: rsqrt GCN (h bf16) ---
    gemm_bt<<<gemm_blocks(N, 768), 256, 0, stream>>>(
        auf, Wg, nullptr, hbf, nullptr, nullptr, 1, N, 768, 0, 1);
    gcn_agg<<<N, 256, 0, stream>>>(hbf, bucket, cnt, dsc, bg, out_feats);

    // --- MultiAttn, last-wins center writeback ---
    winner_kernel<<<(U + 255) / 256, 256, 0, stream>>>(nbidx, slot, U);
    gemm_bt<<<gemm_blocks(UK, 1536), 256, 0, stream>>>(
        out_feats, Wqkv_m + (size_t)768 * 768, bqkv_m + 768, kv, nullptr, nbidx, 1, UK, 1536, 0, 0);
    gemm_bt<<<gemm_blocks(U, 768), 256, 0, stream>>>(
        out_feats, Wqkv_m, bqkv_m, qc, nullptr, nbidx, 32, U, 768, 0, 0);
    attn_m_kernel<<<U, 256, 0, stream>>>(kv, qc, out0);
    gemm_bt<<<gemm_blocks(U, 768), 256, 0, stream>>>(
        out0, Wo_m, bo_m, projm, nullptr, nullptr, 1, U, 768, 0, 0);
    scatter_kernel<<<U, 256, 0, stream>>>(projm, nbidx, slot, out_feats);
}

// Round 22
// 1530.712 us; speedup vs baseline: 33.9234x; 1.0110x over previous
//
#include <hip/hip_runtime.h>
#include <hip/hip_bf16.h>
#include <stdint.h>

typedef __attribute__((ext_vector_type(8))) short short8;
typedef __attribute__((ext_vector_type(4))) float f32x4;
typedef __attribute__((ext_vector_type(2))) unsigned int u32x2;

__device__ __forceinline__ float bf2f(uint32_t u16) {
    union { uint32_t i; float f; } v; v.i = u16 << 16; return v.f;
}
__device__ __forceinline__ uint16_t f2bf(float f) {
    union { float f; uint32_t i; } v; v.f = f;
    uint32_t r = v.i + 0x7fffu + ((v.i >> 16) & 1u);
    return (uint16_t)(r >> 16);
}
// fast f32x8 -> bf16x8 via v_cvt_pk_bf16_f32
__device__ __forceinline__ short8 cvt8(const float* p) {
    const float2* f2 = (const float2*)p;
    union { __hip_bfloat162 h[4]; short8 s; } c;
    c.h[0] = __float22bfloat162_rn(f2[0]);
    c.h[1] = __float22bfloat162_rn(f2[1]);
    c.h[2] = __float22bfloat162_rn(f2[2]);
    c.h[3] = __float22bfloat162_rn(f2[3]);
    return c.s;
}

__global__ void code_write_f32(float* __restrict__ out, int n, float codef)
{
    int i = blockIdx.x * 256 + threadIdx.x;
    if (i < n) out[i] = codef;
}

// ---------- MFMA GEMM: C[M,N] = A[rowmap?][768] @ W[N,768]^T + bias (+R)(leaky) ----------
// 1-D grid, XCD-chunked decode (panel L2-locality); LDS XOR swizzle.
__global__ __launch_bounds__(256) void gemm_bt(
    const float* __restrict__ A, const float* __restrict__ W,
    const float* __restrict__ bias, void* __restrict__ Cv,
    const float* __restrict__ R, const int* __restrict__ rowmap, int rstride,
    int M, int N, int act, int cbf)
{
    const int K = 768;
    int numN = N >> 7;
    int numM = (M + 127) >> 7;
    int lid = blockIdx.x;
    int x = lid & 7, j = lid >> 3;
    int bm_local = j / numN, bn = j - bm_local * numN;
    int q = numM >> 3, rr = numM & 7;
    int cnt = q + (x < rr ? 1 : 0);
    if (bm_local >= cnt) return;
    int bm = x * q + min(x, rr) + bm_local;

    __shared__ __attribute__((aligned(16))) uint16_t As[4096];
    __shared__ __attribute__((aligned(16))) uint16_t Ws[4096];
    int tid = threadIdx.x, wv = tid >> 6, ln = tid & 63;
    int wm = wv >> 1, wn = wv & 1;

    const f32x4 zero4 = {0.f, 0.f, 0.f, 0.f};
    f32x4 acc[4][4];
#pragma unroll
    for (int i = 0; i < 4; ++i)
#pragma unroll
        for (int jj = 0; jj < 4; ++jj) acc[i][jj] = zero4;

    int r0 = tid >> 2, cb = tid & 3;
    int c8 = cb * 8;
    int r1 = r0 + 64;
    int ar0 = min(bm * 128 + r0, M - 1);
    int ar1 = min(bm * 128 + r1, M - 1);
    if (rowmap) { ar0 = rowmap[(size_t)ar0 * rstride]; ar1 = rowmap[(size_t)ar1 * rstride]; }
    int br0 = bn * 128 + r0, br1 = bn * 128 + r1;
    const float* Af0 = A + (size_t)ar0 * K + c8;
    const float* Af1 = A + (size_t)ar1 * K + c8;
    const float* Wf0 = W + (size_t)br0 * K + c8;
    const float* Wf1 = W + (size_t)br1 * K + c8;
    const int sw  = (cb ^ (r0 & 3)) * 8;
    const int s0 = r0 * 32 + sw;
    const int s1 = 2048 + r0 * 32 + sw;
    const int lr = ln & 15, kg = ln >> 4;
    const int kgsw = (kg ^ (lr & 3)) * 8;

    for (int k0 = 0; k0 < K; k0 += 32) {
        short8 a0 = cvt8(Af0 + k0);
        short8 a1 = cvt8(Af1 + k0);
        short8 w0 = cvt8(Wf0 + k0);
        short8 w1 = cvt8(Wf1 + k0);
        __syncthreads();
        *(short8*)&As[s0] = a0;
        *(short8*)&As[s1] = a1;
        *(short8*)&Ws[s0] = w0;
        *(short8*)&Ws[s1] = w1;
        __syncthreads();
        short8 afr[4], bfr[4];
#pragma unroll
        for (int mi = 0; mi < 4; ++mi)
            afr[mi] = *(const short8*)&As[(wm * 64 + mi * 16 + lr) * 32 + kgsw];
#pragma unroll
        for (int nj = 0; nj < 4; ++nj)
            bfr[nj] = *(const short8*)&Ws[(wn * 64 + nj * 16 + lr) * 32 + kgsw];
#pragma unroll
        for (int mi = 0; mi < 4; ++mi)
#pragma unroll
            for (int nj = 0; nj < 4; ++nj)
                acc[mi][nj] = __builtin_amdgcn_mfma_f32_16x16x32_bf16(
                    afr[mi], bfr[nj], acc[mi][nj], 0, 0, 0);
    }

#pragma unroll
    for (int mi = 0; mi < 4; ++mi) {
        int growb = bm * 128 + wm * 64 + mi * 16 + kg * 4;
#pragma unroll
        for (int nj = 0; nj < 4; ++nj) {
            int gcol = bn * 128 + wn * 64 + nj * 16 + lr;
            float bs = bias ? bias[gcol] : 0.f;
#pragma unroll
            for (int qq = 0; qq < 4; ++qq) {
                int grow = growb + qq;
                if (grow < M) {
                    float val = acc[mi][nj][qq] + bs;
                    if (R) val += R[(size_t)grow * N + gcol];
                    if (act == 1) val = (val > 0.f) ? val : 0.01f * val;
                    size_t idx = (size_t)grow * N + gcol;
                    if (cbf) ((uint16_t*)Cv)[idx] = f2bf(val);
                    else     ((float*)Cv)[idx]    = val;
                }
            }
        }
    }
}

// ---------- LayerNorm (f32) ----------
__global__ __launch_bounds__(256) void ln_kernel(
    const float* __restrict__ x, const float* __restrict__ g,
    const float* __restrict__ bb, float* __restrict__ y)
{
    int row = blockIdx.x, tid = threadIdx.x;
    const float* xr = x + (size_t)row * 768;
    float v0 = xr[tid], v1 = xr[tid + 256], v2 = xr[tid + 512];
    float s = v0 + v1 + v2;
    __shared__ float red[4];
#pragma unroll
    for (int mk = 32; mk >= 1; mk >>= 1) s += __shfl_xor(s, mk);
    int wv = tid >> 6, ln = tid & 63;
    if (ln == 0) red[wv] = s;
    __syncthreads();
    float mu = (red[0] + red[1] + red[2] + red[3]) * (1.f / 768.f);
    float d0 = v0 - mu, d1 = v1 - mu, d2 = v2 - mu;
    float ss = d0 * d0 + d1 * d1 + d2 * d2;
#pragma unroll
    for (int mk = 32; mk >= 1; mk >>= 1) ss += __shfl_xor(ss, mk);
    __syncthreads();
    if (ln == 0) red[wv] = ss;
    __syncthreads();
    float var = (red[0] + red[1] + red[2] + red[3]) * (1.f / 768.f);
    float inv = 1.0f / sqrtf(var + 1e-5f);
    float* yr = y + (size_t)row * 768;
    yr[tid]       = d0 * inv * g[tid]       + bb[tid];
    yr[tid + 256] = d1 * inv * g[tid + 256] + bb[tid + 256];
    yr[tid + 512] = d2 * inv * g[tid + 512] + bb[tid + 512];
}

// ---------- wave-parallel text attention; one block per (b,i) ----------
__global__ __launch_bounds__(256) void nattn(
    const float* __restrict__ qkv, float* __restrict__ attnout,
    float* __restrict__ pooled)
{
    int b = blockIdx.x / 126, i = blockIdx.x % 126;
    int tid = threadIdx.x;
    __shared__ float P[4][128];
    __shared__ float poolloc[6];
    if (tid < 6) poolloc[tid] = 0.f;
    const size_t base = (size_t)b * 126 * 2304;
    const float scale = 0.0721687836f;

    for (int p = tid; p < 504; p += 256) {
        int h = p / 126, j = p - h * 126;
        const float* qr = qkv + base + (size_t)i * 2304 + h * 192;
        const float* kr = qkv + base + (size_t)j * 2304 + 768 + h * 192;
        float a = 0.f;
#pragma unroll 8
        for (int d = 0; d < 192; ++d) a += qr[d] * kr[d];
        P[h][j] = a * scale;
    }
    __syncthreads();

    {
        int w = tid >> 6, ln = tid & 63;
        bool v1 = (ln + 64) < 126;
        float s0 = P[w][ln];
        float s1 = v1 ? P[w][ln + 64] : -1e30f;
        float m = fmaxf(s0, s1);
#pragma unroll
        for (int mk = 32; mk >= 1; mk >>= 1) m = fmaxf(m, __shfl_xor(m, mk));
        float e0 = __expf(s0 - m);
        float e1 = v1 ? __expf(s1 - m) : 0.f;
        float z = e0 + e1;
#pragma unroll
        for (int mk = 32; mk >= 1; mk >>= 1) z += __shfl_xor(z, mk);
        float rz = 1.f / z;
        P[w][ln] = e0 * rz;
        if (v1) P[w][ln + 64] = e1 * rz;
    }
    __syncthreads();

    if (tid < 126) {
        float s4 = P[0][tid] + P[1][tid] + P[2][tid] + P[3][tid];
        atomicAdd(&poolloc[tid / 21], s4);
    }

    float o[3];
#pragma unroll
    for (int r = 0; r < 3; ++r) {
        int od = tid + r * 256;
        int h = od / 192;
        float a = 0.f;
        for (int j = 0; j < 126; ++j)
            a += P[h][j] * qkv[base + (size_t)j * 2304 + 1536 + od];
        o[r] = a;
    }
    float* orow = attnout + (size_t)(b * 126 + i) * 768;
#pragma unroll
    for (int r = 0; r < 3; ++r) orow[tid + r * 256] = o[r];

    __syncthreads();
    if (tid < 6)
        atomicAdd(&pooled[b * 36 + (i / 21) * 6 + tid], poolloc[tid]);
}

__global__ void pool_fin_kernel(const float* __restrict__ pooled, float* __restrict__ outp)
{
    int i = blockIdx.x * 36 + threadIdx.x;
    outp[i] = pooled[i] * (1.0f / 1764.0f);
}

// ---------- GCN prep ----------
__global__ void deg_fill_kernel(const int* __restrict__ ei, int E,
                                int* __restrict__ cnt, int* __restrict__ bucket)
{
    int e = blockIdx.x * 256 + threadIdx.x;
    if (e < E) {
        int s = ei[e], d = ei[E + e];
        int p = atomicAdd(&cnt[d], 1);
        if (p < 64) bucket[(size_t)d * 64 + p] = s;
    }
}
__global__ void dinv_kernel(const int* __restrict__ cnt, float* __restrict__ ds, int N)
{
    int i = blockIdx.x * 256 + threadIdx.x;
    if (i < N) ds[i] = 1.0f / sqrtf((float)cnt[i] + 1.0f);
}

// feats[v] = dinv[v]*( sum_src dinv[s]*h[s] + dinv[v]*h[v] ) + bg ; h bf16.
// 192 thr: thread reads u32x2 (4 bf16, 8B/lane); writes f32x4 nt (16B/lane).
__global__ __launch_bounds__(192) void gcn_agg(
    const uint16_t* __restrict__ h, const int* __restrict__ bucket,
    const int* __restrict__ cnt, const float* __restrict__ dsc,
    const float* __restrict__ bg, float* __restrict__ feats)
{
    int v = blockIdx.x;
    int tid = threadIdx.x;
    __shared__ int nbs[64];
    int nb = min(cnt[v], 64);
    if (tid < nb)
        nbs[tid] = __builtin_nontemporal_load(&bucket[(size_t)v * 64 + tid]);
    __syncthreads();
    float sv = dsc[v];
    u32x2 w = ((const u32x2*)(h + (size_t)v * 768))[tid];
    float a0 = bf2f(w.x & 0xffffu) * sv;
    float a1 = bf2f(w.x >> 16)     * sv;
    float a2 = bf2f(w.y & 0xffffu) * sv;
    float a3 = bf2f(w.y >> 16)     * sv;
    for (int e = 0; e < nb; ++e) {
        int s = nbs[e];
        u32x2 u = ((const u32x2*)(h + (size_t)s * 768))[tid];
        float ss = dsc[s];
        a0 += bf2f(u.x & 0xffffu) * ss;
        a1 += bf2f(u.x >> 16)     * ss;
        a2 += bf2f(u.y & 0xffffu) * ss;
        a3 += bf2f(u.y >> 16)     * ss;
    }
    f32x4 bgv = ((const f32x4*)bg)[tid];
    f32x4 o;
    o.x = a0 * sv + bgv.x;
    o.y = a1 * sv + bgv.y;
    o.z = a2 * sv + bgv.z;
    o.w = a3 * sv + bgv.w;
    __builtin_nontemporal_store(o, &((f32x4*)(feats + (size_t)v * 768))[tid]);
}

// ---------- MultiAttn: 1 query (center row) x 32 keys ----------
__global__ __launch_bounds__(256) void attn_m_kernel(
    const float* __restrict__ kv, const float* __restrict__ qc,
    float* __restrict__ out0)
{
    int u = blockIdx.x;
    int tid = threadIdx.x, h = tid >> 6, ln = tid & 63;
    const float scale = 0.0721687836f;
    float s = -1e30f;
    {
        int j = (ln < 32) ? ln : 0;
        const float* qr = qc + (size_t)u * 768 + h * 192;
        const float* kr = kv + ((size_t)u * 32 + j) * 1536 + h * 192;
        float a = 0.f;
#pragma unroll 8
        for (int d = 0; d < 192; ++d) a += qr[d] * kr[d];
        if (ln < 32) s = a * scale;
    }
    float m = s;
#pragma unroll
    for (int mk = 32; mk >= 1; mk >>= 1) m = fmaxf(m, __shfl_xor(m, mk));
    float e = (ln < 32) ? __expf(s - m) : 0.f;
    float z = e;
#pragma unroll
    for (int mk = 32; mk >= 1; mk >>= 1) z += __shfl_xor(z, mk);
    __shared__ float pbuf[4][32];
    if (ln < 32) pbuf[h][ln] = e / z;
    __syncthreads();
    float a0 = 0.f, a1 = 0.f, a2 = 0.f;
    for (int j = 0; j < 32; ++j) {
        const float* vr = kv + ((size_t)u * 32 + j) * 1536 + 768 + h * 192;
        float p = pbuf[h][j];
        a0 += p * vr[ln]; a1 += p * vr[ln + 64]; a2 += p * vr[ln + 128];
    }
    float* o = out0 + (size_t)u * 768 + h * 192;
    o[ln] = a0; o[ln + 64] = a1; o[ln + 128] = a2;
}

// ---------- last-wins winner + scatter ----------
__global__ void winner_kernel(const int* __restrict__ nbidx, int* __restrict__ slot, int U)
{
    int u = blockIdx.x * 256 + threadIdx.x;
    if (u < U) atomicMax(&slot[nbidx[(size_t)u * 32]], u);
}
__global__ __launch_bounds__(256) void scatter_kernel(
    const float* __restrict__ proj, const int* __restrict__ nbidx,
    const int* __restrict__ slot, float* __restrict__ feats)
{
    int u = blockIdx.x;
    int c = nbidx[(size_t)u * 32];
    if (slot[c] != u) return;
    const float* src = proj + (size_t)u * 768;
    float* dst = feats + (size_t)c * 768;
    for (int t = threadIdx.x; t < 768; t += 256) dst[t] = src[t];
}

static inline int gemm_blocks(int M, int N) {
    int numM = (M + 127) >> 7, numN = N >> 7;
    return 8 * ((numM + 7) / 8) * numN;
}

extern "C" void kernel_launch(void* const* d_in, const int* in_sizes, int n_in,
                              void* d_out, int out_size, void* d_ws, size_t ws_size,
                              hipStream_t stream)
{
    const float* user_text = (const float*)d_in[0];
    const float* auf       = (const float*)d_in[1];
    const int*   nbidx     = (const int*)d_in[2];
    const int*   ei        = (const int*)d_in[3];
    const float* Wqkv_l = (const float*)d_in[4];
    const float* bqkv_l = (const float*)d_in[5];
    const float* Wo_l   = (const float*)d_in[6];
    const float* bo_l   = (const float*)d_in[7];
    const float* ln1_g  = (const float*)d_in[8];
    const float* ln1_b  = (const float*)d_in[9];
    const float* ln2_g  = (const float*)d_in[10];
    const float* ln2_b  = (const float*)d_in[11];
    const float* W1 = (const float*)d_in[12];
    const float* b1 = (const float*)d_in[13];
    const float* W2 = (const float*)d_in[14];
    const float* b2 = (const float*)d_in[15];
    const float* Wg = (const float*)d_in[16];
    const float* bg = (const float*)d_in[17];
    const float* Wqkv_m = (const float*)d_in[18];
    const float* bqkv_m = (const float*)d_in[19];
    const float* Wo_m   = (const float*)d_in[20];
    const float* bo_m   = (const float*)d_in[21];

    const int D  = 768;
    const int BS = in_sizes[0] / D;    // 1008
    const int B  = BS / 126;           // 8
    const int N  = in_sizes[1] / D;    // 100000
    const int U  = in_sizes[2] / 32;   // 1024
    const int E  = in_sizes[3] / 2;    // 1600000
    const int UK = U * 32;             // 32768

    float* out_text  = (float*)d_out;
    const int TEXTN = BS * D;
    const int WG_T = (TEXTN + 255) / 256;
    float* out_feats = out_text + (size_t)TEXTN;
    float* out_pool  = out_feats + (size_t)N * D;

    char* ws = (char*)d_ws;
    size_t off = 0;
    auto take = [&](size_t bytes) -> void* {
        void* p = ws + off;
        off += (bytes + 255) & ~(size_t)255;
        return p;
    };
    float* A_h    = (float*)take((size_t)N * D * 4);
    float* qkvl   = (float*)take((size_t)BS * 2304 * 4);
    float* ln1x   = (float*)take((size_t)BS * D * 4);
    float* attnout= (float*)take((size_t)BS * D * 4);
    float* text1  = (float*)take((size_t)BS * D * 4);
    float* ln2x   = (float*)take((size_t)BS * D * 4);
    float* qc     = (float*)take((size_t)U * D * 4);
    float* out0   = (float*)take((size_t)U * D * 4);
    float* projm  = (float*)take((size_t)U * D * 4);
    int*   cnt    = (int*)take((size_t)N * 4);
    float* dsc    = (float*)take((size_t)N * 4);
    int*   slot   = (int*)take((size_t)N * 4);
    int*   bucket = (int*)take((size_t)N * 64 * 4);
    float* pooled = (float*)take((size_t)B * 36 * 4);
    float* hmid   = ln1x;
    uint16_t* hbf = (uint16_t*)A_h;
    float* kv     = A_h;
    size_t required = off;

    if (ws_size < required) {
        code_write_f32<<<WG_T, 256, 0, stream>>>(out_text, TEXTN,
            1.0e6f + (float)(ws_size >> 20) * 1000.0f);
        return;
    }

    hipMemsetAsync(cnt, 0, (size_t)N * 4, stream);
    hipMemsetAsync(slot, 0xFF, (size_t)N * 4, stream);
    hipMemsetAsync(pooled, 0, (size_t)B * 36 * 4, stream);

    deg_fill_kernel<<<(E + 255) / 256, 256, 0, stream>>>(ei, E, cnt, bucket);
    dinv_kernel<<<(N + 255) / 256, 256, 0, stream>>>(cnt, dsc, N);

    // --- text path ---
    ln_kernel<<<BS, 256, 0, stream>>>(user_text, ln1_g, ln1_b, ln1x);
    gemm_bt<<<gemm_blocks(BS, 2304), 256, 0, stream>>>(
        ln1x, Wqkv_l, bqkv_l, qkvl, nullptr, nullptr, 1, BS, 2304, 0, 0);
    nattn<<<BS, 256, 0, stream>>>(qkvl, attnout, pooled);
    gemm_bt<<<gemm_blocks(BS, 768), 256, 0, stream>>>(
        attnout, Wo_l, bo_l, text1, user_text, nullptr, 1, BS, 768, 0, 0);
    ln_kernel<<<BS, 256, 0, stream>>>(text1, ln2_g, ln2_b, ln2x);
    gemm_bt<<<gemm_blocks(BS, 768), 256, 0, stream>>>(
        ln2x, W1, b1, hmid, nullptr, nullptr, 1, BS, 768, 1, 0);
    gemm_bt<<<gemm_blocks(BS, 768), 256, 0, stream>>>(
        hmid, W2, b2, out_text, text1, nullptr, 1, BS, 768, 0, 0);
    pool_fin_kernel<<<B, 36, 0, stream>>>(pooled, out_pool);

    // --- feats: rsqrt GCN (h bf16) ---
    gemm_bt<<<gemm_blocks(N, 768), 256, 0, stream>>>(
        auf, Wg, nullptr, hbf, nullptr, nullptr, 1, N, 768, 0, 1);
    gcn_agg<<<N, 192, 0, stream>>>(hbf, bucket, cnt, dsc, bg, out_feats);

    // --- MultiAttn, last-wins center writeback ---
    winner_kernel<<<(U + 255) / 256, 256, 0, stream>>>(nbidx, slot, U);
    gemm_bt<<<gemm_blocks(UK, 1536), 256, 0, stream>>>(
        out_feats, Wqkv_m + (size_t)768 * 768, bqkv_m + 768, kv, nullptr, nbidx, 1, UK, 1536, 0, 0);
    gemm_bt<<<gemm_blocks(U, 768), 256, 0, stream>>>(
        out_feats, Wqkv_m, bqkv_m, qc, nullptr, nbidx, 32, U, 768, 0, 0);
    attn_m_kernel<<<U, 256, 0, stream>>>(kv, qc, out0);
    gemm_bt<<<gemm_blocks(U, 768), 256, 0, stream>>>(
        out0, Wo_m, bo_m, projm, nullptr, nullptr, 1, U, 768, 0, 0);
    scatter_kernel<<<U, 256, 0, stream>>>(projm, nbidx, slot, out_feats);
}

// Round 23
// 1470.084 us; speedup vs baseline: 35.3225x; 1.0412x over previous
//
#include <hip/hip_runtime.h>
#include <hip/hip_bf16.h>
#include <stdint.h>

typedef __attribute__((ext_vector_type(8))) short short8;
typedef __attribute__((ext_vector_type(4))) float f32x4;
typedef __attribute__((ext_vector_type(2))) unsigned int u32x2;

__device__ __forceinline__ float bf2f(uint32_t u16) {
    union { uint32_t i; float f; } v; v.i = u16 << 16; return v.f;
}
__device__ __forceinline__ uint16_t f2bf(float f) {
    union { float f; uint32_t i; } v; v.f = f;
    uint32_t r = v.i + 0x7fffu + ((v.i >> 16) & 1u);
    return (uint16_t)(r >> 16);
}
// fast f32x8 -> bf16x8 via v_cvt_pk_bf16_f32
__device__ __forceinline__ short8 cvt8(const float* p) {
    const float2* f2 = (const float2*)p;
    union { __hip_bfloat162 h[4]; short8 s; } c;
    c.h[0] = __float22bfloat162_rn(f2[0]);
    c.h[1] = __float22bfloat162_rn(f2[1]);
    c.h[2] = __float22bfloat162_rn(f2[2]);
    c.h[3] = __float22bfloat162_rn(f2[3]);
    return c.s;
}

__global__ void code_write_f32(float* __restrict__ out, int n, float codef)
{
    int i = blockIdx.x * 256 + threadIdx.x;
    if (i < n) out[i] = codef;
}

// ---------- bulk f32 -> bf16 convert (8 elems/thread/iter) ----------
__global__ void f32_to_bf16(const float* __restrict__ in, uint16_t* __restrict__ out, size_t n8)
{
    size_t i = (size_t)blockIdx.x * 256 + threadIdx.x;
    for (; i < n8; i += (size_t)gridDim.x * 256)
        *(short8*)(out + i * 8) = cvt8(in + i * 8);
}

// ---------- MFMA GEMM: C[M,N] = A[rowmap?][768] @ Wb[N,768]^T + bias (+R)(leaky) ----------
// Wb is bf16. A is f32 (abf=0) or bf16 (abf=1). 1-D grid, XCD-chunked decode.
__global__ __launch_bounds__(256) void gemm_bt(
    const void* __restrict__ Av, int abf, const uint16_t* __restrict__ Wb,
    const float* __restrict__ bias, void* __restrict__ Cv,
    const float* __restrict__ R, const int* __restrict__ rowmap, int rstride,
    int M, int N, int act, int cbf)
{
    const int K = 768;
    int numN = N >> 7;
    int numM = (M + 127) >> 7;
    int lid = blockIdx.x;
    int x = lid & 7, j = lid >> 3;
    int bm_local = j / numN, bn = j - bm_local * numN;
    int q = numM >> 3, rr = numM & 7;
    int cnt = q + (x < rr ? 1 : 0);
    if (bm_local >= cnt) return;
    int bm = x * q + min(x, rr) + bm_local;

    __shared__ __attribute__((aligned(16))) uint16_t As[4096];
    __shared__ __attribute__((aligned(16))) uint16_t Ws[4096];
    int tid = threadIdx.x, wv = tid >> 6, ln = tid & 63;
    int wm = wv >> 1, wn = wv & 1;

    const f32x4 zero4 = {0.f, 0.f, 0.f, 0.f};
    f32x4 acc[4][4];
#pragma unroll
    for (int i = 0; i < 4; ++i)
#pragma unroll
        for (int jj = 0; jj < 4; ++jj) acc[i][jj] = zero4;

    int r0 = tid >> 2, cb = tid & 3;
    int c8 = cb * 8;
    int r1 = r0 + 64;
    int ar0 = min(bm * 128 + r0, M - 1);
    int ar1 = min(bm * 128 + r1, M - 1);
    if (rowmap) { ar0 = rowmap[(size_t)ar0 * rstride]; ar1 = rowmap[(size_t)ar1 * rstride]; }
    int br0 = bn * 128 + r0, br1 = bn * 128 + r1;
    const float*    Af0 = (const float*)Av + (size_t)ar0 * K + c8;
    const float*    Af1 = (const float*)Av + (size_t)ar1 * K + c8;
    const uint16_t* Ab0 = (const uint16_t*)Av + (size_t)ar0 * K + c8;
    const uint16_t* Ab1 = (const uint16_t*)Av + (size_t)ar1 * K + c8;
    const uint16_t* Wb0 = Wb + (size_t)br0 * K + c8;
    const uint16_t* Wb1 = Wb + (size_t)br1 * K + c8;
    const int sw  = (cb ^ (r0 & 3)) * 8;
    const int s0 = r0 * 32 + sw;
    const int s1 = 2048 + r0 * 32 + sw;
    const int lr = ln & 15, kg = ln >> 4;
    const int kgsw = (kg ^ (lr & 3)) * 8;

    for (int k0 = 0; k0 < K; k0 += 32) {
        short8 a0, a1;
        if (abf) {
            a0 = *(const short8*)(Ab0 + k0);
            a1 = *(const short8*)(Ab1 + k0);
        } else {
            a0 = cvt8(Af0 + k0);
            a1 = cvt8(Af1 + k0);
        }
        short8 w0 = *(const short8*)(Wb0 + k0);
        short8 w1 = *(const short8*)(Wb1 + k0);
        __syncthreads();
        *(short8*)&As[s0] = a0;
        *(short8*)&As[s1] = a1;
        *(short8*)&Ws[s0] = w0;
        *(short8*)&Ws[s1] = w1;
        __syncthreads();
        short8 afr[4], bfr[4];
#pragma unroll
        for (int mi = 0; mi < 4; ++mi)
            afr[mi] = *(const short8*)&As[(wm * 64 + mi * 16 + lr) * 32 + kgsw];
#pragma unroll
        for (int nj = 0; nj < 4; ++nj)
            bfr[nj] = *(const short8*)&Ws[(wn * 64 + nj * 16 + lr) * 32 + kgsw];
#pragma unroll
        for (int mi = 0; mi < 4; ++mi)
#pragma unroll
            for (int nj = 0; nj < 4; ++nj)
                acc[mi][nj] = __builtin_amdgcn_mfma_f32_16x16x32_bf16(
                    afr[mi], bfr[nj], acc[mi][nj], 0, 0, 0);
    }

#pragma unroll
    for (int mi = 0; mi < 4; ++mi) {
        int growb = bm * 128 + wm * 64 + mi * 16 + kg * 4;
#pragma unroll
        for (int nj = 0; nj < 4; ++nj) {
            int gcol = bn * 128 + wn * 64 + nj * 16 + lr;
            float bs = bias ? bias[gcol] : 0.f;
#pragma unroll
            for (int qq = 0; qq < 4; ++qq) {
                int grow = growb + qq;
                if (grow < M) {
                    float val = acc[mi][nj][qq] + bs;
                    if (R) val += R[(size_t)grow * N + gcol];
                    if (act == 1) val = (val > 0.f) ? val : 0.01f * val;
                    size_t idx = (size_t)grow * N + gcol;
                    if (cbf) ((uint16_t*)Cv)[idx] = f2bf(val);
                    else     ((float*)Cv)[idx]    = val;
                }
            }
        }
    }
}

// ---------- LayerNorm (f32) ----------
__global__ __launch_bounds__(256) void ln_kernel(
    const float* __restrict__ x, const float* __restrict__ g,
    const float* __restrict__ bb, float* __restrict__ y)
{
    int row = blockIdx.x, tid = threadIdx.x;
    const float* xr = x + (size_t)row * 768;
    float v0 = xr[tid], v1 = xr[tid + 256], v2 = xr[tid + 512];
    float s = v0 + v1 + v2;
    __shared__ float red[4];
#pragma unroll
    for (int mk = 32; mk >= 1; mk >>= 1) s += __shfl_xor(s, mk);
    int wv = tid >> 6, ln = tid & 63;
    if (ln == 0) red[wv] = s;
    __syncthreads();
    float mu = (red[0] + red[1] + red[2] + red[3]) * (1.f / 768.f);
    float d0 = v0 - mu, d1 = v1 - mu, d2 = v2 - mu;
    float ss = d0 * d0 + d1 * d1 + d2 * d2;
#pragma unroll
    for (int mk = 32; mk >= 1; mk >>= 1) ss += __shfl_xor(ss, mk);
    __syncthreads();
    if (ln == 0) red[wv] = ss;
    __syncthreads();
    float var = (red[0] + red[1] + red[2] + red[3]) * (1.f / 768.f);
    float inv = 1.0f / sqrtf(var + 1e-5f);
    float* yr = y + (size_t)row * 768;
    yr[tid]       = d0 * inv * g[tid]       + bb[tid];
    yr[tid + 256] = d1 * inv * g[tid + 256] + bb[tid + 256];
    yr[tid + 512] = d2 * inv * g[tid + 512] + bb[tid + 512];
}

// ---------- wave-parallel text attention; one block per (b,i) ----------
__global__ __launch_bounds__(256) void nattn(
    const float* __restrict__ qkv, float* __restrict__ attnout,
    float* __restrict__ pooled)
{
    int b = blockIdx.x / 126, i = blockIdx.x % 126;
    int tid = threadIdx.x;
    __shared__ float P[4][128];
    __shared__ float poolloc[6];
    if (tid < 6) poolloc[tid] = 0.f;
    const size_t base = (size_t)b * 126 * 2304;
    const float scale = 0.0721687836f;

    for (int p = tid; p < 504; p += 256) {
        int h = p / 126, j = p - h * 126;
        const float* qr = qkv + base + (size_t)i * 2304 + h * 192;
        const float* kr = qkv + base + (size_t)j * 2304 + 768 + h * 192;
        float a = 0.f;
#pragma unroll 8
        for (int d = 0; d < 192; ++d) a += qr[d] * kr[d];
        P[h][j] = a * scale;
    }
    __syncthreads();

    {
        int w = tid >> 6, ln = tid & 63;
        bool v1 = (ln + 64) < 126;
        float s0 = P[w][ln];
        float s1 = v1 ? P[w][ln + 64] : -1e30f;
        float m = fmaxf(s0, s1);
#pragma unroll
        for (int mk = 32; mk >= 1; mk >>= 1) m = fmaxf(m, __shfl_xor(m, mk));
        float e0 = __expf(s0 - m);
        float e1 = v1 ? __expf(s1 - m) : 0.f;
        float z = e0 + e1;
#pragma unroll
        for (int mk = 32; mk >= 1; mk >>= 1) z += __shfl_xor(z, mk);
        float rz = 1.f / z;
        P[w][ln] = e0 * rz;
        if (v1) P[w][ln + 64] = e1 * rz;
    }
    __syncthreads();

    if (tid < 126) {
        float s4 = P[0][tid] + P[1][tid] + P[2][tid] + P[3][tid];
        atomicAdd(&poolloc[tid / 21], s4);
    }

    float o[3];
#pragma unroll
    for (int r = 0; r < 3; ++r) {
        int od = tid + r * 256;
        int h = od / 192;
        float a = 0.f;
        for (int j = 0; j < 126; ++j)
            a += P[h][j] * qkv[base + (size_t)j * 2304 + 1536 + od];
        o[r] = a;
    }
    float* orow = attnout + (size_t)(b * 126 + i) * 768;
#pragma unroll
    for (int r = 0; r < 3; ++r) orow[tid + r * 256] = o[r];

    __syncthreads();
    if (tid < 6)
        atomicAdd(&pooled[b * 36 + (i / 21) * 6 + tid], poolloc[tid]);
}

__global__ void pool_fin_kernel(const float* __restrict__ pooled, float* __restrict__ outp)
{
    int i = blockIdx.x * 36 + threadIdx.x;
    outp[i] = pooled[i] * (1.0f / 1764.0f);
}

// ---------- GCN prep ----------
__global__ void deg_fill_kernel(const int* __restrict__ ei, int E,
                                int* __restrict__ cnt, int* __restrict__ bucket)
{
    int e = blockIdx.x * 256 + threadIdx.x;
    if (e < E) {
        int s = ei[e], d = ei[E + e];
        int p = atomicAdd(&cnt[d], 1);
        if (p < 64) bucket[(size_t)d * 64 + p] = s;
    }
}
__global__ void dinv_kernel(const int* __restrict__ cnt, float* __restrict__ ds, int N)
{
    int i = blockIdx.x * 256 + threadIdx.x;
    if (i < N) ds[i] = 1.0f / sqrtf((float)cnt[i] + 1.0f);
}

// feats[v] = dinv[v]*( sum_src dinv[s]*h[s] + dinv[v]*h[v] ) + bg ; h bf16.
// 192 thr; unroll-2 neighbor loop (2 outstanding gather streams); f32x4 nt store.
__global__ __launch_bounds__(192) void gcn_agg(
    const uint16_t* __restrict__ h, const int* __restrict__ bucket,
    const int* __restrict__ cnt, const float* __restrict__ dsc,
    const float* __restrict__ bg, float* __restrict__ feats)
{
    int v = blockIdx.x;
    int tid = threadIdx.x;
    __shared__ int nbs[64];
    int nb = min(cnt[v], 64);
    if (tid < nb)
        nbs[tid] = __builtin_nontemporal_load(&bucket[(size_t)v * 64 + tid]);
    __syncthreads();
    float sv = dsc[v];
    u32x2 w = ((const u32x2*)(h + (size_t)v * 768))[tid];
    float a0 = bf2f(w.x & 0xffffu) * sv;
    float a1 = bf2f(w.x >> 16)     * sv;
    float a2 = bf2f(w.y & 0xffffu) * sv;
    float a3 = bf2f(w.y >> 16)     * sv;
    float b0 = 0.f, b1 = 0.f, b2 = 0.f, b3 = 0.f;
    int e = 0;
    for (; e + 1 < nb; e += 2) {
        int sA = nbs[e], sB = nbs[e + 1];
        u32x2 uA = ((const u32x2*)(h + (size_t)sA * 768))[tid];
        u32x2 uB = ((const u32x2*)(h + (size_t)sB * 768))[tid];
        float ssA = dsc[sA], ssB = dsc[sB];
        a0 += bf2f(uA.x & 0xffffu) * ssA;
        a1 += bf2f(uA.x >> 16)     * ssA;
        a2 += bf2f(uA.y & 0xffffu) * ssA;
        a3 += bf2f(uA.y >> 16)     * ssA;
        b0 += bf2f(uB.x & 0xffffu) * ssB;
        b1 += bf2f(uB.x >> 16)     * ssB;
        b2 += bf2f(uB.y & 0xffffu) * ssB;
        b3 += bf2f(uB.y >> 16)     * ssB;
    }
    if (e < nb) {
        int sA = nbs[e];
        u32x2 uA = ((const u32x2*)(h + (size_t)sA * 768))[tid];
        float ssA = dsc[sA];
        a0 += bf2f(uA.x & 0xffffu) * ssA;
        a1 += bf2f(uA.x >> 16)     * ssA;
        a2 += bf2f(uA.y & 0xffffu) * ssA;
        a3 += bf2f(uA.y >> 16)     * ssA;
    }
    a0 += b0; a1 += b1; a2 += b2; a3 += b3;
    f32x4 bgv = ((const f32x4*)bg)[tid];
    f32x4 o;
    o.x = a0 * sv + bgv.x;
    o.y = a1 * sv + bgv.y;
    o.z = a2 * sv + bgv.z;
    o.w = a3 * sv + bgv.w;
    __builtin_nontemporal_store(o, &((f32x4*)(feats + (size_t)v * 768))[tid]);
}

// ---------- MultiAttn: 1 query (center row) x 32 keys ----------
__global__ __launch_bounds__(256) void attn_m_kernel(
    const float* __restrict__ kv, const float* __restrict__ qc,
    float* __restrict__ out0)
{
    int u = blockIdx.x;
    int tid = threadIdx.x, h = tid >> 6, ln = tid & 63;
    const float scale = 0.0721687836f;
    float s = -1e30f;
    {
        int j = (ln < 32) ? ln : 0;
        const float* qr = qc + (size_t)u * 768 + h * 192;
        const float* kr = kv + ((size_t)u * 32 + j) * 1536 + h * 192;
        float a = 0.f;
#pragma unroll 8
        for (int d = 0; d < 192; ++d) a += qr[d] * kr[d];
        if (ln < 32) s = a * scale;
    }
    float m = s;
#pragma unroll
    for (int mk = 32; mk >= 1; mk >>= 1) m = fmaxf(m, __shfl_xor(m, mk));
    float e = (ln < 32) ? __expf(s - m) : 0.f;
    float z = e;
#pragma unroll
    for (int mk = 32; mk >= 1; mk >>= 1) z += __shfl_xor(z, mk);
    __shared__ float pbuf[4][32];
    if (ln < 32) pbuf[h][ln] = e / z;
    __syncthreads();
    float a0 = 0.f, a1 = 0.f, a2 = 0.f;
    for (int j = 0; j < 32; ++j) {
        const float* vr = kv + ((size_t)u * 32 + j) * 1536 + 768 + h * 192;
        float p = pbuf[h][j];
        a0 += p * vr[ln]; a1 += p * vr[ln + 64]; a2 += p * vr[ln + 128];
    }
    float* o = out0 + (size_t)u * 768 + h * 192;
    o[ln] = a0; o[ln + 64] = a1; o[ln + 128] = a2;
}

// ---------- last-wins winner + scatter ----------
__global__ void winner_kernel(const int* __restrict__ nbidx, int* __restrict__ slot, int U)
{
    int u = blockIdx.x * 256 + threadIdx.x;
    if (u < U) atomicMax(&slot[nbidx[(size_t)u * 32]], u);
}
__global__ __launch_bounds__(256) void scatter_kernel(
    const float* __restrict__ proj, const int* __restrict__ nbidx,
    const int* __restrict__ slot, float* __restrict__ feats)
{
    int u = blockIdx.x;
    int c = nbidx[(size_t)u * 32];
    if (slot[c] != u) return;
    const float* src = proj + (size_t)u * 768;
    float* dst = feats + (size_t)c * 768;
    for (int t = threadIdx.x; t < 768; t += 256) dst[t] = src[t];
}

static inline int gemm_blocks(int M, int N) {
    int numM = (M + 127) >> 7, numN = N >> 7;
    return 8 * ((numM + 7) / 8) * numN;
}

extern "C" void kernel_launch(void* const* d_in, const int* in_sizes, int n_in,
                              void* d_out, int out_size, void* d_ws, size_t ws_size,
                              hipStream_t stream)
{
    const float* user_text = (const float*)d_in[0];
    const float* auf       = (const float*)d_in[1];
    const int*   nbidx     = (const int*)d_in[2];
    const int*   ei        = (const int*)d_in[3];
    const float* Wqkv_l = (const float*)d_in[4];
    const float* bqkv_l = (const float*)d_in[5];
    const float* Wo_l   = (const float*)d_in[6];
    const float* bo_l   = (const float*)d_in[7];
    const float* ln1_g  = (const float*)d_in[8];
    const float* ln1_b  = (const float*)d_in[9];
    const float* ln2_g  = (const float*)d_in[10];
    const float* ln2_b  = (const float*)d_in[11];
    const float* W1 = (const float*)d_in[12];
    const float* b1 = (const float*)d_in[13];
    const float* W2 = (const float*)d_in[14];
    const float* b2 = (const float*)d_in[15];
    const float* Wg = (const float*)d_in[16];
    const float* bg = (const float*)d_in[17];
    const float* Wqkv_m = (const float*)d_in[18];
    const float* bqkv_m = (const float*)d_in[19];
    const float* Wo_m   = (const float*)d_in[20];
    const float* bo_m   = (const float*)d_in[21];

    const int D  = 768;
    const int BS = in_sizes[0] / D;    // 1008
    const int B  = BS / 126;           // 8
    const int N  = in_sizes[1] / D;    // 100000
    const int U  = in_sizes[2] / 32;   // 1024
    const int E  = in_sizes[3] / 2;    // 1600000
    const int UK = U * 32;             // 32768

    float* out_text  = (float*)d_out;
    const int TEXTN = BS * D;
    const int WG_T = (TEXTN + 255) / 256;
    float* out_feats = out_text + (size_t)TEXTN;
    float* out_pool  = out_feats + (size_t)N * D;

    char* ws = (char*)d_ws;
    size_t off = 0;
    auto take = [&](size_t bytes) -> void* {
        void* p = ws + off;
        off += (bytes + 255) & ~(size_t)255;
        return p;
    };
    float* A_h    = (float*)take((size_t)N * D * 4);
    float* qkvl   = (float*)take((size_t)BS * 2304 * 4);
    float* ln1x   = (float*)take((size_t)BS * D * 4);
    float* attnout= (float*)take((size_t)BS * D * 4);
    float* text1  = (float*)take((size_t)BS * D * 4);
    float* ln2x   = (float*)take((size_t)BS * D * 4);
    float* qc     = (float*)take((size_t)U * D * 4);
    float* out0   = (float*)take((size_t)U * D * 4);
    float* projm  = (float*)take((size_t)U * D * 4);
    // bf16 weight copies
    uint16_t* Wqkv_l_b = (uint16_t*)take((size_t)2304 * 768 * 2);
    uint16_t* Wo_l_b   = (uint16_t*)take((size_t)768 * 768 * 2);
    uint16_t* W1_b     = (uint16_t*)take((size_t)768 * 768 * 2);
    uint16_t* W2_b     = (uint16_t*)take((size_t)768 * 768 * 2);
    uint16_t* Wg_b     = (uint16_t*)take((size_t)768 * 768 * 2);
    uint16_t* Wqkv_m_b = (uint16_t*)take((size_t)2304 * 768 * 2);
    uint16_t* Wo_m_b   = (uint16_t*)take((size_t)768 * 768 * 2);
    int*   cnt    = (int*)take((size_t)N * 4);
    float* dsc    = (float*)take((size_t)N * 4);
    int*   slot   = (int*)take((size_t)N * 4);
    int*   bucket = (int*)take((size_t)N * 64 * 4);
    float* pooled = (float*)take((size_t)B * 36 * 4);
    float* hmid   = ln1x;
    uint16_t* hbf = (uint16_t*)A_h;                       // bf16 h in low half of A_h
    uint16_t* auf_bf = (uint16_t*)A_h + (size_t)N * D;    // bf16 auf in high half
    float* kv     = A_h;                                   // kv reuses A_h after agg
    size_t required = off;

    if (ws_size < required) {
        code_write_f32<<<WG_T, 256, 0, stream>>>(out_text, TEXTN,
            1.0e6f + (float)(ws_size >> 20) * 1000.0f);
        return;
    }

    hipMemsetAsync(cnt, 0, (size_t)N * 4, stream);
    hipMemsetAsync(slot, 0xFF, (size_t)N * 4, stream);
    hipMemsetAsync(pooled, 0, (size_t)B * 36 * 4, stream);

    // --- pre-convert: auf and all weights to bf16 ---
    f32_to_bf16<<<2048, 256, 0, stream>>>(auf, auf_bf, (size_t)N * D / 8);
    f32_to_bf16<<<256, 256, 0, stream>>>(Wqkv_l, Wqkv_l_b, (size_t)2304 * 768 / 8);
    f32_to_bf16<<<128, 256, 0, stream>>>(Wo_l, Wo_l_b, (size_t)768 * 768 / 8);
    f32_to_bf16<<<128, 256, 0, stream>>>(W1, W1_b, (size_t)768 * 768 / 8);
    f32_to_bf16<<<128, 256, 0, stream>>>(W2, W2_b, (size_t)768 * 768 / 8);
    f32_to_bf16<<<128, 256, 0, stream>>>(Wg, Wg_b, (size_t)768 * 768 / 8);
    f32_to_bf16<<<256, 256, 0, stream>>>(Wqkv_m, Wqkv_m_b, (size_t)2304 * 768 / 8);
    f32_to_bf16<<<128, 256, 0, stream>>>(Wo_m, Wo_m_b, (size_t)768 * 768 / 8);

    deg_fill_kernel<<<(E + 255) / 256, 256, 0, stream>>>(ei, E, cnt, bucket);
    dinv_kernel<<<(N + 255) / 256, 256, 0, stream>>>(cnt, dsc, N);

    // --- text path ---
    ln_kernel<<<BS, 256, 0, stream>>>(user_text, ln1_g, ln1_b, ln1x);
    gemm_bt<<<gemm_blocks(BS, 2304), 256, 0, stream>>>(
        ln1x, 0, Wqkv_l_b, bqkv_l, qkvl, nullptr, nullptr, 1, BS, 2304, 0, 0);
    nattn<<<BS, 256, 0, stream>>>(qkvl, attnout, pooled);
    gemm_bt<<<gemm_blocks(BS, 768), 256, 0, stream>>>(
        attnout, 0, Wo_l_b, bo_l, text1, user_text, nullptr, 1, BS, 768, 0, 0);
    ln_kernel<<<BS, 256, 0, stream>>>(text1, ln2_g, ln2_b, ln2x);
    gemm_bt<<<gemm_blocks(BS, 768), 256, 0, stream>>>(
        ln2x, 0, W1_b, b1, hmid, nullptr, nullptr, 1, BS, 768, 1, 0);
    gemm_bt<<<gemm_blocks(BS, 768), 256, 0, stream>>>(
        hmid, 0, W2_b, b2, out_text, text1, nullptr, 1, BS, 768, 0, 0);
    pool_fin_kernel<<<B, 36, 0, stream>>>(pooled, out_pool);

    // --- feats: rsqrt GCN (bf16 A and W) ---
    gemm_bt<<<gemm_blocks(N, 768), 256, 0, stream>>>(
        auf_bf, 1, Wg_b, nullptr, hbf, nullptr, nullptr, 1, N, 768, 0, 1);
    gcn_agg<<<N, 192, 0, stream>>>(hbf, bucket, cnt, dsc, bg, out_feats);

    // --- MultiAttn, last-wins center writeback ---
    winner_kernel<<<(U + 255) / 256, 256, 0, stream>>>(nbidx, slot, U);
    gemm_bt<<<gemm_blocks(UK, 1536), 256, 0, stream>>>(
        out_feats, 0, Wqkv_m_b + (size_t)768 * 768, bqkv_m + 768, kv, nullptr, nbidx, 1, UK, 1536, 0, 0);
    gemm_bt<<<gemm_blocks(U, 768), 256, 0, stream>>>(
        out_feats, 0, Wqkv_m_b, bqkv_m, qc, nullptr, nbidx, 32, U, 768, 0, 0);
    attn_m_kernel<<<U, 256, 0, stream>>>(kv, qc, out0);
    gemm_bt<<<gemm_blocks(U, 768), 256, 0, stream>>>(
        out0, 0, Wo_m_b, bo_m, projm, nullptr, nullptr, 1, U, 768, 0, 0);
    scatter_kernel<<<U, 256, 0, stream>>>(projm, nbidx, slot, out_feats);
}

// Round 24
// 1465.018 us; speedup vs baseline: 35.4446x; 1.0035x over previous
//
#include <hip/hip_runtime.h>
#include <hip/hip_bf16.h>
#include <stdint.h>

typedef __attribute__((ext_vector_type(8))) short short8;
typedef __attribute__((ext_vector_type(4))) float f32x4;
typedef __attribute__((ext_vector_type(2))) unsigned int u32x2;

__device__ __forceinline__ float bf2f(uint32_t u16) {
    union { uint32_t i; float f; } v; v.i = u16 << 16; return v.f;
}
__device__ __forceinline__ uint16_t f2bf(float f) {
    union { float f; uint32_t i; } v; v.f = f;
    uint32_t r = v.i + 0x7fffu + ((v.i >> 16) & 1u);
    return (uint16_t)(r >> 16);
}
__device__ __forceinline__ short8 cvt8(const float* p) {
    const float2* f2 = (const float2*)p;
    union { __hip_bfloat162 h[4]; short8 s; } c;
    c.h[0] = __float22bfloat162_rn(f2[0]);
    c.h[1] = __float22bfloat162_rn(f2[1]);
    c.h[2] = __float22bfloat162_rn(f2[2]);
    c.h[3] = __float22bfloat162_rn(f2[3]);
    return c.s;
}

__global__ void code_write_f32(float* __restrict__ out, int n, float codef)
{
    int i = blockIdx.x * 256 + threadIdx.x;
    if (i < n) out[i] = codef;
}

__device__ __forceinline__ void cvt_seg(const float* __restrict__ in,
                                        uint16_t* __restrict__ out, size_t n8)
{
    for (size_t i = (size_t)blockIdx.x * 256 + threadIdx.x; i < n8;
         i += (size_t)gridDim.x * 256)
        *(short8*)(out + i * 8) = cvt8(in + i * 8);
}
// one launch converts auf + all 7 weights
__global__ void convert_all(
    const float* s0, uint16_t* d0, size_t n0,
    const float* s1, uint16_t* d1, size_t n1,
    const float* s2, uint16_t* d2, size_t n2,
    const float* s3, uint16_t* d3, size_t n3,
    const float* s4, uint16_t* d4, size_t n4,
    const float* s5, uint16_t* d5, size_t n5,
    const float* s6, uint16_t* d6, size_t n6,
    const float* s7, uint16_t* d7, size_t n7)
{
    cvt_seg(s0, d0, n0); cvt_seg(s1, d1, n1);
    cvt_seg(s2, d2, n2); cvt_seg(s3, d3, n3);
    cvt_seg(s4, d4, n4); cvt_seg(s5, d5, n5);
    cvt_seg(s6, d6, n6); cvt_seg(s7, d7, n7);
}

// ---------- MFMA GEMM: C[M,N] = A[rowmap?][768] @ Wb[N,768]^T + bias (+R)(leaky) ----------
__global__ __launch_bounds__(256) void gemm_bt(
    const void* __restrict__ Av, int abf, const uint16_t* __restrict__ Wb,
    const float* __restrict__ bias, void* __restrict__ Cv,
    const float* __restrict__ R, const int* __restrict__ rowmap, int rstride,
    int M, int N, int act, int cbf)
{
    const int K = 768;
    int numN = N >> 7;
    int numM = (M + 127) >> 7;
    int lid = blockIdx.x;
    int x = lid & 7, j = lid >> 3;
    int bm_local = j / numN, bn = j - bm_local * numN;
    int q = numM >> 3, rr = numM & 7;
    int cnt = q + (x < rr ? 1 : 0);
    if (bm_local >= cnt) return;
    int bm = x * q + min(x, rr) + bm_local;

    __shared__ __attribute__((aligned(16))) uint16_t As[4096];
    __shared__ __attribute__((aligned(16))) uint16_t Ws[4096];
    int tid = threadIdx.x, wv = tid >> 6, ln = tid & 63;
    int wm = wv >> 1, wn = wv & 1;

    const f32x4 zero4 = {0.f, 0.f, 0.f, 0.f};
    f32x4 acc[4][4];
#pragma unroll
    for (int i = 0; i < 4; ++i)
#pragma unroll
        for (int jj = 0; jj < 4; ++jj) acc[i][jj] = zero4;

    int r0 = tid >> 2, cb = tid & 3;
    int c8 = cb * 8;
    int r1 = r0 + 64;
    int ar0 = min(bm * 128 + r0, M - 1);
    int ar1 = min(bm * 128 + r1, M - 1);
    if (rowmap) { ar0 = rowmap[(size_t)ar0 * rstride]; ar1 = rowmap[(size_t)ar1 * rstride]; }
    int br0 = bn * 128 + r0, br1 = bn * 128 + r1;
    const float*    Af0 = (const float*)Av + (size_t)ar0 * K + c8;
    const float*    Af1 = (const float*)Av + (size_t)ar1 * K + c8;
    const uint16_t* Ab0 = (const uint16_t*)Av + (size_t)ar0 * K + c8;
    const uint16_t* Ab1 = (const uint16_t*)Av + (size_t)ar1 * K + c8;
    const uint16_t* Wb0 = Wb + (size_t)br0 * K + c8;
    const uint16_t* Wb1 = Wb + (size_t)br1 * K + c8;
    const int sw  = (cb ^ (r0 & 3)) * 8;
    const int s0 = r0 * 32 + sw;
    const int s1 = 2048 + r0 * 32 + sw;
    const int lr = ln & 15, kg = ln >> 4;
    const int kgsw = (kg ^ (lr & 3)) * 8;

    for (int k0 = 0; k0 < K; k0 += 32) {
        short8 a0, a1;
        if (abf) {
            a0 = *(const short8*)(Ab0 + k0);
            a1 = *(const short8*)(Ab1 + k0);
        } else {
            a0 = cvt8(Af0 + k0);
            a1 = cvt8(Af1 + k0);
        }
        short8 w0 = *(const short8*)(Wb0 + k0);
        short8 w1 = *(const short8*)(Wb1 + k0);
        __syncthreads();
        *(short8*)&As[s0] = a0;
        *(short8*)&As[s1] = a1;
        *(short8*)&Ws[s0] = w0;
        *(short8*)&Ws[s1] = w1;
        __syncthreads();
        short8 afr[4], bfr[4];
#pragma unroll
        for (int mi = 0; mi < 4; ++mi)
            afr[mi] = *(const short8*)&As[(wm * 64 + mi * 16 + lr) * 32 + kgsw];
#pragma unroll
        for (int nj = 0; nj < 4; ++nj)
            bfr[nj] = *(const short8*)&Ws[(wn * 64 + nj * 16 + lr) * 32 + kgsw];
#pragma unroll
        for (int mi = 0; mi < 4; ++mi)
#pragma unroll
            for (int nj = 0; nj < 4; ++nj)
                acc[mi][nj] = __builtin_amdgcn_mfma_f32_16x16x32_bf16(
                    afr[mi], bfr[nj], acc[mi][nj], 0, 0, 0);
    }

#pragma unroll
    for (int mi = 0; mi < 4; ++mi) {
        int growb = bm * 128 + wm * 64 + mi * 16 + kg * 4;
#pragma unroll
        for (int nj = 0; nj < 4; ++nj) {
            int gcol = bn * 128 + wn * 64 + nj * 16 + lr;
            float bs = bias ? bias[gcol] : 0.f;
#pragma unroll
            for (int qq = 0; qq < 4; ++qq) {
                int grow = growb + qq;
                if (grow < M) {
                    float val = acc[mi][nj][qq] + bs;
                    if (R) val += R[(size_t)grow * N + gcol];
                    if (act == 1) val = (val > 0.f) ? val : 0.01f * val;
                    size_t idx = (size_t)grow * N + gcol;
                    if (cbf) ((uint16_t*)Cv)[idx] = f2bf(val);
                    else     ((float*)Cv)[idx]    = val;
                }
            }
        }
    }
}

// ---------- LayerNorm (f32) ----------
__global__ __launch_bounds__(256) void ln_kernel(
    const float* __restrict__ x, const float* __restrict__ g,
    const float* __restrict__ bb, float* __restrict__ y)
{
    int row = blockIdx.x, tid = threadIdx.x;
    const float* xr = x + (size_t)row * 768;
    float v0 = xr[tid], v1 = xr[tid + 256], v2 = xr[tid + 512];
    float s = v0 + v1 + v2;
    __shared__ float red[4];
#pragma unroll
    for (int mk = 32; mk >= 1; mk >>= 1) s += __shfl_xor(s, mk);
    int wv = tid >> 6, ln = tid & 63;
    if (ln == 0) red[wv] = s;
    __syncthreads();
    float mu = (red[0] + red[1] + red[2] + red[3]) * (1.f / 768.f);
    float d0 = v0 - mu, d1 = v1 - mu, d2 = v2 - mu;
    float ss = d0 * d0 + d1 * d1 + d2 * d2;
#pragma unroll
    for (int mk = 32; mk >= 1; mk >>= 1) ss += __shfl_xor(ss, mk);
    __syncthreads();
    if (ln == 0) red[wv] = ss;
    __syncthreads();
    float var = (red[0] + red[1] + red[2] + red[3]) * (1.f / 768.f);
    float inv = 1.0f / sqrtf(var + 1e-5f);
    float* yr = y + (size_t)row * 768;
    yr[tid]       = d0 * inv * g[tid]       + bb[tid];
    yr[tid + 256] = d1 * inv * g[tid + 256] + bb[tid + 256];
    yr[tid + 512] = d2 * inv * g[tid + 512] + bb[tid + 512];
}

// ---------- wave-parallel text attention; one block per (b,i) ----------
__global__ __launch_bounds__(256) void nattn(
    const float* __restrict__ qkv, float* __restrict__ attnout,
    float* __restrict__ pooled)
{
    int b = blockIdx.x / 126, i = blockIdx.x % 126;
    int tid = threadIdx.x;
    __shared__ float P[4][128];
    __shared__ float poolloc[6];
    if (tid < 6) poolloc[tid] = 0.f;
    const size_t base = (size_t)b * 126 * 2304;
    const float scale = 0.0721687836f;

    for (int p = tid; p < 504; p += 256) {
        int h = p / 126, j = p - h * 126;
        const float* qr = qkv + base + (size_t)i * 2304 + h * 192;
        const float* kr = qkv + base + (size_t)j * 2304 + 768 + h * 192;
        float a = 0.f;
#pragma unroll 8
        for (int d = 0; d < 192; ++d) a += qr[d] * kr[d];
        P[h][j] = a * scale;
    }
    __syncthreads();

    {
        int w = tid >> 6, ln = tid & 63;
        bool v1 = (ln + 64) < 126;
        float s0 = P[w][ln];
        float s1 = v1 ? P[w][ln + 64] : -1e30f;
        float m = fmaxf(s0, s1);
#pragma unroll
        for (int mk = 32; mk >= 1; mk >>= 1) m = fmaxf(m, __shfl_xor(m, mk));
        float e0 = __expf(s0 - m);
        float e1 = v1 ? __expf(s1 - m) : 0.f;
        float z = e0 + e1;
#pragma unroll
        for (int mk = 32; mk >= 1; mk >>= 1) z += __shfl_xor(z, mk);
        float rz = 1.f / z;
        P[w][ln] = e0 * rz;
        if (v1) P[w][ln + 64] = e1 * rz;
    }
    __syncthreads();

    if (tid < 126) {
        float s4 = P[0][tid] + P[1][tid] + P[2][tid] + P[3][tid];
        atomicAdd(&poolloc[tid / 21], s4);
    }

    float o[3];
#pragma unroll
    for (int r = 0; r < 3; ++r) {
        int od = tid + r * 256;
        int h = od / 192;
        float a = 0.f;
        for (int j = 0; j < 126; ++j)
            a += P[h][j] * qkv[base + (size_t)j * 2304 + 1536 + od];
        o[r] = a;
    }
    float* orow = attnout + (size_t)(b * 126 + i) * 768;
#pragma unroll
    for (int r = 0; r < 3; ++r) orow[tid + r * 256] = o[r];

    __syncthreads();
    if (tid < 6)
        atomicAdd(&pooled[b * 36 + (i / 21) * 6 + tid], poolloc[tid]);
}

__global__ void pool_fin_kernel(const float* __restrict__ pooled, float* __restrict__ outp)
{
    int i = blockIdx.x * 36 + threadIdx.x;
    outp[i] = pooled[i] * (1.0f / 1764.0f);
}

// ---------- GCN prep ----------
__global__ void deg_fill_kernel(const int* __restrict__ ei, int E,
                                int* __restrict__ cnt, int* __restrict__ bucket)
{
    int e = blockIdx.x * 256 + threadIdx.x;
    if (e < E) {
        int s = ei[e], d = ei[E + e];
        int p = atomicAdd(&cnt[d], 1);
        if (p < 64) bucket[(size_t)d * 64 + p] = s;
    }
}
__global__ void dinv_kernel(const int* __restrict__ cnt, float* __restrict__ ds, int N)
{
    int i = blockIdx.x * 256 + threadIdx.x;
    if (i < N) ds[i] = 1.0f / sqrtf((float)cnt[i] + 1.0f);
}

// feats[v] = dinv[v]*( sum_src dinv[s]*h[s] + dinv[v]*h[v] ) + bg ; h bf16.
// 192 thr; unroll-4 neighbor loop (4 outstanding gather streams); f32x4 nt store.
__global__ __launch_bounds__(192) void gcn_agg(
    const uint16_t* __restrict__ h, const int* __restrict__ bucket,
    const int* __restrict__ cnt, const float* __restrict__ dsc,
    const float* __restrict__ bg, float* __restrict__ feats)
{
    int v = blockIdx.x;
    int tid = threadIdx.x;
    __shared__ int nbs[64];
    int nb = min(cnt[v], 64);
    if (tid < nb)
        nbs[tid] = __builtin_nontemporal_load(&bucket[(size_t)v * 64 + tid]);
    __syncthreads();
    float sv = dsc[v];
    u32x2 w = ((const u32x2*)(h + (size_t)v * 768))[tid];
    float a0 = bf2f(w.x & 0xffffu) * sv;
    float a1 = bf2f(w.x >> 16)     * sv;
    float a2 = bf2f(w.y & 0xffffu) * sv;
    float a3 = bf2f(w.y >> 16)     * sv;
    float b0 = 0.f, b1 = 0.f, b2 = 0.f, b3 = 0.f;
    float c0 = 0.f, c1 = 0.f, c2 = 0.f, c3 = 0.f;
    float d0 = 0.f, d1 = 0.f, d2 = 0.f, d3 = 0.f;
    int e = 0;
    for (; e + 3 < nb; e += 4) {
        int sA = nbs[e], sB = nbs[e + 1], sC = nbs[e + 2], sD = nbs[e + 3];
        u32x2 uA = ((const u32x2*)(h + (size_t)sA * 768))[tid];
        u32x2 uB = ((const u32x2*)(h + (size_t)sB * 768))[tid];
        u32x2 uC = ((const u32x2*)(h + (size_t)sC * 768))[tid];
        u32x2 uD = ((const u32x2*)(h + (size_t)sD * 768))[tid];
        float ssA = dsc[sA], ssB = dsc[sB], ssC = dsc[sC], ssD = dsc[sD];
        a0 += bf2f(uA.x & 0xffffu) * ssA; a1 += bf2f(uA.x >> 16) * ssA;
        a2 += bf2f(uA.y & 0xffffu) * ssA; a3 += bf2f(uA.y >> 16) * ssA;
        b0 += bf2f(uB.x & 0xffffu) * ssB; b1 += bf2f(uB.x >> 16) * ssB;
        b2 += bf2f(uB.y & 0xffffu) * ssB; b3 += bf2f(uB.y >> 16) * ssB;
        c0 += bf2f(uC.x & 0xffffu) * ssC; c1 += bf2f(uC.x >> 16) * ssC;
        c2 += bf2f(uC.y & 0xffffu) * ssC; c3 += bf2f(uC.y >> 16) * ssC;
        d0 += bf2f(uD.x & 0xffffu) * ssD; d1 += bf2f(uD.x >> 16) * ssD;
        d2 += bf2f(uD.y & 0xffffu) * ssD; d3 += bf2f(uD.y >> 16) * ssD;
    }
    for (; e < nb; ++e) {
        int sA = nbs[e];
        u32x2 uA = ((const u32x2*)(h + (size_t)sA * 768))[tid];
        float ssA = dsc[sA];
        a0 += bf2f(uA.x & 0xffffu) * ssA; a1 += bf2f(uA.x >> 16) * ssA;
        a2 += bf2f(uA.y & 0xffffu) * ssA; a3 += bf2f(uA.y >> 16) * ssA;
    }
    a0 += b0 + c0 + d0; a1 += b1 + c1 + d1;
    a2 += b2 + c2 + d2; a3 += b3 + c3 + d3;
    f32x4 bgv = ((const f32x4*)bg)[tid];
    f32x4 o;
    o.x = a0 * sv + bgv.x;
    o.y = a1 * sv + bgv.y;
    o.z = a2 * sv + bgv.z;
    o.w = a3 * sv + bgv.w;
    __builtin_nontemporal_store(o, &((f32x4*)(feats + (size_t)v * 768))[tid]);
}

// ---------- MultiAttn: 1 query (center row) x 32 keys ----------
__global__ __launch_bounds__(256) void attn_m_kernel(
    const float* __restrict__ kv, const float* __restrict__ qc,
    float* __restrict__ out0)
{
    int u = blockIdx.x;
    int tid = threadIdx.x, h = tid >> 6, ln = tid & 63;
    const float scale = 0.0721687836f;
    float s = -1e30f;
    {
        int j = (ln < 32) ? ln : 0;
        const float* qr = qc + (size_t)u * 768 + h * 192;
        const float* kr = kv + ((size_t)u * 32 + j) * 1536 + h * 192;
        float a = 0.f;
#pragma unroll 8
        for (int d = 0; d < 192; ++d) a += qr[d] * kr[d];
        if (ln < 32) s = a * scale;
    }
    float m = s;
#pragma unroll
    for (int mk = 32; mk >= 1; mk >>= 1) m = fmaxf(m, __shfl_xor(m, mk));
    float e = (ln < 32) ? __expf(s - m) : 0.f;
    float z = e;
#pragma unroll
    for (int mk = 32; mk >= 1; mk >>= 1) z += __shfl_xor(z, mk);
    __shared__ float pbuf[4][32];
    if (ln < 32) pbuf[h][ln] = e / z;
    __syncthreads();
    float a0 = 0.f, a1 = 0.f, a2 = 0.f;
    for (int j = 0; j < 32; ++j) {
        const float* vr = kv + ((size_t)u * 32 + j) * 1536 + 768 + h * 192;
        float p = pbuf[h][j];
        a0 += p * vr[ln]; a1 += p * vr[ln + 64]; a2 += p * vr[ln + 128];
    }
    float* o = out0 + (size_t)u * 768 + h * 192;
    o[ln] = a0; o[ln + 64] = a1; o[ln + 128] = a2;
}

// ---------- last-wins winner + scatter ----------
__global__ void winner_kernel(const int* __restrict__ nbidx, int* __restrict__ slot, int U)
{
    int u = blockIdx.x * 256 + threadIdx.x;
    if (u < U) atomicMax(&slot[nbidx[(size_t)u * 32]], u);
}
__global__ __launch_bounds__(256) void scatter_kernel(
    const float* __restrict__ proj, const int* __restrict__ nbidx,
    const int* __restrict__ slot, float* __restrict__ feats)
{
    int u = blockIdx.x;
    int c = nbidx[(size_t)u * 32];
    if (slot[c] != u) return;
    const float* src = proj + (size_t)u * 768;
    float* dst = feats + (size_t)c * 768;
    for (int t = threadIdx.x; t < 768; t += 256) dst[t] = src[t];
}

static inline int gemm_blocks(int M, int N) {
    int numM = (M + 127) >> 7, numN = N >> 7;
    return 8 * ((numM + 7) / 8) * numN;
}

extern "C" void kernel_launch(void* const* d_in, const int* in_sizes, int n_in,
                              void* d_out, int out_size, void* d_ws, size_t ws_size,
                              hipStream_t stream)
{
    const float* user_text = (const float*)d_in[0];
    const float* auf       = (const float*)d_in[1];
    const int*   nbidx     = (const int*)d_in[2];
    const int*   ei        = (const int*)d_in[3];
    const float* Wqkv_l = (const float*)d_in[4];
    const float* bqkv_l = (const float*)d_in[5];
    const float* Wo_l   = (const float*)d_in[6];
    const float* bo_l   = (const float*)d_in[7];
    const float* ln1_g  = (const float*)d_in[8];
    const float* ln1_b  = (const float*)d_in[9];
    const float* ln2_g  = (const float*)d_in[10];
    const float* ln2_b  = (const float*)d_in[11];
    const float* W1 = (const float*)d_in[12];
    const float* b1 = (const float*)d_in[13];
    const float* W2 = (const float*)d_in[14];
    const float* b2 = (const float*)d_in[15];
    const float* Wg = (const float*)d_in[16];
    const float* bg = (const float*)d_in[17];
    const float* Wqkv_m = (const float*)d_in[18];
    const float* bqkv_m = (const float*)d_in[19];
    const float* Wo_m   = (const float*)d_in[20];
    const float* bo_m   = (const float*)d_in[21];

    const int D  = 768;
    const int BS = in_sizes[0] / D;    // 1008
    const int B  = BS / 126;           // 8
    const int N  = in_sizes[1] / D;    // 100000
    const int U  = in_sizes[2] / 32;   // 1024
    const int E  = in_sizes[3] / 2;    // 1600000
    const int UK = U * 32;             // 32768

    float* out_text  = (float*)d_out;
    const int TEXTN = BS * D;
    const int WG_T = (TEXTN + 255) / 256;
    float* out_feats = out_text + (size_t)TEXTN;
    float* out_pool  = out_feats + (size_t)N * D;

    char* ws = (char*)d_ws;
    size_t off = 0;
    auto take = [&](size_t bytes) -> void* {
        void* p = ws + off;
        off += (bytes + 255) & ~(size_t)255;
        return p;
    };
    float* A_h    = (float*)take((size_t)N * D * 4);
    float* qkvl   = (float*)take((size_t)BS * 2304 * 4);
    float* ln1x   = (float*)take((size_t)BS * D * 4);
    float* attnout= (float*)take((size_t)BS * D * 4);
    float* text1  = (float*)take((size_t)BS * D * 4);
    float* ln2x   = (float*)take((size_t)BS * D * 4);
    float* qc     = (float*)take((size_t)U * D * 4);
    float* out0   = (float*)take((size_t)U * D * 4);
    float* projm  = (float*)take((size_t)U * D * 4);
    uint16_t* Wqkv_l_b = (uint16_t*)take((size_t)2304 * 768 * 2);
    uint16_t* Wo_l_b   = (uint16_t*)take((size_t)768 * 768 * 2);
    uint16_t* W1_b     = (uint16_t*)take((size_t)768 * 768 * 2);
    uint16_t* W2_b     = (uint16_t*)take((size_t)768 * 768 * 2);
    uint16_t* Wg_b     = (uint16_t*)take((size_t)768 * 768 * 2);
    uint16_t* Wqkv_m_b = (uint16_t*)take((size_t)2304 * 768 * 2);
    uint16_t* Wo_m_b   = (uint16_t*)take((size_t)768 * 768 * 2);
    int*   cnt    = (int*)take((size_t)N * 4);
    float* dsc    = (float*)take((size_t)N * 4);
    int*   slot   = (int*)take((size_t)N * 4);
    int*   bucket = (int*)take((size_t)N * 64 * 4);
    float* pooled = (float*)take((size_t)B * 36 * 4);
    float* hmid   = ln1x;
    uint16_t* hbf = (uint16_t*)A_h;
    uint16_t* auf_bf = (uint16_t*)A_h + (size_t)N * D;
    float* kv     = A_h;
    size_t required = off;

    if (ws_size < required) {
        code_write_f32<<<WG_T, 256, 0, stream>>>(out_text, TEXTN,
            1.0e6f + (float)(ws_size >> 20) * 1000.0f);
        return;
    }

    hipMemsetAsync(cnt, 0, (size_t)N * 4, stream);
    hipMemsetAsync(slot, 0xFF, (size_t)N * 4, stream);
    hipMemsetAsync(pooled, 0, (size_t)B * 36 * 4, stream);

    // --- one-launch convert: auf + all weights -> bf16 ---
    convert_all<<<2048, 256, 0, stream>>>(
        auf, auf_bf, (size_t)N * D / 8,
        Wqkv_l, Wqkv_l_b, (size_t)2304 * 768 / 8,
        Wo_l, Wo_l_b, (size_t)768 * 768 / 8,
        W1, W1_b, (size_t)768 * 768 / 8,
        W2, W2_b, (size_t)768 * 768 / 8,
        Wg, Wg_b, (size_t)768 * 768 / 8,
        Wqkv_m, Wqkv_m_b, (size_t)2304 * 768 / 8,
        Wo_m, Wo_m_b, (size_t)768 * 768 / 8);

    deg_fill_kernel<<<(E + 255) / 256, 256, 0, stream>>>(ei, E, cnt, bucket);
    dinv_kernel<<<(N + 255) / 256, 256, 0, stream>>>(cnt, dsc, N);

    // --- text path ---
    ln_kernel<<<BS, 256, 0, stream>>>(user_text, ln1_g, ln1_b, ln1x);
    gemm_bt<<<gemm_blocks(BS, 2304), 256, 0, stream>>>(
        ln1x, 0, Wqkv_l_b, bqkv_l, qkvl, nullptr, nullptr, 1, BS, 2304, 0, 0);
    nattn<<<BS, 256, 0, stream>>>(qkvl, attnout, pooled);
    gemm_bt<<<gemm_blocks(BS, 768), 256, 0, stream>>>(
        attnout, 0, Wo_l_b, bo_l, text1, user_text, nullptr, 1, BS, 768, 0, 0);
    ln_kernel<<<BS, 256, 0, stream>>>(text1, ln2_g, ln2_b, ln2x);
    gemm_bt<<<gemm_blocks(BS, 768), 256, 0, stream>>>(
        ln2x, 0, W1_b, b1, hmid, nullptr, nullptr, 1, BS, 768, 1, 0);
    gemm_bt<<<gemm_blocks(BS, 768), 256, 0, stream>>>(
        hmid, 0, W2_b, b2, out_text, text1, nullptr, 1, BS, 768, 0, 0);
    pool_fin_kernel<<<B, 36, 0, stream>>>(pooled, out_pool);

    // --- feats: rsqrt GCN (bf16 A and W) ---
    gemm_bt<<<gemm_blocks(N, 768), 256, 0, stream>>>(
        auf_bf, 1, Wg_b, nullptr, hbf, nullptr, nullptr, 1, N, 768, 0, 1);
    gcn_agg<<<N, 192, 0, stream>>>(hbf, bucket, cnt, dsc, bg, out_feats);

    // --- MultiAttn, last-wins center writeback ---
    winner_kernel<<<(U + 255) / 256, 256, 0, stream>>>(nbidx, slot, U);
    gemm_bt<<<gemm_blocks(UK, 1536), 256, 0, stream>>>(
        out_feats, 0, Wqkv_m_b + (size_t)768 * 768, bqkv_m + 768, kv, nullptr, nbidx, 1, UK, 1536, 0, 0);
    gemm_bt<<<gemm_blocks(U, 768), 256, 0, stream>>>(
        out_feats, 0, Wqkv_m_b, bqkv_m, qc, nullptr, nbidx, 32, U, 768, 0, 0);
    attn_m_kernel<<<U, 256, 0, stream>>>(kv, qc, out0);
    gemm_bt<<<gemm_blocks(U, 768), 256, 0, stream>>>(
        out0, 0, Wo_m_b, bo_m, projm, nullptr, nullptr, 1, U, 768, 0, 0);
    scatter_kernel<<<U, 256, 0, stream>>>(projm, nbidx, slot, out_feats);
}